// Round 12
// baseline (811.005 us; speedup 1.0000x reference)
//
#include <hip/hip_runtime.h>
#include <cstddef>

typedef _Float16 f16x4 __attribute__((ext_vector_type(4)));
typedef __fp16 h16x2 __attribute__((ext_vector_type(2)));
typedef float f32x4 __attribute__((ext_vector_type(4)));

__device__ __forceinline__ f32x4 mfma16(f16x4 a, f16x4 b, f32x4 c) {
  return __builtin_amdgcn_mfma_f32_16x16x16f16(a, b, c, 0, 0, 0);
}

// raw v_exp_f32 (2^x). OCML exp2f wraps it in denormal fixup we don't need.
__device__ __forceinline__ float fast_exp2(float x) {
#if __has_builtin(__builtin_amdgcn_exp2f)
  return __builtin_amdgcn_exp2f(x);
#else
  return exp2f(x);
#endif
}

// Q is pre-scaled by 0.25 * log2(e) so softmax weights are exp2(score).
#define QSCALE (0.25f * 1.44269504f)
#define NSPLIT 8
#define NMC 4096
#define NPC 8192
#define EMC 65536
#define EPC 262144
#define NTOT (NMC + NPC)      // 12288 combined nodes (prot offset by NMC)
#define ETOT (EMC + EPC)      // 327680 combined edges

// ---------------------------------------------------------------------------
// init node embedding, both graphs
// ---------------------------------------------------------------------------
__global__ __launch_bounds__(256) void init_embed_dual(
    const float* __restrict__ inm, const float* __restrict__ Wm,
    const float* __restrict__ bm, float* __restrict__ outm,
    const float* __restrict__ inp, const float* __restrict__ Wp,
    const float* __restrict__ bp, float* __restrict__ outp)
{
  int idx = blockIdx.x * 256 + threadIdx.x;
  const float *in, *W, *bb;
  float* out;
  int Kin;
  if (idx < NMC * 64) {
    in = inm; W = Wm; bb = bm; out = outm; Kin = 11;
  } else {
    idx -= NMC * 64;
    if (idx >= NPC * 64) return;
    in = inp; W = Wp; bb = bp; out = outp; Kin = 15;
  }
  int n = idx >> 6, o = idx & 63;
  float acc = bb[o];
  const float* row = in + (size_t)n * Kin;
  for (int k = 0; k < Kin; k++) acc += row[k] * W[k * 64 + o];
  out[idx] = acc;
}

// ===========================================================================
// CSR construction (once per call). Combined node space: mol [0,NM),
// prot [NM, NM+NP).
// ===========================================================================
__global__ __launch_bounds__(256) void deg_hist_kernel(
    const int* __restrict__ eim, const int* __restrict__ eip, int* __restrict__ deg)
{
  int idx = blockIdx.x * 256 + threadIdx.x;
  if (idx >= ETOT) return;
  int dst = (idx < EMC) ? eim[EMC + idx] : (eip[EPC + (idx - EMC)] + NMC);
  atomicAdd(&deg[dst], 1);
}

// one block, 1024 threads, 12 elems each: exclusive scan of deg -> rowStart,
// cursor; rowStart[NTOT] = total.
__global__ __launch_bounds__(1024) void scan_kernel(
    const int* __restrict__ deg, int* __restrict__ rowStart, int* __restrict__ cursor)
{
  __shared__ int part[1024];
  int t = threadIdx.x;
  int base = t * 12;
  int local[12];
  int s = 0;
  #pragma unroll
  for (int i = 0; i < 12; i++) { local[i] = s; s += deg[base + i]; }
  part[t] = s;
  __syncthreads();
  #pragma unroll
  for (int d = 1; d < 1024; d <<= 1) {
    int v = (t >= d) ? part[t - d] : 0;
    __syncthreads();
    part[t] += v;
    __syncthreads();
  }
  int prefix = (t == 0) ? 0 : part[t - 1];
  #pragma unroll
  for (int i = 0; i < 12; i++) {
    int v = prefix + local[i];
    rowStart[base + i] = v;
    cursor[base + i] = v;
  }
  if (t == 1023) rowStart[NTOT] = prefix + s;
}

// fill CSR slots; records slotOf[edge] for the attr permute.
__global__ __launch_bounds__(256) void fill_kernel(
    const int* __restrict__ eim, const int* __restrict__ eip,
    int* __restrict__ cursor, int* __restrict__ srcPerm, int* __restrict__ slotOf)
{
  int idx = blockIdx.x * 256 + threadIdx.x;
  if (idx >= ETOT) return;
  int src, dst;
  if (idx < EMC) {
    src = eim[idx]; dst = eim[EMC + idx];
  } else {
    int e = idx - EMC; src = eip[e]; dst = eip[EPC + e] + NMC;
  }
  int slot = atomicAdd(&cursor[dst], 1);
  srcPerm[slot] = src;
  slotOf[idx] = slot;
}

// permute the RAW 10-dim attr into slot order (padded to 12 floats/edge).
// 16 threads per edge: coalesced streaming reads, 48B scatter writes.
__global__ __launch_bounds__(256) void attr_perm_kernel(
    const int* __restrict__ slotOf,
    const float* __restrict__ attrm, const float* __restrict__ attrp,
    float* __restrict__ attrPerm)
{
  int idx = blockIdx.x * 256 + threadIdx.x;
  int e = idx >> 4, k = idx & 15;
  if (e >= ETOT || k >= 12) return;
  float v = 0.f;
  if (k < 10)
    v = (e < EMC) ? attrm[(size_t)e * 10 + k] : attrp[(size_t)(e - EMC) * 10 + k];
  attrPerm[(size_t)slotOf[e] * 12 + k] = v;
}

// ---------------------------------------------------------------------------
// GINE aggregation via CSR gather with INLINE edge embedding:
// agg[n][d] = sum_i relu(x[src_i][d] + be[d] + attr_i . We[:,d])
// wave per node; We column + be cached in registers (11 floats/lane).
// ---------------------------------------------------------------------------
__global__ __launch_bounds__(256) void gine_gather_kernel(
    const float* __restrict__ xm, const float* __restrict__ xp,
    const int* __restrict__ rowStart, const int* __restrict__ srcPerm,
    const float* __restrict__ attrPerm,
    const float* __restrict__ Wem, const float* __restrict__ bem,
    const float* __restrict__ Wep, const float* __restrict__ bep,
    float* __restrict__ aggm, float* __restrict__ aggp)
{
  int n = (blockIdx.x * 256 + threadIdx.x) >> 6;
  int lane = threadIdx.x & 63;
  if (n >= NTOT) return;
  const float *x, *We, *be;
  float* agg;
  int nl;
  if (n < NMC) { x = xm; agg = aggm; We = Wem; be = bem; nl = n; }
  else         { x = xp; agg = aggp; We = Wep; be = bep; nl = n - NMC; }
  float we[10];
  #pragma unroll
  for (int k = 0; k < 10; k++) we[k] = We[k * 64 + lane];
  float bee = be[lane];
  int b0 = rowStart[n], b1 = rowStart[n + 1];
  float acc = 0.f;
  int i = b0;
  for (; i + 1 < b1; i += 2) {
    int s0 = srcPerm[i], s1 = srcPerm[i + 1];
    const float4* ap0 = (const float4*)(attrPerm + (size_t)i * 12);
    const float4* ap1 = (const float4*)(attrPerm + (size_t)(i + 1) * 12);
    float4 a00 = ap0[0], a01 = ap0[1], a02 = ap0[2];
    float4 a10 = ap1[0], a11 = ap1[1], a12 = ap1[2];
    float x0 = x[(size_t)s0 * 64 + lane];
    float x1 = x[(size_t)s1 * 64 + lane];
    float e0 = bee + a00.x * we[0] + a00.y * we[1] + a00.z * we[2] + a00.w * we[3]
                   + a01.x * we[4] + a01.y * we[5] + a01.z * we[6] + a01.w * we[7]
                   + a02.x * we[8] + a02.y * we[9];
    float e1 = bee + a10.x * we[0] + a10.y * we[1] + a10.z * we[2] + a10.w * we[3]
                   + a11.x * we[4] + a11.y * we[5] + a11.z * we[6] + a11.w * we[7]
                   + a12.x * we[8] + a12.y * we[9];
    acc += fmaxf(x0 + e0, 0.f) + fmaxf(x1 + e1, 0.f);
  }
  for (; i < b1; i++) {
    int src = srcPerm[i];
    const float4* ap = (const float4*)(attrPerm + (size_t)i * 12);
    float4 a0 = ap[0], a1 = ap[1], a2 = ap[2];
    float ea = bee + a0.x * we[0] + a0.y * we[1] + a0.z * we[2] + a0.w * we[3]
                   + a1.x * we[4] + a1.y * we[5] + a1.z * we[6] + a1.w * we[7]
                   + a2.x * we[8] + a2.y * we[9];
    acc += fmaxf(x[(size_t)src * 64 + lane] + ea, 0.f);
  }
  agg[(size_t)nl * 64 + lane] = acc;
}

// ---------------------------------------------------------------------------
// Fused GINE node MLP + QKV projection, both graphs.
// blocks [0,64) mol, [64,192) prot.
// ---------------------------------------------------------------------------
__global__ __launch_bounds__(256) void mlp_proj_dual(
    const float* __restrict__ xm, const float* __restrict__ aggm,
    const float* __restrict__ W1m, const float* __restrict__ B1m,
    const float* __restrict__ W2m, const float* __restrict__ B2m,
    float* __restrict__ hm,
    const float* __restrict__ Wqm, const float* __restrict__ bqm,
    const float* __restrict__ Wkm, const float* __restrict__ bkm,
    const float* __restrict__ Wvm, const float* __restrict__ bvm,
    _Float16* __restrict__ Qom, _Float16* __restrict__ Kom, _Float16* __restrict__ Vtom,
    const float* __restrict__ xp, const float* __restrict__ aggp,
    const float* __restrict__ W1p, const float* __restrict__ B1p,
    const float* __restrict__ W2p, const float* __restrict__ B2p,
    float* __restrict__ hp,
    const float* __restrict__ Wqp, const float* __restrict__ bqp,
    const float* __restrict__ Wkp, const float* __restrict__ bkp,
    const float* __restrict__ Wvp, const float* __restrict__ bvp,
    _Float16* __restrict__ Qop, _Float16* __restrict__ Kop, _Float16* __restrict__ Vtop)
{
  __shared__ __align__(16) float sW[64 * 64];
  __shared__ __align__(16) float sBuf[64 * 68];
  int t = threadIdx.x;
  int b = blockIdx.x;
  const float *x, *agg, *W1, *B1, *W2, *B2, *Wq, *bq, *Wk, *bk, *Wv, *bv;
  float* hg;
  _Float16 *Qo, *Ko, *Vto;
  int n0, N;
  if (b < 64) {
    x = xm; agg = aggm; W1 = W1m; B1 = B1m; W2 = W2m; B2 = B2m; hg = hm;
    Wq = Wqm; bq = bqm; Wk = Wkm; bk = bkm; Wv = Wvm; bv = bvm;
    Qo = Qom; Ko = Kom; Vto = Vtom; n0 = b * 64; N = NMC;
  } else {
    x = xp; agg = aggp; W1 = W1p; B1 = B1p; W2 = W2p; B2 = B2p; hg = hp;
    Wq = Wqp; bq = bqp; Wk = Wkp; bk = bkp; Wv = Wvp; bv = bvp;
    Qo = Qop; Ko = Kop; Vto = Vtop; n0 = (b - 64) * 64; N = NPC;
  }
  int n = t >> 2, kk = t & 3;
  float acc[16];

  #pragma unroll
  for (int i = 0; i < 16; i++) {
    int f = t + i * 256;
    size_t g = (size_t)n0 * 64 + f;
    sBuf[(f >> 6) * 68 + (f & 63)] = x[g] + agg[g];
    sW[f] = W1[f];
  }
  __syncthreads();
  #pragma unroll
  for (int j = 0; j < 16; j++) acc[j] = B1[kk * 16 + j];
  #pragma unroll
  for (int d = 0; d < 64; d++) {
    float xv = sBuf[n * 68 + d];
    const float* wrow = &sW[d * 64 + kk * 16];
    #pragma unroll
    for (int j = 0; j < 16; j++) acc[j] += xv * wrow[j];
  }
  __syncthreads();
  #pragma unroll
  for (int j = 0; j < 16; j++) sBuf[n * 68 + kk * 16 + j] = fmaxf(acc[j], 0.f);
  #pragma unroll
  for (int i = 0; i < 16; i++) { int f = t + i * 256; sW[f] = W2[f]; }
  __syncthreads();
  #pragma unroll
  for (int j = 0; j < 16; j++) acc[j] = B2[kk * 16 + j];
  #pragma unroll
  for (int d = 0; d < 64; d++) {
    float xv = sBuf[n * 68 + d];
    const float* wrow = &sW[d * 64 + kk * 16];
    #pragma unroll
    for (int j = 0; j < 16; j++) acc[j] += xv * wrow[j];
  }
  float* hop = hg + (size_t)(n0 + n) * 64 + kk * 16;
  #pragma unroll
  for (int j = 0; j < 16; j++) {
    acc[j] = fmaxf(acc[j], 0.f);
    hop[j] = acc[j];
  }
  __syncthreads();
  #pragma unroll
  for (int j = 0; j < 16; j++) sBuf[n * 68 + kk * 16 + j] = acc[j];

  const float* Ws[3] = {Wq, Wk, Wv};
  const float* bs[3] = {bq, bk, bv};
  for (int p = 0; p < 3; p++) {
    if (p > 0) __syncthreads();
    #pragma unroll
    for (int i = 0; i < 16; i++) { int f = t + i * 256; sW[f] = Ws[p][f]; }
    __syncthreads();
    #pragma unroll
    for (int j = 0; j < 16; j++) acc[j] = bs[p][kk * 16 + j];
    #pragma unroll
    for (int d = 0; d < 64; d++) {
      float xv = sBuf[n * 68 + d];
      const float* wrow = &sW[d * 64 + kk * 16];
      #pragma unroll
      for (int j = 0; j < 16; j++) acc[j] += xv * wrow[j];
    }
    if (p == 2) {
      #pragma unroll
      for (int j = 0; j < 16; j++)
        Vto[((size_t)kk * 16 + j) * N + (n0 + n)] = (_Float16)acc[j];
    } else {
      float scale = (p == 0) ? QSCALE : 1.0f;
      _Float16 tmp[16];
      #pragma unroll
      for (int j = 0; j < 16; j++) tmp[j] = (_Float16)(acc[j] * scale);
      _Float16* base = (p == 0) ? Qo : Ko;
      float4* dst = (float4*)(base + ((size_t)kk * N + n0 + n) * 16);
      dst[0] = ((float4*)tmp)[0];
      dst[1] = ((float4*)tmp)[1];
    }
  }
}

// ---------------------------------------------------------------------------
// Key-split MFMA cross-attention. exp2 via raw v_exp_f32 (no clamp —
// scores empirically << f16 overflow bound; verified vs ref 8 rounds).
// L accumulated on the MFMA pipe via a ones-matrix MFMA (frees VALU).
// ---------------------------------------------------------------------------
__global__ __launch_bounds__(256, 4) void attn_split_kernel(
    const _Float16* __restrict__ Qm, const _Float16* __restrict__ Kp,
    const _Float16* __restrict__ Vtp, float* __restrict__ OPm, float* __restrict__ LPm,
    const _Float16* __restrict__ Qp, const _Float16* __restrict__ Km,
    const _Float16* __restrict__ Vtm, float* __restrict__ OPp, float* __restrict__ LPp)
{
  const int bx = blockIdx.x;
  const _Float16 *Q, *K, *Vt;
  float *Opart, *Lpart;
  int Nq, Nk, qb;
  if (bx < 32) { Q = Qm; K = Kp; Vt = Vtp; Opart = OPm; Lpart = LPm; Nq = NMC; Nk = NPC; qb = bx; }
  else         { Q = Qp; K = Km; Vt = Vtm; Opart = OPp; Lpart = LPp; Nq = NPC; Nk = NMC; qb = bx - 32; }
  const int h = blockIdx.y;
  const int split = blockIdx.z;
  const int Ks = Nk / NSPLIT;
  const int q0 = qb * 128;
  const int t = threadIdx.x;
  const int wave = t >> 6, lane = t & 63;
  const int l16 = lane & 15, quad = lane >> 4;

  f16x4 qf[8];
  #pragma unroll
  for (int g = 0; g < 8; g++)
    qf[g] = *(const f16x4*)(Q + ((size_t)h * Nq + q0 + g * 16 + l16) * 16 + quad * 4);
  const _Float16* Kh = K + (size_t)h * Nk * 16;
  const _Float16* Vh = Vt + ((size_t)h * 16 + l16) * Nk;

  f32x4 oacc[8], lq[8];
  #pragma unroll
  for (int g = 0; g < 8; g++) {
    oacc[g] = (f32x4){0.f, 0.f, 0.f, 0.f};
    lq[g]   = (f32x4){0.f, 0.f, 0.f, 0.f};
  }
  const f32x4 zero = {0.f, 0.f, 0.f, 0.f};
  const f16x4 onesA = {(_Float16)1.f, (_Float16)1.f, (_Float16)1.f, (_Float16)1.f};

  union PF { f16x4 v4; h16x2 h2[2]; };

  const int kend = (split + 1) * Ks;
  for (int kb = split * Ks + wave * 64; kb < kend; kb += 256) {
    f16x4 kf[4], vf[4];
    #pragma unroll
    for (int c = 0; c < 4; c++) {
      kf[c] = *(const f16x4*)(Kh + (size_t)(kb + c * 16 + l16) * 16 + quad * 4);
      vf[c] = *(const f16x4*)(Vh + kb + c * 16 + quad * 4);
    }
    #pragma unroll
    for (int g = 0; g < 8; g++) {
      f32x4 s[4];
      #pragma unroll
      for (int c = 0; c < 4; c++) s[c] = mfma16(kf[c], qf[g], zero);
      f16x4 pf[4];
      #pragma unroll
      for (int c = 0; c < 4; c++) {
        float p0 = fast_exp2(s[c][0]);
        float p1 = fast_exp2(s[c][1]);
        float p2 = fast_exp2(s[c][2]);
        float p3 = fast_exp2(s[c][3]);
        PF u;
        u.h2[0] = __builtin_amdgcn_cvt_pkrtz(p0, p1);
        u.h2[1] = __builtin_amdgcn_cvt_pkrtz(p2, p3);
        pf[c] = u.v4;
      }
      #pragma unroll
      for (int c = 0; c < 4; c++) {
        oacc[g] = mfma16(vf[c], pf[c], oacc[g]);
        lq[g]   = mfma16(onesA, pf[c], lq[g]);   // L[q] in every row
      }
    }
  }

  // lq[g][0] holds L[q=l16] (summed over this wave's keys) in ALL lanes of
  // column q — no shuffles needed.
  __shared__ float sO[4][4][16][17];   // [gg][wave][d][q(+pad)]
  __shared__ float sLw[8][4][16];      // [g][wave][q]
  if (quad == 0) {
    #pragma unroll
    for (int g = 0; g < 8; g++) sLw[g][wave][l16] = lq[g][0];
  }
  int q = t >> 4, d = t & 15;
  #pragma unroll
  for (int pass = 0; pass < 2; pass++) {
    __syncthreads();
    #pragma unroll
    for (int gg = 0; gg < 4; gg++) {
      int g = pass * 4 + gg;
      #pragma unroll
      for (int r = 0; r < 4; r++) sO[gg][wave][quad * 4 + r][l16] = oacc[g][r];
    }
    __syncthreads();
    #pragma unroll
    for (int gg = 0; gg < 4; gg++) {
      int g = pass * 4 + gg;
      float O = 0.f;
      #pragma unroll
      for (int w = 0; w < 4; w++) O += sO[gg][w][d][q];
      size_t row = (size_t)split * Nq + q0 + g * 16 + q;
      Opart[row * 64 + h * 16 + d] = O;
      if (d == 0) {
        float L = sLw[g][0][q] + sLw[g][1][q] + sLw[g][2][q] + sLw[g][3][q];
        Lpart[row * 4 + h] = L;
      }
    }
  }
}

// ---------------------------------------------------------------------------
// Fused attn-split combine + LayerNorm(h + O/L) * g + b, BOTH graphs.
// ---------------------------------------------------------------------------
__global__ __launch_bounds__(256) void ln_combine_dual(
    const float* __restrict__ hm, const float* __restrict__ Om,
    const float* __restrict__ Lm, const float* __restrict__ gm,
    const float* __restrict__ bm, float* __restrict__ outm,
    const float* __restrict__ hp, const float* __restrict__ Op,
    const float* __restrict__ Lp, const float* __restrict__ gp,
    const float* __restrict__ bp, float* __restrict__ outp)
{
  int idx = blockIdx.x * 256 + threadIdx.x;
  const float *hb, *Opart, *Lpart, *g, *bb;
  float* out;
  int N;
  int totalM = NMC * 64;
  if (idx < totalM) {
    hb = hm; Opart = Om; Lpart = Lm; g = gm; bb = bm; out = outm; N = NMC;
  } else {
    idx -= totalM;
    if (idx >= NPC * 64) return;
    hb = hp; Opart = Op; Lpart = Lp; g = gp; bb = bp; out = outp; N = NPC;
  }
  int n = idx >> 6, d = idx & 63, h = d >> 4;
  float O = 0.f, L = 0.f;
  #pragma unroll
  for (int s = 0; s < NSPLIT; s++) {
    size_t row = (size_t)s * N + n;
    O += Opart[row * 64 + d];
    L += Lpart[row * 4 + h];
  }
  float v = hb[idx] + O / L;
  float sm = v;
  #pragma unroll
  for (int o = 1; o < 64; o <<= 1) sm += __shfl_xor(sm, o);
  float mu = sm * 0.015625f;
  float c = v - mu;
  float q = c * c;
  #pragma unroll
  for (int o = 1; o < 64; o <<= 1) q += __shfl_xor(q, o);
  float var = q * 0.015625f;
  out[idx] = c * rsqrtf(var + 1e-5f) * g[d] + bb[d];
}

// ---------------------------------------------------------------------------
// Pooling via sorted-run register accumulation.
// ---------------------------------------------------------------------------
__global__ __launch_bounds__(256) void pool_run_kernel(
    const float* __restrict__ xm, const int* __restrict__ bm,
    const float* __restrict__ xp, const int* __restrict__ bp,
    float* __restrict__ sums, float* __restrict__ cnt)
{
  int wid = (blockIdx.x * 256 + threadIdx.x) >> 6;
  int lane = threadIdx.x & 63;
  const float* x;
  const int* batch;
  int n0, colOff, cntOff;
  if (wid < 64) {
    x = xm; batch = bm; n0 = wid * 64; colOff = 0; cntOff = 0;
  } else {
    wid -= 64;
    if (wid >= 128) return;
    x = xp; batch = bp; n0 = wid * 64; colOff = 64; cntOff = 32;
  }
  float acc = 0.f;
  int cur = batch[n0];
  int run = 0;
  for (int i = 0; i < 64; i++) {
    int n = n0 + i;
    int s = batch[n];
    if (s != cur) {
      atomicAdd(&sums[cur * 128 + colOff + lane], acc);
      if (lane == 0) atomicAdd(&cnt[cntOff + cur], (float)run);
      acc = 0.f; run = 0; cur = s;
    }
    acc += x[(size_t)n * 64 + lane];
    run++;
  }
  atomicAdd(&sums[cur * 128 + colOff + lane], acc);
  if (lane == 0) atomicAdd(&cnt[cntOff + cur], (float)run);
}

// ---------------------------------------------------------------------------
// final head
// ---------------------------------------------------------------------------
__global__ __launch_bounds__(256) void final_kernel(
    const float* __restrict__ sums, const float* __restrict__ cnt,
    const float* __restrict__ fc1w, const float* __restrict__ fc1b,
    const float* __restrict__ fc2w, const float* __restrict__ fc2b,
    float* __restrict__ out)
{
  __shared__ float z[32 * 128];
  __shared__ float h1[32 * 64];
  int t = threadIdx.x;
  for (int f = t; f < 32 * 128; f += 256) {
    int s = f >> 7, j = f & 127;
    float c = cnt[(j >> 6) * 32 + s];
    z[f] = sums[f] / fmaxf(c, 1.f);
  }
  __syncthreads();
  for (int f = t; f < 32 * 64; f += 256) {
    int s = f >> 6, o = f & 63;
    float acc = fc1b[o];
    for (int j = 0; j < 128; j++) acc += z[s * 128 + j] * fc1w[j * 64 + o];
    h1[f] = fmaxf(acc, 0.f);
  }
  __syncthreads();
  if (t < 32) {
    float acc = fc2b[0];
    for (int o = 0; o < 64; o++) acc += h1[t * 64 + o] * fc2w[o];
    out[t] = 1.f / (1.f + __expf(-acc));
  }
}

// ---------------------------------------------------------------------------
extern "C" void kernel_launch(void* const* d_in, const int* in_sizes, int n_in,
                              void* d_out, int out_size, void* d_ws, size_t ws_size,
                              hipStream_t stream)
{
  (void)in_sizes; (void)n_in; (void)out_size; (void)ws_size;
  const float* mol_x          = (const float*)d_in[0];
  const float* prot_x         = (const float*)d_in[1];
  const float* mol_edge_attr  = (const float*)d_in[2];
  const float* prot_edge_attr = (const float*)d_in[3];
  const float* inm_w = (const float*)d_in[4];
  const float* inm_b = (const float*)d_in[5];
  const float* inp_w = (const float*)d_in[6];
  const float* inp_b = (const float*)d_in[7];
  const float* iem_w = (const float*)d_in[8];
  const float* iem_b = (const float*)d_in[9];
  const float* iep_w = (const float*)d_in[10];
  const float* iep_b = (const float*)d_in[11];
  const float* gm_w1 = (const float*)d_in[12];
  const float* gm_b1 = (const float*)d_in[13];
  const float* gm_w2 = (const float*)d_in[14];
  const float* gm_b2 = (const float*)d_in[15];
  const float* gp_w1 = (const float*)d_in[16];
  const float* gp_b1 = (const float*)d_in[17];
  const float* gp_w2 = (const float*)d_in[18];
  const float* gp_b2 = (const float*)d_in[19];
  const float* m2p_w = (const float*)d_in[20];
  const float* m2p_b = (const float*)d_in[21];
  const float* p2m_w = (const float*)d_in[22];
  const float* p2m_b = (const float*)d_in[23];
  const float* lnm_g = (const float*)d_in[24];
  const float* lnm_b = (const float*)d_in[25];
  const float* lnp_g = (const float*)d_in[26];
  const float* lnp_b = (const float*)d_in[27];
  const float* fc1_w = (const float*)d_in[28];
  const float* fc1_b = (const float*)d_in[29];
  const float* fc2_w = (const float*)d_in[30];
  const float* fc2_b = (const float*)d_in[31];
  const int* mol_ei     = (const int*)d_in[32];
  const int* prot_ei    = (const int*)d_in[33];
  const int* mol_batch  = (const int*)d_in[34];
  const int* prot_batch = (const int*)d_in[35];

  const int NM = NMC, NP = NPC;

  float* ws = (float*)d_ws;
  size_t off = 0;
  auto nxt  = [&](size_t n) { float* p = ws + off; off += n; return p; };
  auto nxtH = [&](size_t n) { _Float16* p = (_Float16*)(ws + off); off += (n + 1) / 2; return p; };
  auto nxtI = [&](size_t n) { int* p = (int*)(ws + off); off += n; return p; };
  float* x_mol    = nxt((size_t)NM * 64);
  float* x_prot   = nxt((size_t)NP * 64);
  float* agg_mol  = nxt((size_t)NM * 64);
  float* agg_prot = nxt((size_t)NP * 64);
  float* h_mol    = nxt((size_t)NM * 64);
  float* h_prot   = nxt((size_t)NP * 64);
  _Float16* Qm  = nxtH((size_t)NM * 64);
  _Float16* Km  = nxtH((size_t)NM * 64);
  _Float16* Vtm = nxtH((size_t)NM * 64);
  _Float16* Qp  = nxtH((size_t)NP * 64);
  _Float16* Kp  = nxtH((size_t)NP * 64);
  _Float16* Vtp = nxtH((size_t)NP * 64);
  float* OPm = nxt((size_t)NSPLIT * NM * 64);
  float* LPm = nxt((size_t)NSPLIT * NM * 4);
  float* OPp = nxt((size_t)NSPLIT * NP * 64);
  float* LPp = nxt((size_t)NSPLIT * NP * 4);
  float* pool = nxt(32 * 128);
  float* cnt  = nxt(64);
  int* deg      = nxtI(NTOT);        // zeroed below
  int* rowStart = nxtI(NTOT + 1);
  int* cursor   = nxtI(NTOT);
  int* slotOf   = nxtI(ETOT);
  int* srcPerm  = nxtI(ETOT);
  float* attrPerm = nxt((size_t)ETOT * 12);

  // ---- CSR + attr permute setup (once per call) ----
  (void)hipMemsetAsync(deg, 0, NTOT * 4, stream);
  deg_hist_kernel<<<(ETOT + 255) / 256, 256, 0, stream>>>(mol_ei, prot_ei, deg);
  scan_kernel<<<1, 1024, 0, stream>>>(deg, rowStart, cursor);
  fill_kernel<<<(ETOT + 255) / 256, 256, 0, stream>>>(mol_ei, prot_ei, cursor, srcPerm, slotOf);
  attr_perm_kernel<<<ETOT * 16 / 256, 256, 0, stream>>>(slotOf, mol_edge_attr,
                                                        prot_edge_attr, attrPerm);

  init_embed_dual<<<(NM + NP) * 64 / 256, 256, 0, stream>>>(
      mol_x, inm_w, inm_b, x_mol, prot_x, inp_w, inp_b, x_prot);

  for (int l = 0; l < 3; l++) {
    gine_gather_kernel<<<NTOT / 4, 256, 0, stream>>>(
        x_mol, x_prot, rowStart, srcPerm, attrPerm,
        iem_w, iem_b, iep_w, iep_b, agg_mol, agg_prot);
    // m2p: Q=mol (m2p W0), K/V=prot (m2p W1,W2); p2m: Q=prot (p2m W0), K/V=mol (p2m W1,W2)
    mlp_proj_dual<<<192, 256, 0, stream>>>(
        x_mol, agg_mol, gm_w1 + l * 4096, gm_b1 + l * 64, gm_w2 + l * 4096, gm_b2 + l * 64, h_mol,
        m2p_w + (l * 3 + 0) * 4096, m2p_b + (l * 3 + 0) * 64,
        p2m_w + (l * 3 + 1) * 4096, p2m_b + (l * 3 + 1) * 64,
        p2m_w + (l * 3 + 2) * 4096, p2m_b + (l * 3 + 2) * 64,
        Qm, Km, Vtm,
        x_prot, agg_prot, gp_w1 + l * 4096, gp_b1 + l * 64, gp_w2 + l * 4096, gp_b2 + l * 64, h_prot,
        p2m_w + (l * 3 + 0) * 4096, p2m_b + (l * 3 + 0) * 64,
        m2p_w + (l * 3 + 1) * 4096, m2p_b + (l * 3 + 1) * 64,
        m2p_w + (l * 3 + 2) * 4096, m2p_b + (l * 3 + 2) * 64,
        Qp, Kp, Vtp);
    attn_split_kernel<<<dim3(96, 4, NSPLIT), 256, 0, stream>>>(
        Qm, Kp, Vtp, OPm, LPm, Qp, Km, Vtm, OPp, LPp);
    ln_combine_dual<<<(NM + NP) * 64 / 256, 256, 0, stream>>>(
        h_mol, OPm, LPm, lnm_g + l * 64, lnm_b + l * 64, x_mol,
        h_prot, OPp, LPp, lnp_g + l * 64, lnp_b + l * 64, x_prot);
  }

  (void)hipMemsetAsync(pool, 0, (32 * 128 + 64) * 4, stream);
  pool_run_kernel<<<48, 256, 0, stream>>>(x_mol, mol_batch, x_prot, prot_batch, pool, cnt);
  final_kernel<<<1, 256, 0, stream>>>(pool, cnt, fc1_w, fc1_b, fc2_w, fc2_b, (float*)d_out);
}

// Round 13
// 633.741 us; speedup vs baseline: 1.2797x; 1.2797x over previous
//
#include <hip/hip_runtime.h>
#include <cstddef>

typedef _Float16 f16x4 __attribute__((ext_vector_type(4)));
typedef __fp16 h16x2 __attribute__((ext_vector_type(2)));
typedef float f32x4 __attribute__((ext_vector_type(4)));

__device__ __forceinline__ f32x4 mfma16(f16x4 a, f16x4 b, f32x4 c) {
  return __builtin_amdgcn_mfma_f32_16x16x16f16(a, b, c, 0, 0, 0);
}

// raw v_exp_f32 (2^x). OCML exp2f wraps it in denormal fixup we don't need.
__device__ __forceinline__ float fast_exp2(float x) {
#if __has_builtin(__builtin_amdgcn_exp2f)
  return __builtin_amdgcn_exp2f(x);
#else
  return exp2f(x);
#endif
}

// Q is pre-scaled by 0.25 * log2(e) so softmax weights are exp2(score).
#define QSCALE (0.25f * 1.44269504f)
#define NSPLIT 8
#define NMC 4096
#define NPC 8192
#define EMC 65536
#define EPC 262144
#define NTOT (NMC + NPC)      // 12288 combined nodes (prot offset by NMC)
#define ETOT (EMC + EPC)      // 327680 combined edges

// ---------------------------------------------------------------------------
// init node embedding, both graphs
// ---------------------------------------------------------------------------
__global__ __launch_bounds__(256) void init_embed_dual(
    const float* __restrict__ inm, const float* __restrict__ Wm,
    const float* __restrict__ bm, float* __restrict__ outm,
    const float* __restrict__ inp, const float* __restrict__ Wp,
    const float* __restrict__ bp, float* __restrict__ outp)
{
  int idx = blockIdx.x * 256 + threadIdx.x;
  const float *in, *W, *bb;
  float* out;
  int Kin;
  if (idx < NMC * 64) {
    in = inm; W = Wm; bb = bm; out = outm; Kin = 11;
  } else {
    idx -= NMC * 64;
    if (idx >= NPC * 64) return;
    in = inp; W = Wp; bb = bp; out = outp; Kin = 15;
  }
  int n = idx >> 6, o = idx & 63;
  float acc = bb[o];
  const float* row = in + (size_t)n * Kin;
  for (int k = 0; k < Kin; k++) acc += row[k] * W[k * 64 + o];
  out[idx] = acc;
}

// ===========================================================================
// CSR construction (once per call). Combined node space: mol [0,NM),
// prot [NM, NM+NP). Mol edges fill slots [0,EMC) since all mol dsts < NMC.
// ===========================================================================
__global__ __launch_bounds__(256) void deg_hist_kernel(
    const int* __restrict__ eim, const int* __restrict__ eip, int* __restrict__ deg)
{
  int idx = blockIdx.x * 256 + threadIdx.x;
  if (idx >= ETOT) return;
  int dst = (idx < EMC) ? eim[EMC + idx] : (eip[EPC + (idx - EMC)] + NMC);
  atomicAdd(&deg[dst], 1);
}

// one block, 1024 threads, 12 elems each: exclusive scan of deg -> rowStart,
// cursor; rowStart[NTOT] = total.
__global__ __launch_bounds__(1024) void scan_kernel(
    const int* __restrict__ deg, int* __restrict__ rowStart, int* __restrict__ cursor)
{
  __shared__ int part[1024];
  int t = threadIdx.x;
  int base = t * 12;
  int local[12];
  int s = 0;
  #pragma unroll
  for (int i = 0; i < 12; i++) { local[i] = s; s += deg[base + i]; }
  part[t] = s;
  __syncthreads();
  #pragma unroll
  for (int d = 1; d < 1024; d <<= 1) {
    int v = (t >= d) ? part[t - d] : 0;
    __syncthreads();
    part[t] += v;
    __syncthreads();
  }
  int prefix = (t == 0) ? 0 : part[t - 1];
  #pragma unroll
  for (int i = 0; i < 12; i++) {
    int v = prefix + local[i];
    rowStart[base + i] = v;
    cursor[base + i] = v;
  }
  if (t == 1023) rowStart[NTOT] = prefix + s;
}

// fill CSR slots; records slotOf[edge] for the attr permute.
__global__ __launch_bounds__(256) void fill_kernel(
    const int* __restrict__ eim, const int* __restrict__ eip,
    int* __restrict__ cursor, int* __restrict__ srcPerm, int* __restrict__ slotOf)
{
  int idx = blockIdx.x * 256 + threadIdx.x;
  if (idx >= ETOT) return;
  int src, dst;
  if (idx < EMC) {
    src = eim[idx]; dst = eim[EMC + idx];
  } else {
    int e = idx - EMC; src = eip[e]; dst = eip[EPC + e] + NMC;
  }
  int slot = atomicAdd(&cursor[dst], 1);
  srcPerm[slot] = src;
  slotOf[idx] = slot;
}

// permute the RAW 10-dim attr into slot order (padded to 12 floats/edge).
// 16 threads per edge: coalesced streaming reads, 48B scatter writes.
__global__ __launch_bounds__(256) void attr_perm_kernel(
    const int* __restrict__ slotOf,
    const float* __restrict__ attrm, const float* __restrict__ attrp,
    float* __restrict__ attrPerm)
{
  int idx = blockIdx.x * 256 + threadIdx.x;
  int e = idx >> 4, k = idx & 15;
  if (e >= ETOT || k >= 12) return;
  float v = 0.f;
  if (k < 10)
    v = (e < EMC) ? attrm[(size_t)e * 10 + k] : attrp[(size_t)(e - EMC) * 10 + k];
  attrPerm[(size_t)slotOf[e] * 12 + k] = v;
}

// materialize fp16 edge embeddings in SLOT order: reads attrPerm slot-order
// (coalesced), writes eaPerm slot-order (coalesced) — no scatter anywhere.
// one wave per slot, lane = dim. slot < EMC <=> mol edge.
__global__ __launch_bounds__(256) void ea_lin_kernel(
    const float* __restrict__ attrPerm,
    const float* __restrict__ Wem, const float* __restrict__ bem,
    const float* __restrict__ Wep, const float* __restrict__ bep,
    _Float16* __restrict__ eaPerm)
{
  int slot = (blockIdx.x * 256 + threadIdx.x) >> 6;
  int lane = threadIdx.x & 63;
  if (slot >= ETOT) return;
  const float* We;
  const float* be;
  if (slot < EMC) { We = Wem; be = bem; }
  else            { We = Wep; be = bep; }
  const float* arow = attrPerm + (size_t)slot * 12;
  float ea = be[lane];
  #pragma unroll
  for (int k = 0; k < 10; k++) ea += arow[k] * We[k * 64 + lane];
  eaPerm[(size_t)slot * 64 + lane] = (_Float16)ea;
}

// ---------------------------------------------------------------------------
// GINE aggregation via CSR gather: one wave per node, lane = dim.
// agg[n] = sum_i relu(x[src_i] + ea_i)  -- no atomics, no memset.
// ---------------------------------------------------------------------------
__global__ __launch_bounds__(256) void gine_gather_kernel(
    const float* __restrict__ xm, const float* __restrict__ xp,
    const int* __restrict__ rowStart, const int* __restrict__ srcPerm,
    const _Float16* __restrict__ eaPerm,
    float* __restrict__ aggm, float* __restrict__ aggp)
{
  int n = (blockIdx.x * 256 + threadIdx.x) >> 6;
  int lane = threadIdx.x & 63;
  if (n >= NTOT) return;
  const float* x;
  float* agg;
  int nl;
  if (n < NMC) { x = xm; agg = aggm; nl = n; }
  else         { x = xp; agg = aggp; nl = n - NMC; }
  int b0 = rowStart[n], b1 = rowStart[n + 1];
  float acc = 0.f;
  int i = b0;
  for (; i + 3 < b1; i += 4) {
    int s0 = srcPerm[i], s1 = srcPerm[i + 1], s2 = srcPerm[i + 2], s3 = srcPerm[i + 3];
    float e0 = (float)eaPerm[(size_t)i * 64 + lane];
    float e1 = (float)eaPerm[(size_t)(i + 1) * 64 + lane];
    float e2 = (float)eaPerm[(size_t)(i + 2) * 64 + lane];
    float e3 = (float)eaPerm[(size_t)(i + 3) * 64 + lane];
    float x0 = x[(size_t)s0 * 64 + lane];
    float x1 = x[(size_t)s1 * 64 + lane];
    float x2 = x[(size_t)s2 * 64 + lane];
    float x3 = x[(size_t)s3 * 64 + lane];
    acc += fmaxf(x0 + e0, 0.f) + fmaxf(x1 + e1, 0.f)
         + fmaxf(x2 + e2, 0.f) + fmaxf(x3 + e3, 0.f);
  }
  for (; i < b1; i++) {
    int src = srcPerm[i];
    float m = x[(size_t)src * 64 + lane] + (float)eaPerm[(size_t)i * 64 + lane];
    acc += fmaxf(m, 0.f);
  }
  agg[(size_t)nl * 64 + lane] = acc;
}

// ---------------------------------------------------------------------------
// Fused GINE node MLP + QKV projection, both graphs.
// blocks [0,64) mol, [64,192) prot.
// ---------------------------------------------------------------------------
__global__ __launch_bounds__(256) void mlp_proj_dual(
    const float* __restrict__ xm, const float* __restrict__ aggm,
    const float* __restrict__ W1m, const float* __restrict__ B1m,
    const float* __restrict__ W2m, const float* __restrict__ B2m,
    float* __restrict__ hm,
    const float* __restrict__ Wqm, const float* __restrict__ bqm,
    const float* __restrict__ Wkm, const float* __restrict__ bkm,
    const float* __restrict__ Wvm, const float* __restrict__ bvm,
    _Float16* __restrict__ Qom, _Float16* __restrict__ Kom, _Float16* __restrict__ Vtom,
    const float* __restrict__ xp, const float* __restrict__ aggp,
    const float* __restrict__ W1p, const float* __restrict__ B1p,
    const float* __restrict__ W2p, const float* __restrict__ B2p,
    float* __restrict__ hp,
    const float* __restrict__ Wqp, const float* __restrict__ bqp,
    const float* __restrict__ Wkp, const float* __restrict__ bkp,
    const float* __restrict__ Wvp, const float* __restrict__ bvp,
    _Float16* __restrict__ Qop, _Float16* __restrict__ Kop, _Float16* __restrict__ Vtop)
{
  __shared__ __align__(16) float sW[64 * 64];
  __shared__ __align__(16) float sBuf[64 * 68];
  int t = threadIdx.x;
  int b = blockIdx.x;
  const float *x, *agg, *W1, *B1, *W2, *B2, *Wq, *bq, *Wk, *bk, *Wv, *bv;
  float* hg;
  _Float16 *Qo, *Ko, *Vto;
  int n0, N;
  if (b < 64) {
    x = xm; agg = aggm; W1 = W1m; B1 = B1m; W2 = W2m; B2 = B2m; hg = hm;
    Wq = Wqm; bq = bqm; Wk = Wkm; bk = bkm; Wv = Wvm; bv = bvm;
    Qo = Qom; Ko = Kom; Vto = Vtom; n0 = b * 64; N = NMC;
  } else {
    x = xp; agg = aggp; W1 = W1p; B1 = B1p; W2 = W2p; B2 = B2p; hg = hp;
    Wq = Wqp; bq = bqp; Wk = Wkp; bk = bkp; Wv = Wvp; bv = bvp;
    Qo = Qop; Ko = Kop; Vto = Vtop; n0 = (b - 64) * 64; N = NPC;
  }
  int n = t >> 2, kk = t & 3;
  float acc[16];

  #pragma unroll
  for (int i = 0; i < 16; i++) {
    int f = t + i * 256;
    size_t g = (size_t)n0 * 64 + f;
    sBuf[(f >> 6) * 68 + (f & 63)] = x[g] + agg[g];
    sW[f] = W1[f];
  }
  __syncthreads();
  #pragma unroll
  for (int j = 0; j < 16; j++) acc[j] = B1[kk * 16 + j];
  #pragma unroll
  for (int d = 0; d < 64; d++) {
    float xv = sBuf[n * 68 + d];
    const float* wrow = &sW[d * 64 + kk * 16];
    #pragma unroll
    for (int j = 0; j < 16; j++) acc[j] += xv * wrow[j];
  }
  __syncthreads();
  #pragma unroll
  for (int j = 0; j < 16; j++) sBuf[n * 68 + kk * 16 + j] = fmaxf(acc[j], 0.f);
  #pragma unroll
  for (int i = 0; i < 16; i++) { int f = t + i * 256; sW[f] = W2[f]; }
  __syncthreads();
  #pragma unroll
  for (int j = 0; j < 16; j++) acc[j] = B2[kk * 16 + j];
  #pragma unroll
  for (int d = 0; d < 64; d++) {
    float xv = sBuf[n * 68 + d];
    const float* wrow = &sW[d * 64 + kk * 16];
    #pragma unroll
    for (int j = 0; j < 16; j++) acc[j] += xv * wrow[j];
  }
  float* hop = hg + (size_t)(n0 + n) * 64 + kk * 16;
  #pragma unroll
  for (int j = 0; j < 16; j++) {
    acc[j] = fmaxf(acc[j], 0.f);
    hop[j] = acc[j];
  }
  __syncthreads();
  #pragma unroll
  for (int j = 0; j < 16; j++) sBuf[n * 68 + kk * 16 + j] = acc[j];

  const float* Ws[3] = {Wq, Wk, Wv};
  const float* bs[3] = {bq, bk, bv};
  for (int p = 0; p < 3; p++) {
    if (p > 0) __syncthreads();
    #pragma unroll
    for (int i = 0; i < 16; i++) { int f = t + i * 256; sW[f] = Ws[p][f]; }
    __syncthreads();
    #pragma unroll
    for (int j = 0; j < 16; j++) acc[j] = bs[p][kk * 16 + j];
    #pragma unroll
    for (int d = 0; d < 64; d++) {
      float xv = sBuf[n * 68 + d];
      const float* wrow = &sW[d * 64 + kk * 16];
      #pragma unroll
      for (int j = 0; j < 16; j++) acc[j] += xv * wrow[j];
    }
    if (p == 2) {
      #pragma unroll
      for (int j = 0; j < 16; j++)
        Vto[((size_t)kk * 16 + j) * N + (n0 + n)] = (_Float16)acc[j];
    } else {
      float scale = (p == 0) ? QSCALE : 1.0f;
      _Float16 tmp[16];
      #pragma unroll
      for (int j = 0; j < 16; j++) tmp[j] = (_Float16)(acc[j] * scale);
      _Float16* base = (p == 0) ? Qo : Ko;
      float4* dst = (float4*)(base + ((size_t)kk * N + n0 + n) * 16);
      dst[0] = ((float4*)tmp)[0];
      dst[1] = ((float4*)tmp)[1];
    }
  }
}

// ---------------------------------------------------------------------------
// Key-split MFMA cross-attention (round-11 structure: fdot2 L, 52 VGPR,
// no spills). exp2 via raw v_exp_f32, no clamp (verified vs ref).
// ---------------------------------------------------------------------------
__global__ __launch_bounds__(256, 4) void attn_split_kernel(
    const _Float16* __restrict__ Qm, const _Float16* __restrict__ Kp,
    const _Float16* __restrict__ Vtp, float* __restrict__ OPm, float* __restrict__ LPm,
    const _Float16* __restrict__ Qp, const _Float16* __restrict__ Km,
    const _Float16* __restrict__ Vtm, float* __restrict__ OPp, float* __restrict__ LPp)
{
  const int bx = blockIdx.x;
  const _Float16 *Q, *K, *Vt;
  float *Opart, *Lpart;
  int Nq, Nk, qb;
  if (bx < 32) { Q = Qm; K = Kp; Vt = Vtp; Opart = OPm; Lpart = LPm; Nq = NMC; Nk = NPC; qb = bx; }
  else         { Q = Qp; K = Km; Vt = Vtm; Opart = OPp; Lpart = LPp; Nq = NPC; Nk = NMC; qb = bx - 32; }
  const int h = blockIdx.y;
  const int split = blockIdx.z;
  const int Ks = Nk / NSPLIT;
  const int q0 = qb * 128;
  const int t = threadIdx.x;
  const int wave = t >> 6, lane = t & 63;
  const int l16 = lane & 15, quad = lane >> 4;

  f16x4 qf[8];
  #pragma unroll
  for (int g = 0; g < 8; g++)
    qf[g] = *(const f16x4*)(Q + ((size_t)h * Nq + q0 + g * 16 + l16) * 16 + quad * 4);
  const _Float16* Kh = K + (size_t)h * Nk * 16;
  const _Float16* Vh = Vt + ((size_t)h * 16 + l16) * Nk;

  f32x4 oacc[8];
  float lacc[8];
  #pragma unroll
  for (int g = 0; g < 8; g++) { oacc[g] = (f32x4){0.f,0.f,0.f,0.f}; lacc[g] = 0.f; }
  const f32x4 zero = {0.f, 0.f, 0.f, 0.f};
  const h16x2 ones2 = {(__fp16)1.f, (__fp16)1.f};

  union PF { f16x4 v4; h16x2 h2[2]; };

  const int kend = (split + 1) * Ks;
  for (int kb = split * Ks + wave * 64; kb < kend; kb += 256) {
    f16x4 kf[4], vf[4];
    #pragma unroll
    for (int c = 0; c < 4; c++) {
      kf[c] = *(const f16x4*)(Kh + (size_t)(kb + c * 16 + l16) * 16 + quad * 4);
      vf[c] = *(const f16x4*)(Vh + kb + c * 16 + quad * 4);
    }
    #pragma unroll
    for (int g = 0; g < 8; g++) {
      f32x4 s[4];
      #pragma unroll
      for (int c = 0; c < 4; c++) s[c] = mfma16(kf[c], qf[g], zero);
      f16x4 pf[4];
      #pragma unroll
      for (int c = 0; c < 4; c++) {
        float p0 = fast_exp2(s[c][0]);
        float p1 = fast_exp2(s[c][1]);
        float p2 = fast_exp2(s[c][2]);
        float p3 = fast_exp2(s[c][3]);
        PF u;
        u.h2[0] = __builtin_amdgcn_cvt_pkrtz(p0, p1);
        u.h2[1] = __builtin_amdgcn_cvt_pkrtz(p2, p3);
        pf[c] = u.v4;
        lacc[g] = __builtin_amdgcn_fdot2(u.h2[0], ones2, lacc[g], false);
        lacc[g] = __builtin_amdgcn_fdot2(u.h2[1], ones2, lacc[g], false);
      }
      #pragma unroll
      for (int c = 0; c < 4; c++) oacc[g] = mfma16(vf[c], pf[c], oacc[g]);
    }
  }

  // quad-reduce L within wave
  #pragma unroll
  for (int g = 0; g < 8; g++) {
    lacc[g] += __shfl_xor(lacc[g], 16);
    lacc[g] += __shfl_xor(lacc[g], 32);
  }

  // two-pass cross-wave combine (padded; ~20 KB)
  __shared__ float sO[4][4][16][17];   // [gg][wave][d][q(+pad)]
  __shared__ float sLw[8][4][16];      // [g][wave][q]
  if (quad == 0) {
    #pragma unroll
    for (int g = 0; g < 8; g++) sLw[g][wave][l16] = lacc[g];
  }
  int q = t >> 4, d = t & 15;
  #pragma unroll
  for (int pass = 0; pass < 2; pass++) {
    __syncthreads();
    #pragma unroll
    for (int gg = 0; gg < 4; gg++) {
      int g = pass * 4 + gg;
      #pragma unroll
      for (int r = 0; r < 4; r++) sO[gg][wave][quad * 4 + r][l16] = oacc[g][r];
    }
    __syncthreads();
    #pragma unroll
    for (int gg = 0; gg < 4; gg++) {
      int g = pass * 4 + gg;
      float O = 0.f;
      #pragma unroll
      for (int w = 0; w < 4; w++) O += sO[gg][w][d][q];
      size_t row = (size_t)split * Nq + q0 + g * 16 + q;
      Opart[row * 64 + h * 16 + d] = O;
      if (d == 0) {
        float L = sLw[g][0][q] + sLw[g][1][q] + sLw[g][2][q] + sLw[g][3][q];
        Lpart[row * 4 + h] = L;
      }
    }
  }
}

// ---------------------------------------------------------------------------
// Fused attn-split combine + LayerNorm(h + O/L) * g + b, BOTH graphs.
// ---------------------------------------------------------------------------
__global__ __launch_bounds__(256) void ln_combine_dual(
    const float* __restrict__ hm, const float* __restrict__ Om,
    const float* __restrict__ Lm, const float* __restrict__ gm,
    const float* __restrict__ bm, float* __restrict__ outm,
    const float* __restrict__ hp, const float* __restrict__ Op,
    const float* __restrict__ Lp, const float* __restrict__ gp,
    const float* __restrict__ bp, float* __restrict__ outp)
{
  int idx = blockIdx.x * 256 + threadIdx.x;
  const float *hb, *Opart, *Lpart, *g, *bb;
  float* out;
  int N;
  int totalM = NMC * 64;
  if (idx < totalM) {
    hb = hm; Opart = Om; Lpart = Lm; g = gm; bb = bm; out = outm; N = NMC;
  } else {
    idx -= totalM;
    if (idx >= NPC * 64) return;
    hb = hp; Opart = Op; Lpart = Lp; g = gp; bb = bp; out = outp; N = NPC;
  }
  int n = idx >> 6, d = idx & 63, h = d >> 4;
  float O = 0.f, L = 0.f;
  #pragma unroll
  for (int s = 0; s < NSPLIT; s++) {
    size_t row = (size_t)s * N + n;
    O += Opart[row * 64 + d];
    L += Lpart[row * 4 + h];
  }
  float v = hb[idx] + O / L;
  float sm = v;
  #pragma unroll
  for (int o = 1; o < 64; o <<= 1) sm += __shfl_xor(sm, o);
  float mu = sm * 0.015625f;
  float c = v - mu;
  float q = c * c;
  #pragma unroll
  for (int o = 1; o < 64; o <<= 1) q += __shfl_xor(q, o);
  float var = q * 0.015625f;
  out[idx] = c * rsqrtf(var + 1e-5f) * g[d] + bb[d];
}

// ---------------------------------------------------------------------------
// Pooling via sorted-run register accumulation.
// ---------------------------------------------------------------------------
__global__ __launch_bounds__(256) void pool_run_kernel(
    const float* __restrict__ xm, const int* __restrict__ bm,
    const float* __restrict__ xp, const int* __restrict__ bp,
    float* __restrict__ sums, float* __restrict__ cnt)
{
  int wid = (blockIdx.x * 256 + threadIdx.x) >> 6;
  int lane = threadIdx.x & 63;
  const float* x;
  const int* batch;
  int n0, colOff, cntOff;
  if (wid < 64) {
    x = xm; batch = bm; n0 = wid * 64; colOff = 0; cntOff = 0;
  } else {
    wid -= 64;
    if (wid >= 128) return;
    x = xp; batch = bp; n0 = wid * 64; colOff = 64; cntOff = 32;
  }
  float acc = 0.f;
  int cur = batch[n0];
  int run = 0;
  for (int i = 0; i < 64; i++) {
    int n = n0 + i;
    int s = batch[n];
    if (s != cur) {
      atomicAdd(&sums[cur * 128 + colOff + lane], acc);
      if (lane == 0) atomicAdd(&cnt[cntOff + cur], (float)run);
      acc = 0.f; run = 0; cur = s;
    }
    acc += x[(size_t)n * 64 + lane];
    run++;
  }
  atomicAdd(&sums[cur * 128 + colOff + lane], acc);
  if (lane == 0) atomicAdd(&cnt[cntOff + cur], (float)run);
}

// ---------------------------------------------------------------------------
// final head
// ---------------------------------------------------------------------------
__global__ __launch_bounds__(256) void final_kernel(
    const float* __restrict__ sums, const float* __restrict__ cnt,
    const float* __restrict__ fc1w, const float* __restrict__ fc1b,
    const float* __restrict__ fc2w, const float* __restrict__ fc2b,
    float* __restrict__ out)
{
  __shared__ float z[32 * 128];
  __shared__ float h1[32 * 64];
  int t = threadIdx.x;
  for (int f = t; f < 32 * 128; f += 256) {
    int s = f >> 7, j = f & 127;
    float c = cnt[(j >> 6) * 32 + s];
    z[f] = sums[f] / fmaxf(c, 1.f);
  }
  __syncthreads();
  for (int f = t; f < 32 * 64; f += 256) {
    int s = f >> 6, o = f & 63;
    float acc = fc1b[o];
    for (int j = 0; j < 128; j++) acc += z[s * 128 + j] * fc1w[j * 64 + o];
    h1[f] = fmaxf(acc, 0.f);
  }
  __syncthreads();
  if (t < 32) {
    float acc = fc2b[0];
    for (int o = 0; o < 64; o++) acc += h1[t * 64 + o] * fc2w[o];
    out[t] = 1.f / (1.f + __expf(-acc));
  }
}

// ---------------------------------------------------------------------------
extern "C" void kernel_launch(void* const* d_in, const int* in_sizes, int n_in,
                              void* d_out, int out_size, void* d_ws, size_t ws_size,
                              hipStream_t stream)
{
  (void)in_sizes; (void)n_in; (void)out_size; (void)ws_size;
  const float* mol_x          = (const float*)d_in[0];
  const float* prot_x         = (const float*)d_in[1];
  const float* mol_edge_attr  = (const float*)d_in[2];
  const float* prot_edge_attr = (const float*)d_in[3];
  const float* inm_w = (const float*)d_in[4];
  const float* inm_b = (const float*)d_in[5];
  const float* inp_w = (const float*)d_in[6];
  const float* inp_b = (const float*)d_in[7];
  const float* iem_w = (const float*)d_in[8];
  const float* iem_b = (const float*)d_in[9];
  const float* iep_w = (const float*)d_in[10];
  const float* iep_b = (const float*)d_in[11];
  const float* gm_w1 = (const float*)d_in[12];
  const float* gm_b1 = (const float*)d_in[13];
  const float* gm_w2 = (const float*)d_in[14];
  const float* gm_b2 = (const float*)d_in[15];
  const float* gp_w1 = (const float*)d_in[16];
  const float* gp_b1 = (const float*)d_in[17];
  const float* gp_w2 = (const float*)d_in[18];
  const float* gp_b2 = (const float*)d_in[19];
  const float* m2p_w = (const float*)d_in[20];
  const float* m2p_b = (const float*)d_in[21];
  const float* p2m_w = (const float*)d_in[22];
  const float* p2m_b = (const float*)d_in[23];
  const float* lnm_g = (const float*)d_in[24];
  const float* lnm_b = (const float*)d_in[25];
  const float* lnp_g = (const float*)d_in[26];
  const float* lnp_b = (const float*)d_in[27];
  const float* fc1_w = (const float*)d_in[28];
  const float* fc1_b = (const float*)d_in[29];
  const float* fc2_w = (const float*)d_in[30];
  const float* fc2_b = (const float*)d_in[31];
  const int* mol_ei     = (const int*)d_in[32];
  const int* prot_ei    = (const int*)d_in[33];
  const int* mol_batch  = (const int*)d_in[34];
  const int* prot_batch = (const int*)d_in[35];

  const int NM = NMC, NP = NPC;

  float* ws = (float*)d_ws;
  size_t off = 0;
  auto nxt  = [&](size_t n) { float* p = ws + off; off += n; return p; };
  auto nxtH = [&](size_t n) { _Float16* p = (_Float16*)(ws + off); off += (n + 1) / 2; return p; };
  auto nxtI = [&](size_t n) { int* p = (int*)(ws + off); off += n; return p; };
  float* x_mol    = nxt((size_t)NM * 64);
  float* x_prot   = nxt((size_t)NP * 64);
  float* agg_mol  = nxt((size_t)NM * 64);
  float* agg_prot = nxt((size_t)NP * 64);
  float* h_mol    = nxt((size_t)NM * 64);
  float* h_prot   = nxt((size_t)NP * 64);
  _Float16* Qm  = nxtH((size_t)NM * 64);
  _Float16* Km  = nxtH((size_t)NM * 64);
  _Float16* Vtm = nxtH((size_t)NM * 64);
  _Float16* Qp  = nxtH((size_t)NP * 64);
  _Float16* Kp  = nxtH((size_t)NP * 64);
  _Float16* Vtp = nxtH((size_t)NP * 64);
  float* OPm = nxt((size_t)NSPLIT * NM * 64);
  float* LPm = nxt((size_t)NSPLIT * NM * 4);
  float* OPp = nxt((size_t)NSPLIT * NP * 64);
  float* LPp = nxt((size_t)NSPLIT * NP * 4);
  float* pool = nxt(32 * 128);
  float* cnt  = nxt(64);
  int* deg      = nxtI(NTOT);        // zeroed below
  int* rowStart = nxtI(NTOT + 1);
  int* cursor   = nxtI(NTOT);
  int* slotOf   = nxtI(ETOT);
  int* srcPerm  = nxtI(ETOT);
  float* attrPerm = nxt((size_t)ETOT * 12);
  _Float16* eaPerm = nxtH((size_t)ETOT * 64);

  // ---- CSR + edge-embedding setup (once per call) ----
  (void)hipMemsetAsync(deg, 0, NTOT * 4, stream);
  deg_hist_kernel<<<(ETOT + 255) / 256, 256, 0, stream>>>(mol_ei, prot_ei, deg);
  scan_kernel<<<1, 1024, 0, stream>>>(deg, rowStart, cursor);
  fill_kernel<<<(ETOT + 255) / 256, 256, 0, stream>>>(mol_ei, prot_ei, cursor, srcPerm, slotOf);
  attr_perm_kernel<<<ETOT * 16 / 256, 256, 0, stream>>>(slotOf, mol_edge_attr,
                                                        prot_edge_attr, attrPerm);
  ea_lin_kernel<<<ETOT / 4, 256, 0, stream>>>(attrPerm, iem_w, iem_b, iep_w, iep_b, eaPerm);

  init_embed_dual<<<(NM + NP) * 64 / 256, 256, 0, stream>>>(
      mol_x, inm_w, inm_b, x_mol, prot_x, inp_w, inp_b, x_prot);

  for (int l = 0; l < 3; l++) {
    gine_gather_kernel<<<NTOT / 4, 256, 0, stream>>>(x_mol, x_prot, rowStart, srcPerm,
                                                     eaPerm, agg_mol, agg_prot);
    // m2p: Q=mol (m2p W0), K/V=prot (m2p W1,W2); p2m: Q=prot (p2m W0), K/V=mol (p2m W1,W2)
    mlp_proj_dual<<<192, 256, 0, stream>>>(
        x_mol, agg_mol, gm_w1 + l * 4096, gm_b1 + l * 64, gm_w2 + l * 4096, gm_b2 + l * 64, h_mol,
        m2p_w + (l * 3 + 0) * 4096, m2p_b + (l * 3 + 0) * 64,
        p2m_w + (l * 3 + 1) * 4096, p2m_b + (l * 3 + 1) * 64,
        p2m_w + (l * 3 + 2) * 4096, p2m_b + (l * 3 + 2) * 64,
        Qm, Km, Vtm,
        x_prot, agg_prot, gp_w1 + l * 4096, gp_b1 + l * 64, gp_w2 + l * 4096, gp_b2 + l * 64, h_prot,
        p2m_w + (l * 3 + 0) * 4096, p2m_b + (l * 3 + 0) * 64,
        m2p_w + (l * 3 + 1) * 4096, m2p_b + (l * 3 + 1) * 64,
        m2p_w + (l * 3 + 2) * 4096, m2p_b + (l * 3 + 2) * 64,
        Qp, Kp, Vtp);
    attn_split_kernel<<<dim3(96, 4, NSPLIT), 256, 0, stream>>>(
        Qm, Kp, Vtp, OPm, LPm, Qp, Km, Vtm, OPp, LPp);
    ln_combine_dual<<<(NM + NP) * 64 / 256, 256, 0, stream>>>(
        h_mol, OPm, LPm, lnm_g + l * 64, lnm_b + l * 64, x_mol,
        h_prot, OPp, LPp, lnp_g + l * 64, lnp_b + l * 64, x_prot);
  }

  (void)hipMemsetAsync(pool, 0, (32 * 128 + 64) * 4, stream);
  pool_run_kernel<<<48, 256, 0, stream>>>(x_mol, mol_batch, x_prot, prot_batch, pool, cnt);
  final_kernel<<<1, 256, 0, stream>>>(pool, cnt, fc1_w, fc1_b, fc2_w, fc2_b, (float*)d_out);
}

// Round 14
// 591.396 us; speedup vs baseline: 1.3713x; 1.0716x over previous
//
#include <hip/hip_runtime.h>
#include <cstddef>

typedef _Float16 f16x4 __attribute__((ext_vector_type(4)));
typedef __fp16 h16x2 __attribute__((ext_vector_type(2)));
typedef float f32x4 __attribute__((ext_vector_type(4)));

__device__ __forceinline__ f32x4 mfma16(f16x4 a, f16x4 b, f32x4 c) {
  return __builtin_amdgcn_mfma_f32_16x16x16f16(a, b, c, 0, 0, 0);
}

// raw v_exp_f32 (2^x). OCML exp2f wraps it in denormal fixup we don't need.
__device__ __forceinline__ float fast_exp2(float x) {
#if __has_builtin(__builtin_amdgcn_exp2f)
  return __builtin_amdgcn_exp2f(x);
#else
  return exp2f(x);
#endif
}

// Q is pre-scaled by 0.25 * log2(e) so softmax weights are exp2(score).
#define QSCALE (0.25f * 1.44269504f)
#define NSPLIT 8
#define NMC 4096
#define NPC 8192
#define EMC 65536
#define EPC 262144
#define NTOT (NMC + NPC)      // 12288 combined nodes (prot offset by NMC)
#define ETOT (EMC + EPC)      // 327680 combined edges

// ---------------------------------------------------------------------------
// init node embedding, both graphs
// ---------------------------------------------------------------------------
__global__ __launch_bounds__(256) void init_embed_dual(
    const float* __restrict__ inm, const float* __restrict__ Wm,
    const float* __restrict__ bm, float* __restrict__ outm,
    const float* __restrict__ inp, const float* __restrict__ Wp,
    const float* __restrict__ bp, float* __restrict__ outp)
{
  int idx = blockIdx.x * 256 + threadIdx.x;
  const float *in, *W, *bb;
  float* out;
  int Kin;
  if (idx < NMC * 64) {
    in = inm; W = Wm; bb = bm; out = outm; Kin = 11;
  } else {
    idx -= NMC * 64;
    if (idx >= NPC * 64) return;
    in = inp; W = Wp; bb = bp; out = outp; Kin = 15;
  }
  int n = idx >> 6, o = idx & 63;
  float acc = bb[o];
  const float* row = in + (size_t)n * Kin;
  for (int k = 0; k < Kin; k++) acc += row[k] * W[k * 64 + o];
  out[idx] = acc;
}

// ===========================================================================
// CSR construction (once per call). Combined node space: mol [0,NM),
// prot [NM, NM+NP). Mol edges fill slots [0,EMC) since all mol dsts < NMC.
// ===========================================================================
__global__ __launch_bounds__(256) void deg_hist_kernel(
    const int* __restrict__ eim, const int* __restrict__ eip, int* __restrict__ deg)
{
  int idx = blockIdx.x * 256 + threadIdx.x;
  if (idx >= ETOT) return;
  int dst = (idx < EMC) ? eim[EMC + idx] : (eip[EPC + (idx - EMC)] + NMC);
  atomicAdd(&deg[dst], 1);
}

// one block, 1024 threads, 12 elems each: exclusive scan of deg -> rowStart,
// cursor; rowStart[NTOT] = total.
__global__ __launch_bounds__(1024) void scan_kernel(
    const int* __restrict__ deg, int* __restrict__ rowStart, int* __restrict__ cursor)
{
  __shared__ int part[1024];
  int t = threadIdx.x;
  int base = t * 12;
  int local[12];
  int s = 0;
  #pragma unroll
  for (int i = 0; i < 12; i++) { local[i] = s; s += deg[base + i]; }
  part[t] = s;
  __syncthreads();
  #pragma unroll
  for (int d = 1; d < 1024; d <<= 1) {
    int v = (t >= d) ? part[t - d] : 0;
    __syncthreads();
    part[t] += v;
    __syncthreads();
  }
  int prefix = (t == 0) ? 0 : part[t - 1];
  #pragma unroll
  for (int i = 0; i < 12; i++) {
    int v = prefix + local[i];
    rowStart[base + i] = v;
    cursor[base + i] = v;
  }
  if (t == 1023) rowStart[NTOT] = prefix + s;
}

// fill CSR slots; records slotOf[edge] for the attr permute.
__global__ __launch_bounds__(256) void fill_kernel(
    const int* __restrict__ eim, const int* __restrict__ eip,
    int* __restrict__ cursor, int* __restrict__ srcPerm, int* __restrict__ slotOf)
{
  int idx = blockIdx.x * 256 + threadIdx.x;
  if (idx >= ETOT) return;
  int src, dst;
  if (idx < EMC) {
    src = eim[idx]; dst = eim[EMC + idx];
  } else {
    int e = idx - EMC; src = eip[e]; dst = eip[EPC + e] + NMC;
  }
  int slot = atomicAdd(&cursor[dst], 1);
  srcPerm[slot] = src;
  slotOf[idx] = slot;
}

// permute the RAW 10-dim attr into slot order (padded to 12 floats/edge).
// 16 threads per edge: coalesced streaming reads, 48B scatter writes.
__global__ __launch_bounds__(256) void attr_perm_kernel(
    const int* __restrict__ slotOf,
    const float* __restrict__ attrm, const float* __restrict__ attrp,
    float* __restrict__ attrPerm)
{
  int idx = blockIdx.x * 256 + threadIdx.x;
  int e = idx >> 4, k = idx & 15;
  if (e >= ETOT || k >= 12) return;
  float v = 0.f;
  if (k < 10)
    v = (e < EMC) ? attrm[(size_t)e * 10 + k] : attrp[(size_t)(e - EMC) * 10 + k];
  attrPerm[(size_t)slotOf[e] * 12 + k] = v;
}

// materialize fp16 edge embeddings in SLOT order, 128 slots per block.
// attr tile + We + be staged in LDS; thread computes 32 dims of one slot,
// stores 4x dwordx4 (16B/lane; consecutive lanes cover consecutive 64B).
// A block never spans the mol/prot boundary (EMC % 128 == 0).
__global__ __launch_bounds__(256) void ea_lin_kernel(
    const float* __restrict__ attrPerm,
    const float* __restrict__ Wem, const float* __restrict__ bem,
    const float* __restrict__ Wep, const float* __restrict__ bep,
    _Float16* __restrict__ eaPerm)
{
  __shared__ __align__(16) float sAttr[128 * 12];   // 6 KB
  __shared__ float sWe[10 * 64];                    // 2.5 KB
  __shared__ float sBe[64];
  int t = threadIdx.x;
  int s0 = blockIdx.x * 128;
  const float* We = (s0 < EMC) ? Wem : Wep;
  const float* be = (s0 < EMC) ? bem : bep;
  #pragma unroll
  for (int i = 0; i < 6; i++) {
    int f = t + i * 256;
    sAttr[f] = attrPerm[(size_t)s0 * 12 + f];
  }
  for (int f = t; f < 640; f += 256) sWe[f] = We[f];
  if (t < 64) sBe[t] = be[t];
  __syncthreads();
  int sl = t >> 1;               // slot within tile, 0..127
  int d0 = (t & 1) * 32;         // dim half
  float at[10];
  #pragma unroll
  for (int k = 0; k < 10; k++) at[k] = sAttr[sl * 12 + k];
  _Float16 outv[32];
  #pragma unroll
  for (int j = 0; j < 32; j++) {
    int d = d0 + j;
    float ea = sBe[d];
    #pragma unroll
    for (int k = 0; k < 10; k++) ea += at[k] * sWe[k * 64 + d];
    outv[j] = (_Float16)ea;
  }
  float4* dst = (float4*)(eaPerm + (size_t)(s0 + sl) * 64 + d0);
  const float4* src = (const float4*)outv;
  #pragma unroll
  for (int j = 0; j < 4; j++) dst[j] = src[j];
}

// ---------------------------------------------------------------------------
// GINE aggregation via CSR gather: one wave per node, lane = dim.
// ---------------------------------------------------------------------------
__global__ __launch_bounds__(256) void gine_gather_kernel(
    const float* __restrict__ xm, const float* __restrict__ xp,
    const int* __restrict__ rowStart, const int* __restrict__ srcPerm,
    const _Float16* __restrict__ eaPerm,
    float* __restrict__ aggm, float* __restrict__ aggp)
{
  int n = (blockIdx.x * 256 + threadIdx.x) >> 6;
  int lane = threadIdx.x & 63;
  if (n >= NTOT) return;
  const float* x;
  float* agg;
  int nl;
  if (n < NMC) { x = xm; agg = aggm; nl = n; }
  else         { x = xp; agg = aggp; nl = n - NMC; }
  int b0 = rowStart[n], b1 = rowStart[n + 1];
  float acc = 0.f;
  int i = b0;
  for (; i + 3 < b1; i += 4) {
    int s0 = srcPerm[i], s1 = srcPerm[i + 1], s2 = srcPerm[i + 2], s3 = srcPerm[i + 3];
    float e0 = (float)eaPerm[(size_t)i * 64 + lane];
    float e1 = (float)eaPerm[(size_t)(i + 1) * 64 + lane];
    float e2 = (float)eaPerm[(size_t)(i + 2) * 64 + lane];
    float e3 = (float)eaPerm[(size_t)(i + 3) * 64 + lane];
    float x0 = x[(size_t)s0 * 64 + lane];
    float x1 = x[(size_t)s1 * 64 + lane];
    float x2 = x[(size_t)s2 * 64 + lane];
    float x3 = x[(size_t)s3 * 64 + lane];
    acc += fmaxf(x0 + e0, 0.f) + fmaxf(x1 + e1, 0.f)
         + fmaxf(x2 + e2, 0.f) + fmaxf(x3 + e3, 0.f);
  }
  for (; i < b1; i++) {
    int src = srcPerm[i];
    float m = x[(size_t)src * 64 + lane] + (float)eaPerm[(size_t)i * 64 + lane];
    acc += fmaxf(m, 0.f);
  }
  agg[(size_t)nl * 64 + lane] = acc;
}

// ---------------------------------------------------------------------------
// Fused GINE node MLP + QKV projection, both graphs.
// blocks [0,64) mol, [64,192) prot.
// ---------------------------------------------------------------------------
__global__ __launch_bounds__(256) void mlp_proj_dual(
    const float* __restrict__ xm, const float* __restrict__ aggm,
    const float* __restrict__ W1m, const float* __restrict__ B1m,
    const float* __restrict__ W2m, const float* __restrict__ B2m,
    float* __restrict__ hm,
    const float* __restrict__ Wqm, const float* __restrict__ bqm,
    const float* __restrict__ Wkm, const float* __restrict__ bkm,
    const float* __restrict__ Wvm, const float* __restrict__ bvm,
    _Float16* __restrict__ Qom, _Float16* __restrict__ Kom, _Float16* __restrict__ Vtom,
    const float* __restrict__ xp, const float* __restrict__ aggp,
    const float* __restrict__ W1p, const float* __restrict__ B1p,
    const float* __restrict__ W2p, const float* __restrict__ B2p,
    float* __restrict__ hp,
    const float* __restrict__ Wqp, const float* __restrict__ bqp,
    const float* __restrict__ Wkp, const float* __restrict__ bkp,
    const float* __restrict__ Wvp, const float* __restrict__ bvp,
    _Float16* __restrict__ Qop, _Float16* __restrict__ Kop, _Float16* __restrict__ Vtop)
{
  __shared__ __align__(16) float sW[64 * 64];
  __shared__ __align__(16) float sBuf[64 * 68];
  int t = threadIdx.x;
  int b = blockIdx.x;
  const float *x, *agg, *W1, *B1, *W2, *B2, *Wq, *bq, *Wk, *bk, *Wv, *bv;
  float* hg;
  _Float16 *Qo, *Ko, *Vto;
  int n0, N;
  if (b < 64) {
    x = xm; agg = aggm; W1 = W1m; B1 = B1m; W2 = W2m; B2 = B2m; hg = hm;
    Wq = Wqm; bq = bqm; Wk = Wkm; bk = bkm; Wv = Wvm; bv = bvm;
    Qo = Qom; Ko = Kom; Vto = Vtom; n0 = b * 64; N = NMC;
  } else {
    x = xp; agg = aggp; W1 = W1p; B1 = B1p; W2 = W2p; B2 = B2p; hg = hp;
    Wq = Wqp; bq = bqp; Wk = Wkp; bk = bkp; Wv = Wvp; bv = bvp;
    Qo = Qop; Ko = Kop; Vto = Vtop; n0 = (b - 64) * 64; N = NPC;
  }
  int n = t >> 2, kk = t & 3;
  float acc[16];

  #pragma unroll
  for (int i = 0; i < 16; i++) {
    int f = t + i * 256;
    size_t g = (size_t)n0 * 64 + f;
    sBuf[(f >> 6) * 68 + (f & 63)] = x[g] + agg[g];
    sW[f] = W1[f];
  }
  __syncthreads();
  #pragma unroll
  for (int j = 0; j < 16; j++) acc[j] = B1[kk * 16 + j];
  #pragma unroll
  for (int d = 0; d < 64; d++) {
    float xv = sBuf[n * 68 + d];
    const float* wrow = &sW[d * 64 + kk * 16];
    #pragma unroll
    for (int j = 0; j < 16; j++) acc[j] += xv * wrow[j];
  }
  __syncthreads();
  #pragma unroll
  for (int j = 0; j < 16; j++) sBuf[n * 68 + kk * 16 + j] = fmaxf(acc[j], 0.f);
  #pragma unroll
  for (int i = 0; i < 16; i++) { int f = t + i * 256; sW[f] = W2[f]; }
  __syncthreads();
  #pragma unroll
  for (int j = 0; j < 16; j++) acc[j] = B2[kk * 16 + j];
  #pragma unroll
  for (int d = 0; d < 64; d++) {
    float xv = sBuf[n * 68 + d];
    const float* wrow = &sW[d * 64 + kk * 16];
    #pragma unroll
    for (int j = 0; j < 16; j++) acc[j] += xv * wrow[j];
  }
  float* hop = hg + (size_t)(n0 + n) * 64 + kk * 16;
  #pragma unroll
  for (int j = 0; j < 16; j++) {
    acc[j] = fmaxf(acc[j], 0.f);
    hop[j] = acc[j];
  }
  __syncthreads();
  #pragma unroll
  for (int j = 0; j < 16; j++) sBuf[n * 68 + kk * 16 + j] = acc[j];

  const float* Ws[3] = {Wq, Wk, Wv};
  const float* bs[3] = {bq, bk, bv};
  for (int p = 0; p < 3; p++) {
    if (p > 0) __syncthreads();
    #pragma unroll
    for (int i = 0; i < 16; i++) { int f = t + i * 256; sW[f] = Ws[p][f]; }
    __syncthreads();
    #pragma unroll
    for (int j = 0; j < 16; j++) acc[j] = bs[p][kk * 16 + j];
    #pragma unroll
    for (int d = 0; d < 64; d++) {
      float xv = sBuf[n * 68 + d];
      const float* wrow = &sW[d * 64 + kk * 16];
      #pragma unroll
      for (int j = 0; j < 16; j++) acc[j] += xv * wrow[j];
    }
    if (p == 2) {
      #pragma unroll
      for (int j = 0; j < 16; j++)
        Vto[((size_t)kk * 16 + j) * N + (n0 + n)] = (_Float16)acc[j];
    } else {
      float scale = (p == 0) ? QSCALE : 1.0f;
      _Float16 tmp[16];
      #pragma unroll
      for (int j = 0; j < 16; j++) tmp[j] = (_Float16)(acc[j] * scale);
      _Float16* base = (p == 0) ? Qo : Ko;
      float4* dst = (float4*)(base + ((size_t)kk * N + n0 + n) * 16);
      dst[0] = ((float4*)tmp)[0];
      dst[1] = ((float4*)tmp)[1];
    }
  }
}

// ---------------------------------------------------------------------------
// Key-split MFMA cross-attention, 2x software-pipelined K-loop: both tiles'
// K/V loads issue before either tile's compute (iteration counts are even:
// m2p 4, p2m 2). fdot2-L (no spills), raw exp2, no clamp.
// ---------------------------------------------------------------------------
__global__ __launch_bounds__(256, 4) void attn_split_kernel(
    const _Float16* __restrict__ Qm, const _Float16* __restrict__ Kp,
    const _Float16* __restrict__ Vtp, float* __restrict__ OPm, float* __restrict__ LPm,
    const _Float16* __restrict__ Qp, const _Float16* __restrict__ Km,
    const _Float16* __restrict__ Vtm, float* __restrict__ OPp, float* __restrict__ LPp)
{
  const int bx = blockIdx.x;
  const _Float16 *Q, *K, *Vt;
  float *Opart, *Lpart;
  int Nq, Nk, qb;
  if (bx < 32) { Q = Qm; K = Kp; Vt = Vtp; Opart = OPm; Lpart = LPm; Nq = NMC; Nk = NPC; qb = bx; }
  else         { Q = Qp; K = Km; Vt = Vtm; Opart = OPp; Lpart = LPp; Nq = NPC; Nk = NMC; qb = bx - 32; }
  const int h = blockIdx.y;
  const int split = blockIdx.z;
  const int Ks = Nk / NSPLIT;
  const int q0 = qb * 128;
  const int t = threadIdx.x;
  const int wave = t >> 6, lane = t & 63;
  const int l16 = lane & 15, quad = lane >> 4;

  f16x4 qf[8];
  #pragma unroll
  for (int g = 0; g < 8; g++)
    qf[g] = *(const f16x4*)(Q + ((size_t)h * Nq + q0 + g * 16 + l16) * 16 + quad * 4);
  const _Float16* Kh = K + (size_t)h * Nk * 16;
  const _Float16* Vh = Vt + ((size_t)h * 16 + l16) * Nk;

  f32x4 oacc[8];
  float lacc[8];
  #pragma unroll
  for (int g = 0; g < 8; g++) { oacc[g] = (f32x4){0.f,0.f,0.f,0.f}; lacc[g] = 0.f; }
  const f32x4 zero = {0.f, 0.f, 0.f, 0.f};
  const h16x2 ones2 = {(__fp16)1.f, (__fp16)1.f};

  union PF { f16x4 v4; h16x2 h2[2]; };

  auto process = [&](const f16x4* kf, const f16x4* vf) {
    #pragma unroll
    for (int g = 0; g < 8; g++) {
      f32x4 s[4];
      #pragma unroll
      for (int c = 0; c < 4; c++) s[c] = mfma16(kf[c], qf[g], zero);
      f16x4 pf[4];
      #pragma unroll
      for (int c = 0; c < 4; c++) {
        float p0 = fast_exp2(s[c][0]);
        float p1 = fast_exp2(s[c][1]);
        float p2 = fast_exp2(s[c][2]);
        float p3 = fast_exp2(s[c][3]);
        PF u;
        u.h2[0] = __builtin_amdgcn_cvt_pkrtz(p0, p1);
        u.h2[1] = __builtin_amdgcn_cvt_pkrtz(p2, p3);
        pf[c] = u.v4;
        lacc[g] = __builtin_amdgcn_fdot2(u.h2[0], ones2, lacc[g], false);
        lacc[g] = __builtin_amdgcn_fdot2(u.h2[1], ones2, lacc[g], false);
      }
      #pragma unroll
      for (int c = 0; c < 4; c++) oacc[g] = mfma16(vf[c], pf[c], oacc[g]);
    }
  };

  const int kend = (split + 1) * Ks;
  int kb = split * Ks + wave * 64;
  for (; kb + 256 < kend; kb += 512) {
    f16x4 kfA[4], vfA[4], kfB[4], vfB[4];
    #pragma unroll
    for (int c = 0; c < 4; c++) {
      kfA[c] = *(const f16x4*)(Kh + (size_t)(kb + c * 16 + l16) * 16 + quad * 4);
      vfA[c] = *(const f16x4*)(Vh + kb + c * 16 + quad * 4);
    }
    #pragma unroll
    for (int c = 0; c < 4; c++) {
      kfB[c] = *(const f16x4*)(Kh + (size_t)(kb + 256 + c * 16 + l16) * 16 + quad * 4);
      vfB[c] = *(const f16x4*)(Vh + kb + 256 + c * 16 + quad * 4);
    }
    process(kfA, vfA);
    process(kfB, vfB);
  }
  for (; kb < kend; kb += 256) {     // remainder (unused for current shapes)
    f16x4 kf[4], vf[4];
    #pragma unroll
    for (int c = 0; c < 4; c++) {
      kf[c] = *(const f16x4*)(Kh + (size_t)(kb + c * 16 + l16) * 16 + quad * 4);
      vf[c] = *(const f16x4*)(Vh + kb + c * 16 + quad * 4);
    }
    process(kf, vf);
  }

  // quad-reduce L within wave
  #pragma unroll
  for (int g = 0; g < 8; g++) {
    lacc[g] += __shfl_xor(lacc[g], 16);
    lacc[g] += __shfl_xor(lacc[g], 32);
  }

  // two-pass cross-wave combine (padded; ~20 KB)
  __shared__ float sO[4][4][16][17];   // [gg][wave][d][q(+pad)]
  __shared__ float sLw[8][4][16];      // [g][wave][q]
  if (quad == 0) {
    #pragma unroll
    for (int g = 0; g < 8; g++) sLw[g][wave][l16] = lacc[g];
  }
  int q = t >> 4, d = t & 15;
  #pragma unroll
  for (int pass = 0; pass < 2; pass++) {
    __syncthreads();
    #pragma unroll
    for (int gg = 0; gg < 4; gg++) {
      int g = pass * 4 + gg;
      #pragma unroll
      for (int r = 0; r < 4; r++) sO[gg][wave][quad * 4 + r][l16] = oacc[g][r];
    }
    __syncthreads();
    #pragma unroll
    for (int gg = 0; gg < 4; gg++) {
      int g = pass * 4 + gg;
      float O = 0.f;
      #pragma unroll
      for (int w = 0; w < 4; w++) O += sO[gg][w][d][q];
      size_t row = (size_t)split * Nq + q0 + g * 16 + q;
      Opart[row * 64 + h * 16 + d] = O;
      if (d == 0) {
        float L = sLw[g][0][q] + sLw[g][1][q] + sLw[g][2][q] + sLw[g][3][q];
        Lpart[row * 4 + h] = L;
      }
    }
  }
}

// ---------------------------------------------------------------------------
// Fused attn-split combine + LayerNorm(h + O/L) * g + b, BOTH graphs.
// ---------------------------------------------------------------------------
__global__ __launch_bounds__(256) void ln_combine_dual(
    const float* __restrict__ hm, const float* __restrict__ Om,
    const float* __restrict__ Lm, const float* __restrict__ gm,
    const float* __restrict__ bm, float* __restrict__ outm,
    const float* __restrict__ hp, const float* __restrict__ Op,
    const float* __restrict__ Lp, const float* __restrict__ gp,
    const float* __restrict__ bp, float* __restrict__ outp)
{
  int idx = blockIdx.x * 256 + threadIdx.x;
  const float *hb, *Opart, *Lpart, *g, *bb;
  float* out;
  int N;
  int totalM = NMC * 64;
  if (idx < totalM) {
    hb = hm; Opart = Om; Lpart = Lm; g = gm; bb = bm; out = outm; N = NMC;
  } else {
    idx -= totalM;
    if (idx >= NPC * 64) return;
    hb = hp; Opart = Op; Lpart = Lp; g = gp; bb = bp; out = outp; N = NPC;
  }
  int n = idx >> 6, d = idx & 63, h = d >> 4;
  float O = 0.f, L = 0.f;
  #pragma unroll
  for (int s = 0; s < NSPLIT; s++) {
    size_t row = (size_t)s * N + n;
    O += Opart[row * 64 + d];
    L += Lpart[row * 4 + h];
  }
  float v = hb[idx] + O / L;
  float sm = v;
  #pragma unroll
  for (int o = 1; o < 64; o <<= 1) sm += __shfl_xor(sm, o);
  float mu = sm * 0.015625f;
  float c = v - mu;
  float q = c * c;
  #pragma unroll
  for (int o = 1; o < 64; o <<= 1) q += __shfl_xor(q, o);
  float var = q * 0.015625f;
  out[idx] = c * rsqrtf(var + 1e-5f) * g[d] + bb[d];
}

// ---------------------------------------------------------------------------
// Pooling via sorted-run register accumulation.
// ---------------------------------------------------------------------------
__global__ __launch_bounds__(256) void pool_run_kernel(
    const float* __restrict__ xm, const int* __restrict__ bm,
    const float* __restrict__ xp, const int* __restrict__ bp,
    float* __restrict__ sums, float* __restrict__ cnt)
{
  int wid = (blockIdx.x * 256 + threadIdx.x) >> 6;
  int lane = threadIdx.x & 63;
  const float* x;
  const int* batch;
  int n0, colOff, cntOff;
  if (wid < 64) {
    x = xm; batch = bm; n0 = wid * 64; colOff = 0; cntOff = 0;
  } else {
    wid -= 64;
    if (wid >= 128) return;
    x = xp; batch = bp; n0 = wid * 64; colOff = 64; cntOff = 32;
  }
  float acc = 0.f;
  int cur = batch[n0];
  int run = 0;
  for (int i = 0; i < 64; i++) {
    int n = n0 + i;
    int s = batch[n];
    if (s != cur) {
      atomicAdd(&sums[cur * 128 + colOff + lane], acc);
      if (lane == 0) atomicAdd(&cnt[cntOff + cur], (float)run);
      acc = 0.f; run = 0; cur = s;
    }
    acc += x[(size_t)n * 64 + lane];
    run++;
  }
  atomicAdd(&sums[cur * 128 + colOff + lane], acc);
  if (lane == 0) atomicAdd(&cnt[cntOff + cur], (float)run);
}

// ---------------------------------------------------------------------------
// final head
// ---------------------------------------------------------------------------
__global__ __launch_bounds__(256) void final_kernel(
    const float* __restrict__ sums, const float* __restrict__ cnt,
    const float* __restrict__ fc1w, const float* __restrict__ fc1b,
    const float* __restrict__ fc2w, const float* __restrict__ fc2b,
    float* __restrict__ out)
{
  __shared__ float z[32 * 128];
  __shared__ float h1[32 * 64];
  int t = threadIdx.x;
  for (int f = t; f < 32 * 128; f += 256) {
    int s = f >> 7, j = f & 127;
    float c = cnt[(j >> 6) * 32 + s];
    z[f] = sums[f] / fmaxf(c, 1.f);
  }
  __syncthreads();
  for (int f = t; f < 32 * 64; f += 256) {
    int s = f >> 6, o = f & 63;
    float acc = fc1b[o];
    for (int j = 0; j < 128; j++) acc += z[s * 128 + j] * fc1w[j * 64 + o];
    h1[f] = fmaxf(acc, 0.f);
  }
  __syncthreads();
  if (t < 32) {
    float acc = fc2b[0];
    for (int o = 0; o < 64; o++) acc += h1[t * 64 + o] * fc2w[o];
    out[t] = 1.f / (1.f + __expf(-acc));
  }
}

// ---------------------------------------------------------------------------
extern "C" void kernel_launch(void* const* d_in, const int* in_sizes, int n_in,
                              void* d_out, int out_size, void* d_ws, size_t ws_size,
                              hipStream_t stream)
{
  (void)in_sizes; (void)n_in; (void)out_size; (void)ws_size;
  const float* mol_x          = (const float*)d_in[0];
  const float* prot_x         = (const float*)d_in[1];
  const float* mol_edge_attr  = (const float*)d_in[2];
  const float* prot_edge_attr = (const float*)d_in[3];
  const float* inm_w = (const float*)d_in[4];
  const float* inm_b = (const float*)d_in[5];
  const float* inp_w = (const float*)d_in[6];
  const float* inp_b = (const float*)d_in[7];
  const float* iem_w = (const float*)d_in[8];
  const float* iem_b = (const float*)d_in[9];
  const float* iep_w = (const float*)d_in[10];
  const float* iep_b = (const float*)d_in[11];
  const float* gm_w1 = (const float*)d_in[12];
  const float* gm_b1 = (const float*)d_in[13];
  const float* gm_w2 = (const float*)d_in[14];
  const float* gm_b2 = (const float*)d_in[15];
  const float* gp_w1 = (const float*)d_in[16];
  const float* gp_b1 = (const float*)d_in[17];
  const float* gp_w2 = (const float*)d_in[18];
  const float* gp_b2 = (const float*)d_in[19];
  const float* m2p_w = (const float*)d_in[20];
  const float* m2p_b = (const float*)d_in[21];
  const float* p2m_w = (const float*)d_in[22];
  const float* p2m_b = (const float*)d_in[23];
  const float* lnm_g = (const float*)d_in[24];
  const float* lnm_b = (const float*)d_in[25];
  const float* lnp_g = (const float*)d_in[26];
  const float* lnp_b = (const float*)d_in[27];
  const float* fc1_w = (const float*)d_in[28];
  const float* fc1_b = (const float*)d_in[29];
  const float* fc2_w = (const float*)d_in[30];
  const float* fc2_b = (const float*)d_in[31];
  const int* mol_ei     = (const int*)d_in[32];
  const int* prot_ei    = (const int*)d_in[33];
  const int* mol_batch  = (const int*)d_in[34];
  const int* prot_batch = (const int*)d_in[35];

  const int NM = NMC, NP = NPC;

  float* ws = (float*)d_ws;
  size_t off = 0;
  auto nxt  = [&](size_t n) { float* p = ws + off; off += n; return p; };
  auto nxtH = [&](size_t n) { _Float16* p = (_Float16*)(ws + off); off += (n + 1) / 2; return p; };
  auto nxtI = [&](size_t n) { int* p = (int*)(ws + off); off += n; return p; };
  float* x_mol    = nxt((size_t)NM * 64);
  float* x_prot   = nxt((size_t)NP * 64);
  float* agg_mol  = nxt((size_t)NM * 64);
  float* agg_prot = nxt((size_t)NP * 64);
  float* h_mol    = nxt((size_t)NM * 64);
  float* h_prot   = nxt((size_t)NP * 64);
  _Float16* Qm  = nxtH((size_t)NM * 64);
  _Float16* Km  = nxtH((size_t)NM * 64);
  _Float16* Vtm = nxtH((size_t)NM * 64);
  _Float16* Qp  = nxtH((size_t)NP * 64);
  _Float16* Kp  = nxtH((size_t)NP * 64);
  _Float16* Vtp = nxtH((size_t)NP * 64);
  float* OPm = nxt((size_t)NSPLIT * NM * 64);
  float* LPm = nxt((size_t)NSPLIT * NM * 4);
  float* OPp = nxt((size_t)NSPLIT * NP * 64);
  float* LPp = nxt((size_t)NSPLIT * NP * 4);
  float* pool = nxt(32 * 128);
  float* cnt  = nxt(64);
  int* deg      = nxtI(NTOT);        // zeroed below
  int* rowStart = nxtI(NTOT + 1);
  int* cursor   = nxtI(NTOT);
  int* slotOf   = nxtI(ETOT);
  int* srcPerm  = nxtI(ETOT);
  float* attrPerm = nxt((size_t)ETOT * 12);
  _Float16* eaPerm = nxtH((size_t)ETOT * 64);

  // ---- CSR + edge-embedding setup (once per call) ----
  (void)hipMemsetAsync(deg, 0, NTOT * 4, stream);
  deg_hist_kernel<<<(ETOT + 255) / 256, 256, 0, stream>>>(mol_ei, prot_ei, deg);
  scan_kernel<<<1, 1024, 0, stream>>>(deg, rowStart, cursor);
  fill_kernel<<<(ETOT + 255) / 256, 256, 0, stream>>>(mol_ei, prot_ei, cursor, srcPerm, slotOf);
  attr_perm_kernel<<<ETOT * 16 / 256, 256, 0, stream>>>(slotOf, mol_edge_attr,
                                                        prot_edge_attr, attrPerm);
  ea_lin_kernel<<<ETOT / 128, 256, 0, stream>>>(attrPerm, iem_w, iem_b, iep_w, iep_b, eaPerm);

  init_embed_dual<<<(NM + NP) * 64 / 256, 256, 0, stream>>>(
      mol_x, inm_w, inm_b, x_mol, prot_x, inp_w, inp_b, x_prot);

  for (int l = 0; l < 3; l++) {
    gine_gather_kernel<<<NTOT / 4, 256, 0, stream>>>(x_mol, x_prot, rowStart, srcPerm,
                                                     eaPerm, agg_mol, agg_prot);
    // m2p: Q=mol (m2p W0), K/V=prot (m2p W1,W2); p2m: Q=prot (p2m W0), K/V=mol (p2m W1,W2)
    mlp_proj_dual<<<192, 256, 0, stream>>>(
        x_mol, agg_mol, gm_w1 + l * 4096, gm_b1 + l * 64, gm_w2 + l * 4096, gm_b2 + l * 64, h_mol,
        m2p_w + (l * 3 + 0) * 4096, m2p_b + (l * 3 + 0) * 64,
        p2m_w + (l * 3 + 1) * 4096, p2m_b + (l * 3 + 1) * 64,
        p2m_w + (l * 3 + 2) * 4096, p2m_b + (l * 3 + 2) * 64,
        Qm, Km, Vtm,
        x_prot, agg_prot, gp_w1 + l * 4096, gp_b1 + l * 64, gp_w2 + l * 4096, gp_b2 + l * 64, h_prot,
        p2m_w + (l * 3 + 0) * 4096, p2m_b + (l * 3 + 0) * 64,
        m2p_w + (l * 3 + 1) * 4096, m2p_b + (l * 3 + 1) * 64,
        m2p_w + (l * 3 + 2) * 4096, m2p_b + (l * 3 + 2) * 64,
        Qp, Kp, Vtp);
    attn_split_kernel<<<dim3(96, 4, NSPLIT), 256, 0, stream>>>(
        Qm, Kp, Vtp, OPm, LPm, Qp, Km, Vtm, OPp, LPp);
    ln_combine_dual<<<(NM + NP) * 64 / 256, 256, 0, stream>>>(
        h_mol, OPm, LPm, lnm_g + l * 64, lnm_b + l * 64, x_mol,
        h_prot, OPp, LPp, lnp_g + l * 64, lnp_b + l * 64, x_prot);
  }

  (void)hipMemsetAsync(pool, 0, (32 * 128 + 64) * 4, stream);
  pool_run_kernel<<<48, 256, 0, stream>>>(x_mol, mol_batch, x_prot, prot_batch, pool, cnt);
  final_kernel<<<1, 256, 0, stream>>>(pool, cnt, fc1_w, fc1_b, fc2_w, fc2_b, (float*)d_out);
}

// Round 15
// 506.232 us; speedup vs baseline: 1.6020x; 1.1682x over previous
//
#include <hip/hip_runtime.h>
#include <cstddef>

typedef _Float16 f16x4 __attribute__((ext_vector_type(4)));
typedef __fp16 h16x2 __attribute__((ext_vector_type(2)));
typedef float f32x4 __attribute__((ext_vector_type(4)));

__device__ __forceinline__ f32x4 mfma16(f16x4 a, f16x4 b, f32x4 c) {
  return __builtin_amdgcn_mfma_f32_16x16x16f16(a, b, c, 0, 0, 0);
}

// raw v_exp_f32 (2^x). OCML exp2f wraps it in denormal fixup we don't need.
__device__ __forceinline__ float fast_exp2(float x) {
#if __has_builtin(__builtin_amdgcn_exp2f)
  return __builtin_amdgcn_exp2f(x);
#else
  return exp2f(x);
#endif
}

// Q is pre-scaled by 0.25 * log2(e) so softmax weights are exp2(score).
#define QSCALE (0.25f * 1.44269504f)
#define NSPLIT 4
#define NMC 4096
#define NPC 8192
#define EMC 65536
#define EPC 262144
#define NTOT (NMC + NPC)      // 12288 combined nodes (prot offset by NMC)
#define ETOT (EMC + EPC)      // 327680 combined edges

// ---------------------------------------------------------------------------
// init node embedding, both graphs
// ---------------------------------------------------------------------------
__global__ __launch_bounds__(256) void init_embed_dual(
    const float* __restrict__ inm, const float* __restrict__ Wm,
    const float* __restrict__ bm, float* __restrict__ outm,
    const float* __restrict__ inp, const float* __restrict__ Wp,
    const float* __restrict__ bp, float* __restrict__ outp)
{
  int idx = blockIdx.x * 256 + threadIdx.x;
  const float *in, *W, *bb;
  float* out;
  int Kin;
  if (idx < NMC * 64) {
    in = inm; W = Wm; bb = bm; out = outm; Kin = 11;
  } else {
    idx -= NMC * 64;
    if (idx >= NPC * 64) return;
    in = inp; W = Wp; bb = bp; out = outp; Kin = 15;
  }
  int n = idx >> 6, o = idx & 63;
  float acc = bb[o];
  const float* row = in + (size_t)n * Kin;
  for (int k = 0; k < Kin; k++) acc += row[k] * W[k * 64 + o];
  out[idx] = acc;
}

// ===========================================================================
// CSR construction (once per call). Combined node space: mol [0,NM),
// prot [NM, NM+NP). Mol edges fill slots [0,EMC) since all mol dsts < NMC.
// ===========================================================================
__global__ __launch_bounds__(256) void deg_hist_kernel(
    const int* __restrict__ eim, const int* __restrict__ eip, int* __restrict__ deg)
{
  int idx = blockIdx.x * 256 + threadIdx.x;
  if (idx >= ETOT) return;
  int dst = (idx < EMC) ? eim[EMC + idx] : (eip[EPC + (idx - EMC)] + NMC);
  atomicAdd(&deg[dst], 1);
}

// one block, 1024 threads, 12 elems each: exclusive scan of deg -> rowStart,
// cursor; rowStart[NTOT] = total.
__global__ __launch_bounds__(1024) void scan_kernel(
    const int* __restrict__ deg, int* __restrict__ rowStart, int* __restrict__ cursor)
{
  __shared__ int part[1024];
  int t = threadIdx.x;
  int base = t * 12;
  int local[12];
  int s = 0;
  #pragma unroll
  for (int i = 0; i < 12; i++) { local[i] = s; s += deg[base + i]; }
  part[t] = s;
  __syncthreads();
  #pragma unroll
  for (int d = 1; d < 1024; d <<= 1) {
    int v = (t >= d) ? part[t - d] : 0;
    __syncthreads();
    part[t] += v;
    __syncthreads();
  }
  int prefix = (t == 0) ? 0 : part[t - 1];
  #pragma unroll
  for (int i = 0; i < 12; i++) {
    int v = prefix + local[i];
    rowStart[base + i] = v;
    cursor[base + i] = v;
  }
  if (t == 1023) rowStart[NTOT] = prefix + s;
}

// fill CSR slots; records slotOf[edge] for the attr permute.
__global__ __launch_bounds__(256) void fill_kernel(
    const int* __restrict__ eim, const int* __restrict__ eip,
    int* __restrict__ cursor, int* __restrict__ srcPerm, int* __restrict__ slotOf)
{
  int idx = blockIdx.x * 256 + threadIdx.x;
  if (idx >= ETOT) return;
  int src, dst;
  if (idx < EMC) {
    src = eim[idx]; dst = eim[EMC + idx];
  } else {
    int e = idx - EMC; src = eip[e]; dst = eip[EPC + e] + NMC;
  }
  int slot = atomicAdd(&cursor[dst], 1);
  srcPerm[slot] = src;
  slotOf[idx] = slot;
}

// permute the RAW 10-dim attr into slot order (padded to 12 floats/edge).
__global__ __launch_bounds__(256) void attr_perm_kernel(
    const int* __restrict__ slotOf,
    const float* __restrict__ attrm, const float* __restrict__ attrp,
    float* __restrict__ attrPerm)
{
  int idx = blockIdx.x * 256 + threadIdx.x;
  int e = idx >> 4, k = idx & 15;
  if (e >= ETOT || k >= 12) return;
  float v = 0.f;
  if (k < 10)
    v = (e < EMC) ? attrm[(size_t)e * 10 + k] : attrp[(size_t)(e - EMC) * 10 + k];
  attrPerm[(size_t)slotOf[e] * 12 + k] = v;
}

// materialize fp16 edge embeddings in SLOT order, 128 slots per block.
__global__ __launch_bounds__(256) void ea_lin_kernel(
    const float* __restrict__ attrPerm,
    const float* __restrict__ Wem, const float* __restrict__ bem,
    const float* __restrict__ Wep, const float* __restrict__ bep,
    _Float16* __restrict__ eaPerm)
{
  __shared__ __align__(16) float sAttr[128 * 12];
  __shared__ float sWe[10 * 64];
  __shared__ float sBe[64];
  int t = threadIdx.x;
  int s0 = blockIdx.x * 128;
  const float* We = (s0 < EMC) ? Wem : Wep;
  const float* be = (s0 < EMC) ? bem : bep;
  #pragma unroll
  for (int i = 0; i < 6; i++) {
    int f = t + i * 256;
    sAttr[f] = attrPerm[(size_t)s0 * 12 + f];
  }
  for (int f = t; f < 640; f += 256) sWe[f] = We[f];
  if (t < 64) sBe[t] = be[t];
  __syncthreads();
  int sl = t >> 1;
  int d0 = (t & 1) * 32;
  float at[10];
  #pragma unroll
  for (int k = 0; k < 10; k++) at[k] = sAttr[sl * 12 + k];
  _Float16 outv[32];
  #pragma unroll
  for (int j = 0; j < 32; j++) {
    int d = d0 + j;
    float ea = sBe[d];
    #pragma unroll
    for (int k = 0; k < 10; k++) ea += at[k] * sWe[k * 64 + d];
    outv[j] = (_Float16)ea;
  }
  float4* dst = (float4*)(eaPerm + (size_t)(s0 + sl) * 64 + d0);
  const float4* src = (const float4*)outv;
  #pragma unroll
  for (int j = 0; j < 4; j++) dst[j] = src[j];
}

// ---------------------------------------------------------------------------
// GINE aggregation via CSR gather: one wave per node, lane = dim.
// ---------------------------------------------------------------------------
__global__ __launch_bounds__(256) void gine_gather_kernel(
    const float* __restrict__ xm, const float* __restrict__ xp,
    const int* __restrict__ rowStart, const int* __restrict__ srcPerm,
    const _Float16* __restrict__ eaPerm,
    float* __restrict__ aggm, float* __restrict__ aggp)
{
  int n = (blockIdx.x * 256 + threadIdx.x) >> 6;
  int lane = threadIdx.x & 63;
  if (n >= NTOT) return;
  const float* x;
  float* agg;
  int nl;
  if (n < NMC) { x = xm; agg = aggm; nl = n; }
  else         { x = xp; agg = aggp; nl = n - NMC; }
  int b0 = rowStart[n], b1 = rowStart[n + 1];
  float acc = 0.f;
  int i = b0;
  for (; i + 3 < b1; i += 4) {
    int s0 = srcPerm[i], s1 = srcPerm[i + 1], s2 = srcPerm[i + 2], s3 = srcPerm[i + 3];
    float e0 = (float)eaPerm[(size_t)i * 64 + lane];
    float e1 = (float)eaPerm[(size_t)(i + 1) * 64 + lane];
    float e2 = (float)eaPerm[(size_t)(i + 2) * 64 + lane];
    float e3 = (float)eaPerm[(size_t)(i + 3) * 64 + lane];
    float x0 = x[(size_t)s0 * 64 + lane];
    float x1 = x[(size_t)s1 * 64 + lane];
    float x2 = x[(size_t)s2 * 64 + lane];
    float x3 = x[(size_t)s3 * 64 + lane];
    acc += fmaxf(x0 + e0, 0.f) + fmaxf(x1 + e1, 0.f)
         + fmaxf(x2 + e2, 0.f) + fmaxf(x3 + e3, 0.f);
  }
  for (; i < b1; i++) {
    int src = srcPerm[i];
    float m = x[(size_t)src * 64 + lane] + (float)eaPerm[(size_t)i * 64 + lane];
    acc += fmaxf(m, 0.f);
  }
  agg[(size_t)nl * 64 + lane] = acc;
}

// ---------------------------------------------------------------------------
// Fused GINE node MLP + QKV projection via MFMA, both graphs.
// Per 64-node tile: 5 GEMMs (W1,W2,Wq,Wk,Wv), each 16 mfma_16x16x16_f16
// per wave (wave w owns output dims w*16..w*16+15 = head w for Q/K/V).
// A = node tile f16 (LDS stride 68), B = transposed weights sWt[n][k]
// (contiguous 8B B-frags). Intermediates ping-pong sA/sB; h also stored
// f32 to global for the LN residual. blocks [0,64) mol, [64,192) prot.
// ---------------------------------------------------------------------------
__global__ __launch_bounds__(256) void mlp_proj_dual(
    const float* __restrict__ xm, const float* __restrict__ aggm,
    const float* __restrict__ W1m, const float* __restrict__ B1m,
    const float* __restrict__ W2m, const float* __restrict__ B2m,
    float* __restrict__ hm,
    const float* __restrict__ Wqm, const float* __restrict__ bqm,
    const float* __restrict__ Wkm, const float* __restrict__ bkm,
    const float* __restrict__ Wvm, const float* __restrict__ bvm,
    _Float16* __restrict__ Qom, _Float16* __restrict__ Kom, _Float16* __restrict__ Vtom,
    const float* __restrict__ xp, const float* __restrict__ aggp,
    const float* __restrict__ W1p, const float* __restrict__ B1p,
    const float* __restrict__ W2p, const float* __restrict__ B2p,
    float* __restrict__ hp,
    const float* __restrict__ Wqp, const float* __restrict__ bqp,
    const float* __restrict__ Wkp, const float* __restrict__ bkp,
    const float* __restrict__ Wvp, const float* __restrict__ bvp,
    _Float16* __restrict__ Qop, _Float16* __restrict__ Kop, _Float16* __restrict__ Vtop)
{
  __shared__ __align__(16) _Float16 sA[64 * 68];
  __shared__ __align__(16) _Float16 sB[64 * 68];
  __shared__ __align__(16) _Float16 sWt[64 * 68];
  __shared__ float sBias[64];
  int t = threadIdx.x;
  int b = blockIdx.x;
  const float *x, *agg, *W1, *B1, *W2, *B2, *Wq, *bq, *Wk, *bk, *Wv, *bv;
  float* hg;
  _Float16 *Qo, *Ko, *Vto;
  int n0, N;
  if (b < 64) {
    x = xm; agg = aggm; W1 = W1m; B1 = B1m; W2 = W2m; B2 = B2m; hg = hm;
    Wq = Wqm; bq = bqm; Wk = Wkm; bk = bkm; Wv = Wvm; bv = bvm;
    Qo = Qom; Ko = Kom; Vto = Vtom; n0 = b * 64; N = NMC;
  } else {
    x = xp; agg = aggp; W1 = W1p; B1 = B1p; W2 = W2p; B2 = B2p; hg = hp;
    Wq = Wqp; bq = bqp; Wk = Wkp; bk = bkp; Wv = Wvp; bv = bvp;
    Qo = Qop; Ko = Kop; Vto = Vtop; n0 = (b - 64) * 64; N = NPC;
  }
  const int wave = t >> 6, lane = t & 63;
  const int l16 = lane & 15, quad = lane >> 4;

  auto stageW = [&](const float* W, const float* bias) {
    #pragma unroll
    for (int i = 0; i < 16; i++) {
      int f = t + i * 256;
      sWt[(f & 63) * 68 + (f >> 6)] = (_Float16)W[f];   // transposed
    }
    if (t < 64) sBias[t] = bias[t];
  };

  f32x4 acc[4];
  auto gemm = [&](const _Float16* src) {
    #pragma unroll
    for (int mt = 0; mt < 4; mt++) acc[mt] = (f32x4){0.f, 0.f, 0.f, 0.f};
    #pragma unroll
    for (int ks = 0; ks < 4; ks++) {
      f16x4 bf = *(const f16x4*)(sWt + (wave * 16 + l16) * 68 + ks * 16 + quad * 4);
      #pragma unroll
      for (int mt = 0; mt < 4; mt++) {
        f16x4 af = *(const f16x4*)(src + (mt * 16 + l16) * 68 + ks * 16 + quad * 4);
        acc[mt] = mfma16(af, bf, acc[mt]);
      }
    }
  };

  // stage input tile (x+agg, f32->f16) + W1
  #pragma unroll
  for (int i = 0; i < 16; i++) {
    int f = t + i * 256;
    size_t g = (size_t)n0 * 64 + f;
    sA[(f >> 6) * 68 + (f & 63)] = (_Float16)(x[g] + agg[g]);
  }
  stageW(W1, B1);
  __syncthreads();

  int od = wave * 16 + l16;   // this lane's output dim (= head*16+d for QKV)

  // phase 1: hidden = relu(in @ W1 + B1) -> sB
  {
    float bias = sBias[od];
    gemm(sA);
    __syncthreads();
    #pragma unroll
    for (int mt = 0; mt < 4; mt++)
      #pragma unroll
      for (int r = 0; r < 4; r++) {
        int node = mt * 16 + quad * 4 + r;
        sB[node * 68 + od] = (_Float16)fmaxf(acc[mt][r] + bias, 0.f);
      }
    stageW(W2, B2);
    __syncthreads();
  }
  // phase 2: h = relu(hidden @ W2 + B2) -> global f32 + sA
  {
    float bias = sBias[od];
    gemm(sB);
    __syncthreads();
    #pragma unroll
    for (int mt = 0; mt < 4; mt++)
      #pragma unroll
      for (int r = 0; r < 4; r++) {
        int node = mt * 16 + quad * 4 + r;
        float v = fmaxf(acc[mt][r] + bias, 0.f);
        hg[(size_t)(n0 + node) * 64 + od] = v;
        sA[node * 68 + od] = (_Float16)v;
      }
    stageW(Wq, bq);
    __syncthreads();
  }
  // phase 3: Q = (h @ Wq + bq) * QSCALE -> fp16 [head=wave][n][16]
  {
    float bias = sBias[od];
    gemm(sA);
    __syncthreads();
    #pragma unroll
    for (int mt = 0; mt < 4; mt++)
      #pragma unroll
      for (int r = 0; r < 4; r++) {
        int node = mt * 16 + quad * 4 + r;
        Qo[((size_t)wave * N + n0 + node) * 16 + l16] =
            (_Float16)((acc[mt][r] + bias) * QSCALE);
      }
    stageW(Wk, bk);
    __syncthreads();
  }
  // phase 4: K = h @ Wk + bk -> fp16 [head][n][16]
  {
    float bias = sBias[od];
    gemm(sA);
    __syncthreads();
    #pragma unroll
    for (int mt = 0; mt < 4; mt++)
      #pragma unroll
      for (int r = 0; r < 4; r++) {
        int node = mt * 16 + quad * 4 + r;
        Ko[((size_t)wave * N + n0 + node) * 16 + l16] = (_Float16)(acc[mt][r] + bias);
      }
    stageW(Wv, bv);
    __syncthreads();
  }
  // phase 5: Vt = (h @ Wv + bv)^T -> fp16 [head][16][N]; 4 consecutive
  // nodes per (mt) pack into one 8B store.
  {
    float bias = sBias[od];
    gemm(sA);
    #pragma unroll
    for (int mt = 0; mt < 4; mt++) {
      f16x4 pk;
      #pragma unroll
      for (int r = 0; r < 4; r++) pk[r] = (_Float16)(acc[mt][r] + bias);
      *(f16x4*)(Vto + ((size_t)wave * 16 + l16) * N + n0 + mt * 16 + quad * 4) = pk;
    }
  }
}

// ---------------------------------------------------------------------------
// Key-split MFMA cross-attention, 2x software-pipelined K-loop.
// fdot2-L (no spills), raw exp2, no clamp.
// ---------------------------------------------------------------------------
__global__ __launch_bounds__(256, 4) void attn_split_kernel(
    const _Float16* __restrict__ Qm, const _Float16* __restrict__ Kp,
    const _Float16* __restrict__ Vtp, float* __restrict__ OPm, float* __restrict__ LPm,
    const _Float16* __restrict__ Qp, const _Float16* __restrict__ Km,
    const _Float16* __restrict__ Vtm, float* __restrict__ OPp, float* __restrict__ LPp)
{
  const int bx = blockIdx.x;
  const _Float16 *Q, *K, *Vt;
  float *Opart, *Lpart;
  int Nq, Nk, qb;
  if (bx < 32) { Q = Qm; K = Kp; Vt = Vtp; Opart = OPm; Lpart = LPm; Nq = NMC; Nk = NPC; qb = bx; }
  else         { Q = Qp; K = Km; Vt = Vtm; Opart = OPp; Lpart = LPp; Nq = NPC; Nk = NMC; qb = bx - 32; }
  const int h = blockIdx.y;
  const int split = blockIdx.z;
  const int Ks = Nk / NSPLIT;
  const int q0 = qb * 128;
  const int t = threadIdx.x;
  const int wave = t >> 6, lane = t & 63;
  const int l16 = lane & 15, quad = lane >> 4;

  f16x4 qf[8];
  #pragma unroll
  for (int g = 0; g < 8; g++)
    qf[g] = *(const f16x4*)(Q + ((size_t)h * Nq + q0 + g * 16 + l16) * 16 + quad * 4);
  const _Float16* Kh = K + (size_t)h * Nk * 16;
  const _Float16* Vh = Vt + ((size_t)h * 16 + l16) * Nk;

  f32x4 oacc[8];
  float lacc[8];
  #pragma unroll
  for (int g = 0; g < 8; g++) { oacc[g] = (f32x4){0.f,0.f,0.f,0.f}; lacc[g] = 0.f; }
  const f32x4 zero = {0.f, 0.f, 0.f, 0.f};
  const h16x2 ones2 = {(__fp16)1.f, (__fp16)1.f};

  union PF { f16x4 v4; h16x2 h2[2]; };

  auto process = [&](const f16x4* kf, const f16x4* vf) {
    #pragma unroll
    for (int g = 0; g < 8; g++) {
      f32x4 s[4];
      #pragma unroll
      for (int c = 0; c < 4; c++) s[c] = mfma16(kf[c], qf[g], zero);
      f16x4 pf[4];
      #pragma unroll
      for (int c = 0; c < 4; c++) {
        float p0 = fast_exp2(s[c][0]);
        float p1 = fast_exp2(s[c][1]);
        float p2 = fast_exp2(s[c][2]);
        float p3 = fast_exp2(s[c][3]);
        PF u;
        u.h2[0] = __builtin_amdgcn_cvt_pkrtz(p0, p1);
        u.h2[1] = __builtin_amdgcn_cvt_pkrtz(p2, p3);
        pf[c] = u.v4;
        lacc[g] = __builtin_amdgcn_fdot2(u.h2[0], ones2, lacc[g], false);
        lacc[g] = __builtin_amdgcn_fdot2(u.h2[1], ones2, lacc[g], false);
      }
      #pragma unroll
      for (int c = 0; c < 4; c++) oacc[g] = mfma16(vf[c], pf[c], oacc[g]);
    }
  };

  const int kend = (split + 1) * Ks;
  int kb = split * Ks + wave * 64;
  for (; kb + 256 < kend; kb += 512) {
    f16x4 kfA[4], vfA[4], kfB[4], vfB[4];
    #pragma unroll
    for (int c = 0; c < 4; c++) {
      kfA[c] = *(const f16x4*)(Kh + (size_t)(kb + c * 16 + l16) * 16 + quad * 4);
      vfA[c] = *(const f16x4*)(Vh + kb + c * 16 + quad * 4);
    }
    #pragma unroll
    for (int c = 0; c < 4; c++) {
      kfB[c] = *(const f16x4*)(Kh + (size_t)(kb + 256 + c * 16 + l16) * 16 + quad * 4);
      vfB[c] = *(const f16x4*)(Vh + kb + 256 + c * 16 + quad * 4);
    }
    process(kfA, vfA);
    process(kfB, vfB);
  }
  for (; kb < kend; kb += 256) {
    f16x4 kf[4], vf[4];
    #pragma unroll
    for (int c = 0; c < 4; c++) {
      kf[c] = *(const f16x4*)(Kh + (size_t)(kb + c * 16 + l16) * 16 + quad * 4);
      vf[c] = *(const f16x4*)(Vh + kb + c * 16 + quad * 4);
    }
    process(kf, vf);
  }

  // quad-reduce L within wave
  #pragma unroll
  for (int g = 0; g < 8; g++) {
    lacc[g] += __shfl_xor(lacc[g], 16);
    lacc[g] += __shfl_xor(lacc[g], 32);
  }

  // two-pass cross-wave combine (padded; ~20 KB)
  __shared__ float sO[4][4][16][17];
  __shared__ float sLw[8][4][16];
  if (quad == 0) {
    #pragma unroll
    for (int g = 0; g < 8; g++) sLw[g][wave][l16] = lacc[g];
  }
  int q = t >> 4, d = t & 15;
  #pragma unroll
  for (int pass = 0; pass < 2; pass++) {
    __syncthreads();
    #pragma unroll
    for (int gg = 0; gg < 4; gg++) {
      int g = pass * 4 + gg;
      #pragma unroll
      for (int r = 0; r < 4; r++) sO[gg][wave][quad * 4 + r][l16] = oacc[g][r];
    }
    __syncthreads();
    #pragma unroll
    for (int gg = 0; gg < 4; gg++) {
      int g = pass * 4 + gg;
      float O = 0.f;
      #pragma unroll
      for (int w = 0; w < 4; w++) O += sO[gg][w][d][q];
      size_t row = (size_t)split * Nq + q0 + g * 16 + q;
      Opart[row * 64 + h * 16 + d] = O;
      if (d == 0) {
        float L = sLw[g][0][q] + sLw[g][1][q] + sLw[g][2][q] + sLw[g][3][q];
        Lpart[row * 4 + h] = L;
      }
    }
  }
}

// ---------------------------------------------------------------------------
// Fused attn-split combine + LayerNorm(h + O/L) * g + b, BOTH graphs.
// ---------------------------------------------------------------------------
__global__ __launch_bounds__(256) void ln_combine_dual(
    const float* __restrict__ hm, const float* __restrict__ Om,
    const float* __restrict__ Lm, const float* __restrict__ gm,
    const float* __restrict__ bm, float* __restrict__ outm,
    const float* __restrict__ hp, const float* __restrict__ Op,
    const float* __restrict__ Lp, const float* __restrict__ gp,
    const float* __restrict__ bp, float* __restrict__ outp)
{
  int idx = blockIdx.x * 256 + threadIdx.x;
  const float *hb, *Opart, *Lpart, *g, *bb;
  float* out;
  int N;
  int totalM = NMC * 64;
  if (idx < totalM) {
    hb = hm; Opart = Om; Lpart = Lm; g = gm; bb = bm; out = outm; N = NMC;
  } else {
    idx -= totalM;
    if (idx >= NPC * 64) return;
    hb = hp; Opart = Op; Lpart = Lp; g = gp; bb = bp; out = outp; N = NPC;
  }
  int n = idx >> 6, d = idx & 63, h = d >> 4;
  float O = 0.f, L = 0.f;
  #pragma unroll
  for (int s = 0; s < NSPLIT; s++) {
    size_t row = (size_t)s * N + n;
    O += Opart[row * 64 + d];
    L += Lpart[row * 4 + h];
  }
  float v = hb[idx] + O / L;
  float sm = v;
  #pragma unroll
  for (int o = 1; o < 64; o <<= 1) sm += __shfl_xor(sm, o);
  float mu = sm * 0.015625f;
  float c = v - mu;
  float q = c * c;
  #pragma unroll
  for (int o = 1; o < 64; o <<= 1) q += __shfl_xor(q, o);
  float var = q * 0.015625f;
  out[idx] = c * rsqrtf(var + 1e-5f) * g[d] + bb[d];
}

// ---------------------------------------------------------------------------
// Pooling via sorted-run register accumulation.
// ---------------------------------------------------------------------------
__global__ __launch_bounds__(256) void pool_run_kernel(
    const float* __restrict__ xm, const int* __restrict__ bm,
    const float* __restrict__ xp, const int* __restrict__ bp,
    float* __restrict__ sums, float* __restrict__ cnt)
{
  int wid = (blockIdx.x * 256 + threadIdx.x) >> 6;
  int lane = threadIdx.x & 63;
  const float* x;
  const int* batch;
  int n0, colOff, cntOff;
  if (wid < 64) {
    x = xm; batch = bm; n0 = wid * 64; colOff = 0; cntOff = 0;
  } else {
    wid -= 64;
    if (wid >= 128) return;
    x = xp; batch = bp; n0 = wid * 64; colOff = 64; cntOff = 32;
  }
  float acc = 0.f;
  int cur = batch[n0];
  int run = 0;
  for (int i = 0; i < 64; i++) {
    int n = n0 + i;
    int s = batch[n];
    if (s != cur) {
      atomicAdd(&sums[cur * 128 + colOff + lane], acc);
      if (lane == 0) atomicAdd(&cnt[cntOff + cur], (float)run);
      acc = 0.f; run = 0; cur = s;
    }
    acc += x[(size_t)n * 64 + lane];
    run++;
  }
  atomicAdd(&sums[cur * 128 + colOff + lane], acc);
  if (lane == 0) atomicAdd(&cnt[cntOff + cur], (float)run);
}

// ---------------------------------------------------------------------------
// final head
// ---------------------------------------------------------------------------
__global__ __launch_bounds__(256) void final_kernel(
    const float* __restrict__ sums, const float* __restrict__ cnt,
    const float* __restrict__ fc1w, const float* __restrict__ fc1b,
    const float* __restrict__ fc2w, const float* __restrict__ fc2b,
    float* __restrict__ out)
{
  __shared__ float z[32 * 128];
  __shared__ float h1[32 * 64];
  int t = threadIdx.x;
  for (int f = t; f < 32 * 128; f += 256) {
    int s = f >> 7, j = f & 127;
    float c = cnt[(j >> 6) * 32 + s];
    z[f] = sums[f] / fmaxf(c, 1.f);
  }
  __syncthreads();
  for (int f = t; f < 32 * 64; f += 256) {
    int s = f >> 6, o = f & 63;
    float acc = fc1b[o];
    for (int j = 0; j < 128; j++) acc += z[s * 128 + j] * fc1w[j * 64 + o];
    h1[f] = fmaxf(acc, 0.f);
  }
  __syncthreads();
  if (t < 32) {
    float acc = fc2b[0];
    for (int o = 0; o < 64; o++) acc += h1[t * 64 + o] * fc2w[o];
    out[t] = 1.f / (1.f + __expf(-acc));
  }
}

// ---------------------------------------------------------------------------
extern "C" void kernel_launch(void* const* d_in, const int* in_sizes, int n_in,
                              void* d_out, int out_size, void* d_ws, size_t ws_size,
                              hipStream_t stream)
{
  (void)in_sizes; (void)n_in; (void)out_size; (void)ws_size;
  const float* mol_x          = (const float*)d_in[0];
  const float* prot_x         = (const float*)d_in[1];
  const float* mol_edge_attr  = (const float*)d_in[2];
  const float* prot_edge_attr = (const float*)d_in[3];
  const float* inm_w = (const float*)d_in[4];
  const float* inm_b = (const float*)d_in[5];
  const float* inp_w = (const float*)d_in[6];
  const float* inp_b = (const float*)d_in[7];
  const float* iem_w = (const float*)d_in[8];
  const float* iem_b = (const float*)d_in[9];
  const float* iep_w = (const float*)d_in[10];
  const float* iep_b = (const float*)d_in[11];
  const float* gm_w1 = (const float*)d_in[12];
  const float* gm_b1 = (const float*)d_in[13];
  const float* gm_w2 = (const float*)d_in[14];
  const float* gm_b2 = (const float*)d_in[15];
  const float* gp_w1 = (const float*)d_in[16];
  const float* gp_b1 = (const float*)d_in[17];
  const float* gp_w2 = (const float*)d_in[18];
  const float* gp_b2 = (const float*)d_in[19];
  const float* m2p_w = (const float*)d_in[20];
  const float* m2p_b = (const float*)d_in[21];
  const float* p2m_w = (const float*)d_in[22];
  const float* p2m_b = (const float*)d_in[23];
  const float* lnm_g = (const float*)d_in[24];
  const float* lnm_b = (const float*)d_in[25];
  const float* lnp_g = (const float*)d_in[26];
  const float* lnp_b = (const float*)d_in[27];
  const float* fc1_w = (const float*)d_in[28];
  const float* fc1_b = (const float*)d_in[29];
  const float* fc2_w = (const float*)d_in[30];
  const float* fc2_b = (const float*)d_in[31];
  const int* mol_ei     = (const int*)d_in[32];
  const int* prot_ei    = (const int*)d_in[33];
  const int* mol_batch  = (const int*)d_in[34];
  const int* prot_batch = (const int*)d_in[35];

  const int NM = NMC, NP = NPC;

  float* ws = (float*)d_ws;
  size_t off = 0;
  auto nxt  = [&](size_t n) { float* p = ws + off; off += n; return p; };
  auto nxtH = [&](size_t n) { _Float16* p = (_Float16*)(ws + off); off += (n + 1) / 2; return p; };
  auto nxtI = [&](size_t n) { int* p = (int*)(ws + off); off += n; return p; };
  float* x_mol    = nxt((size_t)NM * 64);
  float* x_prot   = nxt((size_t)NP * 64);
  float* agg_mol  = nxt((size_t)NM * 64);
  float* agg_prot = nxt((size_t)NP * 64);
  float* h_mol    = nxt((size_t)NM * 64);
  float* h_prot   = nxt((size_t)NP * 64);
  _Float16* Qm  = nxtH((size_t)NM * 64);
  _Float16* Km  = nxtH((size_t)NM * 64);
  _Float16* Vtm = nxtH((size_t)NM * 64);
  _Float16* Qp  = nxtH((size_t)NP * 64);
  _Float16* Kp  = nxtH((size_t)NP * 64);
  _Float16* Vtp = nxtH((size_t)NP * 64);
  float* OPm = nxt((size_t)NSPLIT * NM * 64);
  float* LPm = nxt((size_t)NSPLIT * NM * 4);
  float* OPp = nxt((size_t)NSPLIT * NP * 64);
  float* LPp = nxt((size_t)NSPLIT * NP * 4);
  float* pool = nxt(32 * 128);
  float* cnt  = nxt(64);
  int* deg      = nxtI(NTOT);
  int* rowStart = nxtI(NTOT + 1);
  int* cursor   = nxtI(NTOT);
  int* slotOf   = nxtI(ETOT);
  int* srcPerm  = nxtI(ETOT);
  float* attrPerm = nxt((size_t)ETOT * 12);
  _Float16* eaPerm = nxtH((size_t)ETOT * 64);

  // ---- CSR + edge-embedding setup (once per call) ----
  (void)hipMemsetAsync(deg, 0, NTOT * 4, stream);
  deg_hist_kernel<<<(ETOT + 255) / 256, 256, 0, stream>>>(mol_ei, prot_ei, deg);
  scan_kernel<<<1, 1024, 0, stream>>>(deg, rowStart, cursor);
  fill_kernel<<<(ETOT + 255) / 256, 256, 0, stream>>>(mol_ei, prot_ei, cursor, srcPerm, slotOf);
  attr_perm_kernel<<<ETOT * 16 / 256, 256, 0, stream>>>(slotOf, mol_edge_attr,
                                                        prot_edge_attr, attrPerm);
  ea_lin_kernel<<<ETOT / 128, 256, 0, stream>>>(attrPerm, iem_w, iem_b, iep_w, iep_b, eaPerm);

  init_embed_dual<<<(NM + NP) * 64 / 256, 256, 0, stream>>>(
      mol_x, inm_w, inm_b, x_mol, prot_x, inp_w, inp_b, x_prot);

  for (int l = 0; l < 3; l++) {
    gine_gather_kernel<<<NTOT / 4, 256, 0, stream>>>(x_mol, x_prot, rowStart, srcPerm,
                                                     eaPerm, agg_mol, agg_prot);
    // m2p: Q=mol (m2p W0), K/V=prot (m2p W1,W2); p2m: Q=prot (p2m W0), K/V=mol (p2m W1,W2)
    mlp_proj_dual<<<192, 256, 0, stream>>>(
        x_mol, agg_mol, gm_w1 + l * 4096, gm_b1 + l * 64, gm_w2 + l * 4096, gm_b2 + l * 64, h_mol,
        m2p_w + (l * 3 + 0) * 4096, m2p_b + (l * 3 + 0) * 64,
        p2m_w + (l * 3 + 1) * 4096, p2m_b + (l * 3 + 1) * 64,
        p2m_w + (l * 3 + 2) * 4096, p2m_b + (l * 3 + 2) * 64,
        Qm, Km, Vtm,
        x_prot, agg_prot, gp_w1 + l * 4096, gp_b1 + l * 64, gp_w2 + l * 4096, gp_b2 + l * 64, h_prot,
        p2m_w + (l * 3 + 0) * 4096, p2m_b + (l * 3 + 0) * 64,
        m2p_w + (l * 3 + 1) * 4096, m2p_b + (l * 3 + 1) * 64,
        m2p_w + (l * 3 + 2) * 4096, m2p_b + (l * 3 + 2) * 64,
        Qp, Kp, Vtp);
    attn_split_kernel<<<dim3(96, 4, NSPLIT), 256, 0, stream>>>(
        Qm, Kp, Vtp, OPm, LPm, Qp, Km, Vtm, OPp, LPp);
    ln_combine_dual<<<(NM + NP) * 64 / 256, 256, 0, stream>>>(
        h_mol, OPm, LPm, lnm_g + l * 64, lnm_b + l * 64, x_mol,
        h_prot, OPp, LPp, lnp_g + l * 64, lnp_b + l * 64, x_prot);
  }

  (void)hipMemsetAsync(pool, 0, (32 * 128 + 64) * 4, stream);
  pool_run_kernel<<<48, 256, 0, stream>>>(x_mol, mol_batch, x_prot, prot_batch, pool, cnt);
  final_kernel<<<1, 256, 0, stream>>>(pool, cnt, fc1_w, fc1_b, fc2_w, fc2_b, (float*)d_out);
}

// Round 16
// 482.421 us; speedup vs baseline: 1.6811x; 1.0494x over previous
//
#include <hip/hip_runtime.h>
#include <cstddef>

typedef _Float16 f16x4 __attribute__((ext_vector_type(4)));
typedef __fp16 h16x2 __attribute__((ext_vector_type(2)));
typedef float f32x4 __attribute__((ext_vector_type(4)));

__device__ __forceinline__ f32x4 mfma16(f16x4 a, f16x4 b, f32x4 c) {
  return __builtin_amdgcn_mfma_f32_16x16x16f16(a, b, c, 0, 0, 0);
}

// raw v_exp_f32 (2^x). OCML exp2f wraps it in denormal fixup we don't need.
__device__ __forceinline__ float fast_exp2(float x) {
#if __has_builtin(__builtin_amdgcn_exp2f)
  return __builtin_amdgcn_exp2f(x);
#else
  return exp2f(x);
#endif
}

// Q is pre-scaled by 0.25 * log2(e) so softmax weights are exp2(score).
#define QSCALE (0.25f * 1.44269504f)
#define SPLIT_M2P 8
#define SPLIT_P2M 4
#define NMC 4096
#define NPC 8192
#define EMC 65536
#define EPC 262144
#define NTOT (NMC + NPC)      // 12288 combined nodes (prot offset by NMC)
#define ETOT (EMC + EPC)      // 327680 combined edges

// ---------------------------------------------------------------------------
// init node embedding, both graphs
// ---------------------------------------------------------------------------
__global__ __launch_bounds__(256) void init_embed_dual(
    const float* __restrict__ inm, const float* __restrict__ Wm,
    const float* __restrict__ bm, float* __restrict__ outm,
    const float* __restrict__ inp, const float* __restrict__ Wp,
    const float* __restrict__ bp, float* __restrict__ outp)
{
  int idx = blockIdx.x * 256 + threadIdx.x;
  const float *in, *W, *bb;
  float* out;
  int Kin;
  if (idx < NMC * 64) {
    in = inm; W = Wm; bb = bm; out = outm; Kin = 11;
  } else {
    idx -= NMC * 64;
    if (idx >= NPC * 64) return;
    in = inp; W = Wp; bb = bp; out = outp; Kin = 15;
  }
  int n = idx >> 6, o = idx & 63;
  float acc = bb[o];
  const float* row = in + (size_t)n * Kin;
  for (int k = 0; k < Kin; k++) acc += row[k] * W[k * 64 + o];
  out[idx] = acc;
}

// ===========================================================================
// CSR construction (once per call).
// ===========================================================================
__global__ __launch_bounds__(256) void deg_hist_kernel(
    const int* __restrict__ eim, const int* __restrict__ eip, int* __restrict__ deg)
{
  int idx = blockIdx.x * 256 + threadIdx.x;
  if (idx >= ETOT) return;
  int dst = (idx < EMC) ? eim[EMC + idx] : (eip[EPC + (idx - EMC)] + NMC);
  atomicAdd(&deg[dst], 1);
}

__global__ __launch_bounds__(1024) void scan_kernel(
    const int* __restrict__ deg, int* __restrict__ rowStart, int* __restrict__ cursor)
{
  __shared__ int part[1024];
  int t = threadIdx.x;
  int base = t * 12;
  int local[12];
  int s = 0;
  #pragma unroll
  for (int i = 0; i < 12; i++) { local[i] = s; s += deg[base + i]; }
  part[t] = s;
  __syncthreads();
  #pragma unroll
  for (int d = 1; d < 1024; d <<= 1) {
    int v = (t >= d) ? part[t - d] : 0;
    __syncthreads();
    part[t] += v;
    __syncthreads();
  }
  int prefix = (t == 0) ? 0 : part[t - 1];
  #pragma unroll
  for (int i = 0; i < 12; i++) {
    int v = prefix + local[i];
    rowStart[base + i] = v;
    cursor[base + i] = v;
  }
  if (t == 1023) rowStart[NTOT] = prefix + s;
}

__global__ __launch_bounds__(256) void fill_kernel(
    const int* __restrict__ eim, const int* __restrict__ eip,
    int* __restrict__ cursor, int* __restrict__ srcPerm, int* __restrict__ slotOf)
{
  int idx = blockIdx.x * 256 + threadIdx.x;
  if (idx >= ETOT) return;
  int src, dst;
  if (idx < EMC) {
    src = eim[idx]; dst = eim[EMC + idx];
  } else {
    int e = idx - EMC; src = eip[e]; dst = eip[EPC + e] + NMC;
  }
  int slot = atomicAdd(&cursor[dst], 1);
  srcPerm[slot] = src;
  slotOf[idx] = slot;
}

__global__ __launch_bounds__(256) void attr_perm_kernel(
    const int* __restrict__ slotOf,
    const float* __restrict__ attrm, const float* __restrict__ attrp,
    float* __restrict__ attrPerm)
{
  int idx = blockIdx.x * 256 + threadIdx.x;
  int e = idx >> 4, k = idx & 15;
  if (e >= ETOT || k >= 12) return;
  float v = 0.f;
  if (k < 10)
    v = (e < EMC) ? attrm[(size_t)e * 10 + k] : attrp[(size_t)(e - EMC) * 10 + k];
  attrPerm[(size_t)slotOf[e] * 12 + k] = v;
}

// materialize fp16 edge embeddings in SLOT order, 128 slots per block.
__global__ __launch_bounds__(256) void ea_lin_kernel(
    const float* __restrict__ attrPerm,
    const float* __restrict__ Wem, const float* __restrict__ bem,
    const float* __restrict__ Wep, const float* __restrict__ bep,
    _Float16* __restrict__ eaPerm)
{
  __shared__ __align__(16) float sAttr[128 * 12];
  __shared__ float sWe[10 * 64];
  __shared__ float sBe[64];
  int t = threadIdx.x;
  int s0 = blockIdx.x * 128;
  const float* We = (s0 < EMC) ? Wem : Wep;
  const float* be = (s0 < EMC) ? bem : bep;
  #pragma unroll
  for (int i = 0; i < 6; i++) {
    int f = t + i * 256;
    sAttr[f] = attrPerm[(size_t)s0 * 12 + f];
  }
  for (int f = t; f < 640; f += 256) sWe[f] = We[f];
  if (t < 64) sBe[t] = be[t];
  __syncthreads();
  int sl = t >> 1;
  int d0 = (t & 1) * 32;
  float at[10];
  #pragma unroll
  for (int k = 0; k < 10; k++) at[k] = sAttr[sl * 12 + k];
  _Float16 outv[32];
  #pragma unroll
  for (int j = 0; j < 32; j++) {
    int d = d0 + j;
    float ea = sBe[d];
    #pragma unroll
    for (int k = 0; k < 10; k++) ea += at[k] * sWe[k * 64 + d];
    outv[j] = (_Float16)ea;
  }
  float4* dst = (float4*)(eaPerm + (size_t)(s0 + sl) * 64 + d0);
  const float4* src = (const float4*)outv;
  #pragma unroll
  for (int j = 0; j < 4; j++) dst[j] = src[j];
}

// ---------------------------------------------------------------------------
// GINE aggregation via CSR gather: one wave per node, lane = dim.
// ---------------------------------------------------------------------------
__global__ __launch_bounds__(256) void gine_gather_kernel(
    const float* __restrict__ xm, const float* __restrict__ xp,
    const int* __restrict__ rowStart, const int* __restrict__ srcPerm,
    const _Float16* __restrict__ eaPerm,
    float* __restrict__ aggm, float* __restrict__ aggp)
{
  int n = (blockIdx.x * 256 + threadIdx.x) >> 6;
  int lane = threadIdx.x & 63;
  if (n >= NTOT) return;
  const float* x;
  float* agg;
  int nl;
  if (n < NMC) { x = xm; agg = aggm; nl = n; }
  else         { x = xp; agg = aggp; nl = n - NMC; }
  int b0 = rowStart[n], b1 = rowStart[n + 1];
  float acc = 0.f;
  int i = b0;
  for (; i + 3 < b1; i += 4) {
    int s0 = srcPerm[i], s1 = srcPerm[i + 1], s2 = srcPerm[i + 2], s3 = srcPerm[i + 3];
    float e0 = (float)eaPerm[(size_t)i * 64 + lane];
    float e1 = (float)eaPerm[(size_t)(i + 1) * 64 + lane];
    float e2 = (float)eaPerm[(size_t)(i + 2) * 64 + lane];
    float e3 = (float)eaPerm[(size_t)(i + 3) * 64 + lane];
    float x0 = x[(size_t)s0 * 64 + lane];
    float x1 = x[(size_t)s1 * 64 + lane];
    float x2 = x[(size_t)s2 * 64 + lane];
    float x3 = x[(size_t)s3 * 64 + lane];
    acc += fmaxf(x0 + e0, 0.f) + fmaxf(x1 + e1, 0.f)
         + fmaxf(x2 + e2, 0.f) + fmaxf(x3 + e3, 0.f);
  }
  for (; i < b1; i++) {
    int src = srcPerm[i];
    float m = x[(size_t)src * 64 + lane] + (float)eaPerm[(size_t)i * 64 + lane];
    acc += fmaxf(m, 0.f);
  }
  agg[(size_t)nl * 64 + lane] = acc;
}

// ---------------------------------------------------------------------------
// Fused GINE node MLP + QKV projection via MFMA, both graphs.
// ---------------------------------------------------------------------------
__global__ __launch_bounds__(256) void mlp_proj_dual(
    const float* __restrict__ xm, const float* __restrict__ aggm,
    const float* __restrict__ W1m, const float* __restrict__ B1m,
    const float* __restrict__ W2m, const float* __restrict__ B2m,
    float* __restrict__ hm,
    const float* __restrict__ Wqm, const float* __restrict__ bqm,
    const float* __restrict__ Wkm, const float* __restrict__ bkm,
    const float* __restrict__ Wvm, const float* __restrict__ bvm,
    _Float16* __restrict__ Qom, _Float16* __restrict__ Kom, _Float16* __restrict__ Vtom,
    const float* __restrict__ xp, const float* __restrict__ aggp,
    const float* __restrict__ W1p, const float* __restrict__ B1p,
    const float* __restrict__ W2p, const float* __restrict__ B2p,
    float* __restrict__ hp,
    const float* __restrict__ Wqp, const float* __restrict__ bqp,
    const float* __restrict__ Wkp, const float* __restrict__ bkp,
    const float* __restrict__ Wvp, const float* __restrict__ bvp,
    _Float16* __restrict__ Qop, _Float16* __restrict__ Kop, _Float16* __restrict__ Vtop)
{
  __shared__ __align__(16) _Float16 sA[64 * 68];
  __shared__ __align__(16) _Float16 sB[64 * 68];
  __shared__ __align__(16) _Float16 sWt[64 * 68];
  __shared__ float sBias[64];
  int t = threadIdx.x;
  int b = blockIdx.x;
  const float *x, *agg, *W1, *B1, *W2, *B2, *Wq, *bq, *Wk, *bk, *Wv, *bv;
  float* hg;
  _Float16 *Qo, *Ko, *Vto;
  int n0, N;
  if (b < 64) {
    x = xm; agg = aggm; W1 = W1m; B1 = B1m; W2 = W2m; B2 = B2m; hg = hm;
    Wq = Wqm; bq = bqm; Wk = Wkm; bk = bkm; Wv = Wvm; bv = bvm;
    Qo = Qom; Ko = Kom; Vto = Vtom; n0 = b * 64; N = NMC;
  } else {
    x = xp; agg = aggp; W1 = W1p; B1 = B1p; W2 = W2p; B2 = B2p; hg = hp;
    Wq = Wqp; bq = bqp; Wk = Wkp; bk = bkp; Wv = Wvp; bv = bvp;
    Qo = Qop; Ko = Kop; Vto = Vtop; n0 = (b - 64) * 64; N = NPC;
  }
  const int wave = t >> 6, lane = t & 63;
  const int l16 = lane & 15, quad = lane >> 4;

  auto stageW = [&](const float* W, const float* bias) {
    #pragma unroll
    for (int i = 0; i < 16; i++) {
      int f = t + i * 256;
      sWt[(f & 63) * 68 + (f >> 6)] = (_Float16)W[f];   // transposed
    }
    if (t < 64) sBias[t] = bias[t];
  };

  f32x4 acc[4];
  auto gemm = [&](const _Float16* src) {
    #pragma unroll
    for (int mt = 0; mt < 4; mt++) acc[mt] = (f32x4){0.f, 0.f, 0.f, 0.f};
    #pragma unroll
    for (int ks = 0; ks < 4; ks++) {
      f16x4 bf = *(const f16x4*)(sWt + (wave * 16 + l16) * 68 + ks * 16 + quad * 4);
      #pragma unroll
      for (int mt = 0; mt < 4; mt++) {
        f16x4 af = *(const f16x4*)(src + (mt * 16 + l16) * 68 + ks * 16 + quad * 4);
        acc[mt] = mfma16(af, bf, acc[mt]);
      }
    }
  };

  #pragma unroll
  for (int i = 0; i < 16; i++) {
    int f = t + i * 256;
    size_t g = (size_t)n0 * 64 + f;
    sA[(f >> 6) * 68 + (f & 63)] = (_Float16)(x[g] + agg[g]);
  }
  stageW(W1, B1);
  __syncthreads();

  int od = wave * 16 + l16;

  // phase 1: hidden = relu(in @ W1 + B1) -> sB
  {
    float bias = sBias[od];
    gemm(sA);
    __syncthreads();
    #pragma unroll
    for (int mt = 0; mt < 4; mt++)
      #pragma unroll
      for (int r = 0; r < 4; r++) {
        int node = mt * 16 + quad * 4 + r;
        sB[node * 68 + od] = (_Float16)fmaxf(acc[mt][r] + bias, 0.f);
      }
    stageW(W2, B2);
    __syncthreads();
  }
  // phase 2: h = relu(hidden @ W2 + B2) -> global f32 + sA
  {
    float bias = sBias[od];
    gemm(sB);
    __syncthreads();
    #pragma unroll
    for (int mt = 0; mt < 4; mt++)
      #pragma unroll
      for (int r = 0; r < 4; r++) {
        int node = mt * 16 + quad * 4 + r;
        float v = fmaxf(acc[mt][r] + bias, 0.f);
        hg[(size_t)(n0 + node) * 64 + od] = v;
        sA[node * 68 + od] = (_Float16)v;
      }
    stageW(Wq, bq);
    __syncthreads();
  }
  // phase 3: Q
  {
    float bias = sBias[od];
    gemm(sA);
    __syncthreads();
    #pragma unroll
    for (int mt = 0; mt < 4; mt++)
      #pragma unroll
      for (int r = 0; r < 4; r++) {
        int node = mt * 16 + quad * 4 + r;
        Qo[((size_t)wave * N + n0 + node) * 16 + l16] =
            (_Float16)((acc[mt][r] + bias) * QSCALE);
      }
    stageW(Wk, bk);
    __syncthreads();
  }
  // phase 4: K
  {
    float bias = sBias[od];
    gemm(sA);
    __syncthreads();
    #pragma unroll
    for (int mt = 0; mt < 4; mt++)
      #pragma unroll
      for (int r = 0; r < 4; r++) {
        int node = mt * 16 + quad * 4 + r;
        Ko[((size_t)wave * N + n0 + node) * 16 + l16] = (_Float16)(acc[mt][r] + bias);
      }
    stageW(Wv, bv);
    __syncthreads();
  }
  // phase 5: Vt
  {
    float bias = sBias[od];
    gemm(sA);
    #pragma unroll
    for (int mt = 0; mt < 4; mt++) {
      f16x4 pk;
      #pragma unroll
      for (int r = 0; r < 4; r++) pk[r] = (_Float16)(acc[mt][r] + bias);
      *(f16x4*)(Vto + ((size_t)wave * 16 + l16) * N + n0 + mt * 16 + quad * 4) = pk;
    }
  }
}

// ---------------------------------------------------------------------------
// Key-split MFMA cross-attention, balanced per-direction splits:
// m2p uses SPLIT_M2P=8 (2048 keys/8 = 256/split), p2m SPLIT_P2M=4
// (4096/4 = 1024... keys/split 1024) -> EVERY block runs exactly 4
// pipelined 256-key iterations. Grid (512, H): u<256 m2p (qb=u&31,
// split=u>>5), else p2m (qb=v&63, split=v>>6).
// ---------------------------------------------------------------------------
__global__ __launch_bounds__(256, 4) void attn_split_kernel(
    const _Float16* __restrict__ Qm, const _Float16* __restrict__ Kp,
    const _Float16* __restrict__ Vtp, float* __restrict__ OPm, float* __restrict__ LPm,
    const _Float16* __restrict__ Qp, const _Float16* __restrict__ Km,
    const _Float16* __restrict__ Vtm, float* __restrict__ OPp, float* __restrict__ LPp)
{
  const int u = blockIdx.x;
  const _Float16 *Q, *K, *Vt;
  float *Opart, *Lpart;
  int Nq, Nk, qb, split, nsplit;
  if (u < 256) {
    Q = Qm; K = Kp; Vt = Vtp; Opart = OPm; Lpart = LPm;
    Nq = NMC; Nk = NPC; qb = u & 31; split = u >> 5; nsplit = SPLIT_M2P;
  } else {
    int v = u - 256;
    Q = Qp; K = Km; Vt = Vtm; Opart = OPp; Lpart = LPp;
    Nq = NPC; Nk = NMC; qb = v & 63; split = v >> 6; nsplit = SPLIT_P2M;
  }
  const int h = blockIdx.y;
  const int Ks = Nk / nsplit;
  const int q0 = qb * 128;
  const int t = threadIdx.x;
  const int wave = t >> 6, lane = t & 63;
  const int l16 = lane & 15, quad = lane >> 4;

  f16x4 qf[8];
  #pragma unroll
  for (int g = 0; g < 8; g++)
    qf[g] = *(const f16x4*)(Q + ((size_t)h * Nq + q0 + g * 16 + l16) * 16 + quad * 4);
  const _Float16* Kh = K + (size_t)h * Nk * 16;
  const _Float16* Vh = Vt + ((size_t)h * 16 + l16) * Nk;

  f32x4 oacc[8];
  float lacc[8];
  #pragma unroll
  for (int g = 0; g < 8; g++) { oacc[g] = (f32x4){0.f,0.f,0.f,0.f}; lacc[g] = 0.f; }
  const f32x4 zero = {0.f, 0.f, 0.f, 0.f};
  const h16x2 ones2 = {(__fp16)1.f, (__fp16)1.f};

  union PF { f16x4 v4; h16x2 h2[2]; };

  auto process = [&](const f16x4* kf, const f16x4* vf) {
    #pragma unroll
    for (int g = 0; g < 8; g++) {
      f32x4 s[4];
      #pragma unroll
      for (int c = 0; c < 4; c++) s[c] = mfma16(kf[c], qf[g], zero);
      f16x4 pf[4];
      #pragma unroll
      for (int c = 0; c < 4; c++) {
        float p0 = fast_exp2(s[c][0]);
        float p1 = fast_exp2(s[c][1]);
        float p2 = fast_exp2(s[c][2]);
        float p3 = fast_exp2(s[c][3]);
        PF u2;
        u2.h2[0] = __builtin_amdgcn_cvt_pkrtz(p0, p1);
        u2.h2[1] = __builtin_amdgcn_cvt_pkrtz(p2, p3);
        pf[c] = u2.v4;
        lacc[g] = __builtin_amdgcn_fdot2(u2.h2[0], ones2, lacc[g], false);
        lacc[g] = __builtin_amdgcn_fdot2(u2.h2[1], ones2, lacc[g], false);
      }
      #pragma unroll
      for (int c = 0; c < 4; c++) oacc[g] = mfma16(vf[c], pf[c], oacc[g]);
    }
  };

  const int kend = (split + 1) * Ks;
  int kb = split * Ks + wave * 64;
  for (; kb + 256 < kend; kb += 512) {
    f16x4 kfA[4], vfA[4], kfB[4], vfB[4];
    #pragma unroll
    for (int c = 0; c < 4; c++) {
      kfA[c] = *(const f16x4*)(Kh + (size_t)(kb + c * 16 + l16) * 16 + quad * 4);
      vfA[c] = *(const f16x4*)(Vh + kb + c * 16 + quad * 4);
    }
    #pragma unroll
    for (int c = 0; c < 4; c++) {
      kfB[c] = *(const f16x4*)(Kh + (size_t)(kb + 256 + c * 16 + l16) * 16 + quad * 4);
      vfB[c] = *(const f16x4*)(Vh + kb + 256 + c * 16 + quad * 4);
    }
    process(kfA, vfA);
    process(kfB, vfB);
  }
  for (; kb < kend; kb += 256) {
    f16x4 kf[4], vf[4];
    #pragma unroll
    for (int c = 0; c < 4; c++) {
      kf[c] = *(const f16x4*)(Kh + (size_t)(kb + c * 16 + l16) * 16 + quad * 4);
      vf[c] = *(const f16x4*)(Vh + kb + c * 16 + quad * 4);
    }
    process(kf, vf);
  }

  // quad-reduce L within wave
  #pragma unroll
  for (int g = 0; g < 8; g++) {
    lacc[g] += __shfl_xor(lacc[g], 16);
    lacc[g] += __shfl_xor(lacc[g], 32);
  }

  // two-pass cross-wave combine (padded; ~20 KB)
  __shared__ float sO[4][4][16][17];
  __shared__ float sLw[8][4][16];
  if (quad == 0) {
    #pragma unroll
    for (int g = 0; g < 8; g++) sLw[g][wave][l16] = lacc[g];
  }
  int q = t >> 4, d = t & 15;
  #pragma unroll
  for (int pass = 0; pass < 2; pass++) {
    __syncthreads();
    #pragma unroll
    for (int gg = 0; gg < 4; gg++) {
      int g = pass * 4 + gg;
      #pragma unroll
      for (int r = 0; r < 4; r++) sO[gg][wave][quad * 4 + r][l16] = oacc[g][r];
    }
    __syncthreads();
    #pragma unroll
    for (int gg = 0; gg < 4; gg++) {
      int g = pass * 4 + gg;
      float O = 0.f;
      #pragma unroll
      for (int w = 0; w < 4; w++) O += sO[gg][w][d][q];
      size_t row = (size_t)split * Nq + q0 + g * 16 + q;
      Opart[row * 64 + h * 16 + d] = O;
      if (d == 0) {
        float L = sLw[g][0][q] + sLw[g][1][q] + sLw[g][2][q] + sLw[g][3][q];
        Lpart[row * 4 + h] = L;
      }
    }
  }
}

// ---------------------------------------------------------------------------
// Fused attn-split combine + LayerNorm(h + O/L) * g + b, BOTH graphs.
// mol sums SPLIT_M2P partials, prot sums SPLIT_P2M.
// ---------------------------------------------------------------------------
__global__ __launch_bounds__(256) void ln_combine_dual(
    const float* __restrict__ hm, const float* __restrict__ Om,
    const float* __restrict__ Lm, const float* __restrict__ gm,
    const float* __restrict__ bm, float* __restrict__ outm,
    const float* __restrict__ hp, const float* __restrict__ Op,
    const float* __restrict__ Lp, const float* __restrict__ gp,
    const float* __restrict__ bp, float* __restrict__ outp)
{
  int idx = blockIdx.x * 256 + threadIdx.x;
  float O = 0.f, L = 0.f;
  const float *hb, *g, *bb;
  float* out;
  int totalM = NMC * 64;
  int n, d, h;
  if (idx < totalM) {
    n = idx >> 6; d = idx & 63; h = d >> 4;
    #pragma unroll
    for (int s = 0; s < SPLIT_M2P; s++) {
      size_t row = (size_t)s * NMC + n;
      O += Om[row * 64 + d];
      L += Lm[row * 4 + h];
    }
    hb = hm; g = gm; bb = bm; out = outm;
  } else {
    idx -= totalM;
    if (idx >= NPC * 64) return;
    n = idx >> 6; d = idx & 63; h = d >> 4;
    #pragma unroll
    for (int s = 0; s < SPLIT_P2M; s++) {
      size_t row = (size_t)s * NPC + n;
      O += Op[row * 64 + d];
      L += Lp[row * 4 + h];
    }
    hb = hp; g = gp; bb = bp; out = outp;
  }
  float v = hb[idx] + O / L;
  float sm = v;
  #pragma unroll
  for (int o = 1; o < 64; o <<= 1) sm += __shfl_xor(sm, o);
  float mu = sm * 0.015625f;
  float c = v - mu;
  float q = c * c;
  #pragma unroll
  for (int o = 1; o < 64; o <<= 1) q += __shfl_xor(q, o);
  float var = q * 0.015625f;
  out[idx] = c * rsqrtf(var + 1e-5f) * g[d] + bb[d];
}

// ---------------------------------------------------------------------------
// Pooling via sorted-run register accumulation.
// ---------------------------------------------------------------------------
__global__ __launch_bounds__(256) void pool_run_kernel(
    const float* __restrict__ xm, const int* __restrict__ bm,
    const float* __restrict__ xp, const int* __restrict__ bp,
    float* __restrict__ sums, float* __restrict__ cnt)
{
  int wid = (blockIdx.x * 256 + threadIdx.x) >> 6;
  int lane = threadIdx.x & 63;
  const float* x;
  const int* batch;
  int n0, colOff, cntOff;
  if (wid < 64) {
    x = xm; batch = bm; n0 = wid * 64; colOff = 0; cntOff = 0;
  } else {
    wid -= 64;
    if (wid >= 128) return;
    x = xp; batch = bp; n0 = wid * 64; colOff = 64; cntOff = 32;
  }
  float acc = 0.f;
  int cur = batch[n0];
  int run = 0;
  for (int i = 0; i < 64; i++) {
    int n = n0 + i;
    int s = batch[n];
    if (s != cur) {
      atomicAdd(&sums[cur * 128 + colOff + lane], acc);
      if (lane == 0) atomicAdd(&cnt[cntOff + cur], (float)run);
      acc = 0.f; run = 0; cur = s;
    }
    acc += x[(size_t)n * 64 + lane];
    run++;
  }
  atomicAdd(&sums[cur * 128 + colOff + lane], acc);
  if (lane == 0) atomicAdd(&cnt[cntOff + cur], (float)run);
}

// ---------------------------------------------------------------------------
// final head
// ---------------------------------------------------------------------------
__global__ __launch_bounds__(256) void final_kernel(
    const float* __restrict__ sums, const float* __restrict__ cnt,
    const float* __restrict__ fc1w, const float* __restrict__ fc1b,
    const float* __restrict__ fc2w, const float* __restrict__ fc2b,
    float* __restrict__ out)
{
  __shared__ float z[32 * 128];
  __shared__ float h1[32 * 64];
  int t = threadIdx.x;
  for (int f = t; f < 32 * 128; f += 256) {
    int s = f >> 7, j = f & 127;
    float c = cnt[(j >> 6) * 32 + s];
    z[f] = sums[f] / fmaxf(c, 1.f);
  }
  __syncthreads();
  for (int f = t; f < 32 * 64; f += 256) {
    int s = f >> 6, o = f & 63;
    float acc = fc1b[o];
    for (int j = 0; j < 128; j++) acc += z[s * 128 + j] * fc1w[j * 64 + o];
    h1[f] = fmaxf(acc, 0.f);
  }
  __syncthreads();
  if (t < 32) {
    float acc = fc2b[0];
    for (int o = 0; o < 64; o++) acc += h1[t * 64 + o] * fc2w[o];
    out[t] = 1.f / (1.f + __expf(-acc));
  }
}

// ---------------------------------------------------------------------------
extern "C" void kernel_launch(void* const* d_in, const int* in_sizes, int n_in,
                              void* d_out, int out_size, void* d_ws, size_t ws_size,
                              hipStream_t stream)
{
  (void)in_sizes; (void)n_in; (void)out_size; (void)ws_size;
  const float* mol_x          = (const float*)d_in[0];
  const float* prot_x         = (const float*)d_in[1];
  const float* mol_edge_attr  = (const float*)d_in[2];
  const float* prot_edge_attr = (const float*)d_in[3];
  const float* inm_w = (const float*)d_in[4];
  const float* inm_b = (const float*)d_in[5];
  const float* inp_w = (const float*)d_in[6];
  const float* inp_b = (const float*)d_in[7];
  const float* iem_w = (const float*)d_in[8];
  const float* iem_b = (const float*)d_in[9];
  const float* iep_w = (const float*)d_in[10];
  const float* iep_b = (const float*)d_in[11];
  const float* gm_w1 = (const float*)d_in[12];
  const float* gm_b1 = (const float*)d_in[13];
  const float* gm_w2 = (const float*)d_in[14];
  const float* gm_b2 = (const float*)d_in[15];
  const float* gp_w1 = (const float*)d_in[16];
  const float* gp_b1 = (const float*)d_in[17];
  const float* gp_w2 = (const float*)d_in[18];
  const float* gp_b2 = (const float*)d_in[19];
  const float* m2p_w = (const float*)d_in[20];
  const float* m2p_b = (const float*)d_in[21];
  const float* p2m_w = (const float*)d_in[22];
  const float* p2m_b = (const float*)d_in[23];
  const float* lnm_g = (const float*)d_in[24];
  const float* lnm_b = (const float*)d_in[25];
  const float* lnp_g = (const float*)d_in[26];
  const float* lnp_b = (const float*)d_in[27];
  const float* fc1_w = (const float*)d_in[28];
  const float* fc1_b = (const float*)d_in[29];
  const float* fc2_w = (const float*)d_in[30];
  const float* fc2_b = (const float*)d_in[31];
  const int* mol_ei     = (const int*)d_in[32];
  const int* prot_ei    = (const int*)d_in[33];
  const int* mol_batch  = (const int*)d_in[34];
  const int* prot_batch = (const int*)d_in[35];

  const int NM = NMC, NP = NPC;

  float* ws = (float*)d_ws;
  size_t off = 0;
  auto nxt  = [&](size_t n) { float* p = ws + off; off += n; return p; };
  auto nxtH = [&](size_t n) { _Float16* p = (_Float16*)(ws + off); off += (n + 1) / 2; return p; };
  auto nxtI = [&](size_t n) { int* p = (int*)(ws + off); off += n; return p; };
  float* x_mol    = nxt((size_t)NM * 64);
  float* x_prot   = nxt((size_t)NP * 64);
  float* agg_mol  = nxt((size_t)NM * 64);
  float* agg_prot = nxt((size_t)NP * 64);
  float* h_mol    = nxt((size_t)NM * 64);
  float* h_prot   = nxt((size_t)NP * 64);
  _Float16* Qm  = nxtH((size_t)NM * 64);
  _Float16* Km  = nxtH((size_t)NM * 64);
  _Float16* Vtm = nxtH((size_t)NM * 64);
  _Float16* Qp  = nxtH((size_t)NP * 64);
  _Float16* Kp  = nxtH((size_t)NP * 64);
  _Float16* Vtp = nxtH((size_t)NP * 64);
  float* OPm = nxt((size_t)SPLIT_M2P * NM * 64);
  float* LPm = nxt((size_t)SPLIT_M2P * NM * 4);
  float* OPp = nxt((size_t)SPLIT_P2M * NP * 64);
  float* LPp = nxt((size_t)SPLIT_P2M * NP * 4);
  float* pool = nxt(32 * 128);
  float* cnt  = nxt(64);
  int* deg      = nxtI(NTOT);
  int* rowStart = nxtI(NTOT + 1);
  int* cursor   = nxtI(NTOT);
  int* slotOf   = nxtI(ETOT);
  int* srcPerm  = nxtI(ETOT);
  float* attrPerm = nxt((size_t)ETOT * 12);
  _Float16* eaPerm = nxtH((size_t)ETOT * 64);

  // ---- CSR + edge-embedding setup (once per call) ----
  (void)hipMemsetAsync(deg, 0, NTOT * 4, stream);
  deg_hist_kernel<<<(ETOT + 255) / 256, 256, 0, stream>>>(mol_ei, prot_ei, deg);
  scan_kernel<<<1, 1024, 0, stream>>>(deg, rowStart, cursor);
  fill_kernel<<<(ETOT + 255) / 256, 256, 0, stream>>>(mol_ei, prot_ei, cursor, srcPerm, slotOf);
  attr_perm_kernel<<<ETOT * 16 / 256, 256, 0, stream>>>(slotOf, mol_edge_attr,
                                                        prot_edge_attr, attrPerm);
  ea_lin_kernel<<<ETOT / 128, 256, 0, stream>>>(attrPerm, iem_w, iem_b, iep_w, iep_b, eaPerm);

  init_embed_dual<<<(NM + NP) * 64 / 256, 256, 0, stream>>>(
      mol_x, inm_w, inm_b, x_mol, prot_x, inp_w, inp_b, x_prot);

  for (int l = 0; l < 3; l++) {
    gine_gather_kernel<<<NTOT / 4, 256, 0, stream>>>(x_mol, x_prot, rowStart, srcPerm,
                                                     eaPerm, agg_mol, agg_prot);
    // m2p: Q=mol (m2p W0), K/V=prot (m2p W1,W2); p2m: Q=prot (p2m W0), K/V=mol (p2m W1,W2)
    mlp_proj_dual<<<192, 256, 0, stream>>>(
        x_mol, agg_mol, gm_w1 + l * 4096, gm_b1 + l * 64, gm_w2 + l * 4096, gm_b2 + l * 64, h_mol,
        m2p_w + (l * 3 + 0) * 4096, m2p_b + (l * 3 + 0) * 64,
        p2m_w + (l * 3 + 1) * 4096, p2m_b + (l * 3 + 1) * 64,
        p2m_w + (l * 3 + 2) * 4096, p2m_b + (l * 3 + 2) * 64,
        Qm, Km, Vtm,
        x_prot, agg_prot, gp_w1 + l * 4096, gp_b1 + l * 64, gp_w2 + l * 4096, gp_b2 + l * 64, h_prot,
        p2m_w + (l * 3 + 0) * 4096, p2m_b + (l * 3 + 0) * 64,
        m2p_w + (l * 3 + 1) * 4096, m2p_b + (l * 3 + 1) * 64,
        m2p_w + (l * 3 + 2) * 4096, m2p_b + (l * 3 + 2) * 64,
        Qp, Kp, Vtp);
    attn_split_kernel<<<dim3(512, 4), 256, 0, stream>>>(
        Qm, Kp, Vtp, OPm, LPm, Qp, Km, Vtm, OPp, LPp);
    ln_combine_dual<<<(NM + NP) * 64 / 256, 256, 0, stream>>>(
        h_mol, OPm, LPm, lnm_g + l * 64, lnm_b + l * 64, x_mol,
        h_prot, OPp, LPp, lnp_g + l * 64, lnp_b + l * 64, x_prot);
  }

  (void)hipMemsetAsync(pool, 0, (32 * 128 + 64) * 4, stream);
  pool_run_kernel<<<48, 256, 0, stream>>>(x_mol, mol_batch, x_prot, prot_batch, pool, cnt);
  final_kernel<<<1, 256, 0, stream>>>(pool, cnt, fc1_w, fc1_b, fc2_w, fc2_b, (float*)d_out);
}

// Round 17
// 476.413 us; speedup vs baseline: 1.7023x; 1.0126x over previous
//
#include <hip/hip_runtime.h>
#include <cstddef>

typedef _Float16 f16x4 __attribute__((ext_vector_type(4)));
typedef __fp16 h16x2 __attribute__((ext_vector_type(2)));
typedef float f32x4 __attribute__((ext_vector_type(4)));

__device__ __forceinline__ f32x4 mfma16(f16x4 a, f16x4 b, f32x4 c) {
  return __builtin_amdgcn_mfma_f32_16x16x16f16(a, b, c, 0, 0, 0);
}

// raw v_exp_f32 (2^x). OCML exp2f wraps it in denormal fixup we don't need.
__device__ __forceinline__ float fast_exp2(float x) {
#if __has_builtin(__builtin_amdgcn_exp2f)
  return __builtin_amdgcn_exp2f(x);
#else
  return exp2f(x);
#endif
}

// Q is pre-scaled by 0.25 * log2(e) so softmax weights are exp2(score).
#define QSCALE (0.25f * 1.44269504f)
#define SPLIT_M2P 4
#define SPLIT_P2M 2
#define NMC 4096
#define NPC 8192
#define EMC 65536
#define EPC 262144
#define NTOT (NMC + NPC)      // 12288 combined nodes (prot offset by NMC)
#define ETOT (EMC + EPC)      // 327680 combined edges

// ---------------------------------------------------------------------------
// init node embedding, both graphs
// ---------------------------------------------------------------------------
__global__ __launch_bounds__(256) void init_embed_dual(
    const float* __restrict__ inm, const float* __restrict__ Wm,
    const float* __restrict__ bm, float* __restrict__ outm,
    const float* __restrict__ inp, const float* __restrict__ Wp,
    const float* __restrict__ bp, float* __restrict__ outp)
{
  int idx = blockIdx.x * 256 + threadIdx.x;
  const float *in, *W, *bb;
  float* out;
  int Kin;
  if (idx < NMC * 64) {
    in = inm; W = Wm; bb = bm; out = outm; Kin = 11;
  } else {
    idx -= NMC * 64;
    if (idx >= NPC * 64) return;
    in = inp; W = Wp; bb = bp; out = outp; Kin = 15;
  }
  int n = idx >> 6, o = idx & 63;
  float acc = bb[o];
  const float* row = in + (size_t)n * Kin;
  for (int k = 0; k < Kin; k++) acc += row[k] * W[k * 64 + o];
  out[idx] = acc;
}

// ===========================================================================
// CSR construction (once per call).
// ===========================================================================
__global__ __launch_bounds__(256) void deg_hist_kernel(
    const int* __restrict__ eim, const int* __restrict__ eip, int* __restrict__ deg)
{
  int idx = blockIdx.x * 256 + threadIdx.x;
  if (idx >= ETOT) return;
  int dst = (idx < EMC) ? eim[EMC + idx] : (eip[EPC + (idx - EMC)] + NMC);
  atomicAdd(&deg[dst], 1);
}

__global__ __launch_bounds__(1024) void scan_kernel(
    const int* __restrict__ deg, int* __restrict__ rowStart, int* __restrict__ cursor)
{
  __shared__ int part[1024];
  int t = threadIdx.x;
  int base = t * 12;
  int local[12];
  int s = 0;
  #pragma unroll
  for (int i = 0; i < 12; i++) { local[i] = s; s += deg[base + i]; }
  part[t] = s;
  __syncthreads();
  #pragma unroll
  for (int d = 1; d < 1024; d <<= 1) {
    int v = (t >= d) ? part[t - d] : 0;
    __syncthreads();
    part[t] += v;
    __syncthreads();
  }
  int prefix = (t == 0) ? 0 : part[t - 1];
  #pragma unroll
  for (int i = 0; i < 12; i++) {
    int v = prefix + local[i];
    rowStart[base + i] = v;
    cursor[base + i] = v;
  }
  if (t == 1023) rowStart[NTOT] = prefix + s;
}

__global__ __launch_bounds__(256) void fill_kernel(
    const int* __restrict__ eim, const int* __restrict__ eip,
    int* __restrict__ cursor, int* __restrict__ srcPerm, int* __restrict__ slotOf)
{
  int idx = blockIdx.x * 256 + threadIdx.x;
  if (idx >= ETOT) return;
  int src, dst;
  if (idx < EMC) {
    src = eim[idx]; dst = eim[EMC + idx];
  } else {
    int e = idx - EMC; src = eip[e]; dst = eip[EPC + e] + NMC;
  }
  int slot = atomicAdd(&cursor[dst], 1);
  srcPerm[slot] = src;
  slotOf[idx] = slot;
}

__global__ __launch_bounds__(256) void attr_perm_kernel(
    const int* __restrict__ slotOf,
    const float* __restrict__ attrm, const float* __restrict__ attrp,
    float* __restrict__ attrPerm)
{
  int idx = blockIdx.x * 256 + threadIdx.x;
  int e = idx >> 4, k = idx & 15;
  if (e >= ETOT || k >= 12) return;
  float v = 0.f;
  if (k < 10)
    v = (e < EMC) ? attrm[(size_t)e * 10 + k] : attrp[(size_t)(e - EMC) * 10 + k];
  attrPerm[(size_t)slotOf[e] * 12 + k] = v;
}

// materialize fp16 edge embeddings in SLOT order, 128 slots per block.
__global__ __launch_bounds__(256) void ea_lin_kernel(
    const float* __restrict__ attrPerm,
    const float* __restrict__ Wem, const float* __restrict__ bem,
    const float* __restrict__ Wep, const float* __restrict__ bep,
    _Float16* __restrict__ eaPerm)
{
  __shared__ __align__(16) float sAttr[128 * 12];
  __shared__ float sWe[10 * 64];
  __shared__ float sBe[64];
  int t = threadIdx.x;
  int s0 = blockIdx.x * 128;
  const float* We = (s0 < EMC) ? Wem : Wep;
  const float* be = (s0 < EMC) ? bem : bep;
  #pragma unroll
  for (int i = 0; i < 6; i++) {
    int f = t + i * 256;
    sAttr[f] = attrPerm[(size_t)s0 * 12 + f];
  }
  for (int f = t; f < 640; f += 256) sWe[f] = We[f];
  if (t < 64) sBe[t] = be[t];
  __syncthreads();
  int sl = t >> 1;
  int d0 = (t & 1) * 32;
  float at[10];
  #pragma unroll
  for (int k = 0; k < 10; k++) at[k] = sAttr[sl * 12 + k];
  _Float16 outv[32];
  #pragma unroll
  for (int j = 0; j < 32; j++) {
    int d = d0 + j;
    float ea = sBe[d];
    #pragma unroll
    for (int k = 0; k < 10; k++) ea += at[k] * sWe[k * 64 + d];
    outv[j] = (_Float16)ea;
  }
  float4* dst = (float4*)(eaPerm + (size_t)(s0 + sl) * 64 + d0);
  const float4* src = (const float4*)outv;
  #pragma unroll
  for (int j = 0; j < 4; j++) dst[j] = src[j];
}

// ---------------------------------------------------------------------------
// GINE aggregation via CSR gather: one wave per node, lane = dim.
// ---------------------------------------------------------------------------
__global__ __launch_bounds__(256) void gine_gather_kernel(
    const float* __restrict__ xm, const float* __restrict__ xp,
    const int* __restrict__ rowStart, const int* __restrict__ srcPerm,
    const _Float16* __restrict__ eaPerm,
    float* __restrict__ aggm, float* __restrict__ aggp)
{
  int n = (blockIdx.x * 256 + threadIdx.x) >> 6;
  int lane = threadIdx.x & 63;
  if (n >= NTOT) return;
  const float* x;
  float* agg;
  int nl;
  if (n < NMC) { x = xm; agg = aggm; nl = n; }
  else         { x = xp; agg = aggp; nl = n - NMC; }
  int b0 = rowStart[n], b1 = rowStart[n + 1];
  float acc = 0.f;
  int i = b0;
  for (; i + 3 < b1; i += 4) {
    int s0 = srcPerm[i], s1 = srcPerm[i + 1], s2 = srcPerm[i + 2], s3 = srcPerm[i + 3];
    float e0 = (float)eaPerm[(size_t)i * 64 + lane];
    float e1 = (float)eaPerm[(size_t)(i + 1) * 64 + lane];
    float e2 = (float)eaPerm[(size_t)(i + 2) * 64 + lane];
    float e3 = (float)eaPerm[(size_t)(i + 3) * 64 + lane];
    float x0 = x[(size_t)s0 * 64 + lane];
    float x1 = x[(size_t)s1 * 64 + lane];
    float x2 = x[(size_t)s2 * 64 + lane];
    float x3 = x[(size_t)s3 * 64 + lane];
    acc += fmaxf(x0 + e0, 0.f) + fmaxf(x1 + e1, 0.f)
         + fmaxf(x2 + e2, 0.f) + fmaxf(x3 + e3, 0.f);
  }
  for (; i < b1; i++) {
    int src = srcPerm[i];
    float m = x[(size_t)src * 64 + lane] + (float)eaPerm[(size_t)i * 64 + lane];
    acc += fmaxf(m, 0.f);
  }
  agg[(size_t)nl * 64 + lane] = acc;
}

// ---------------------------------------------------------------------------
// Fused GINE node MLP + QKV projection via MFMA, both graphs.
// 32-node tiles (384 blocks) for latency hiding: wave w owns output dims
// w*16..+15 (= head w for QKV); 8 mfma per wave per phase.
// blocks [0,128) mol, [128,384) prot.
// ---------------------------------------------------------------------------
__global__ __launch_bounds__(256) void mlp_proj_dual(
    const float* __restrict__ xm, const float* __restrict__ aggm,
    const float* __restrict__ W1m, const float* __restrict__ B1m,
    const float* __restrict__ W2m, const float* __restrict__ B2m,
    float* __restrict__ hm,
    const float* __restrict__ Wqm, const float* __restrict__ bqm,
    const float* __restrict__ Wkm, const float* __restrict__ bkm,
    const float* __restrict__ Wvm, const float* __restrict__ bvm,
    _Float16* __restrict__ Qom, _Float16* __restrict__ Kom, _Float16* __restrict__ Vtom,
    const float* __restrict__ xp, const float* __restrict__ aggp,
    const float* __restrict__ W1p, const float* __restrict__ B1p,
    const float* __restrict__ W2p, const float* __restrict__ B2p,
    float* __restrict__ hp,
    const float* __restrict__ Wqp, const float* __restrict__ bqp,
    const float* __restrict__ Wkp, const float* __restrict__ bkp,
    const float* __restrict__ Wvp, const float* __restrict__ bvp,
    _Float16* __restrict__ Qop, _Float16* __restrict__ Kop, _Float16* __restrict__ Vtop)
{
  __shared__ __align__(16) _Float16 sA[32 * 68];
  __shared__ __align__(16) _Float16 sB[32 * 68];
  __shared__ __align__(16) _Float16 sWt[64 * 68];
  __shared__ float sBias[64];
  int t = threadIdx.x;
  int b = blockIdx.x;
  const float *x, *agg, *W1, *B1, *W2, *B2, *Wq, *bq, *Wk, *bk, *Wv, *bv;
  float* hg;
  _Float16 *Qo, *Ko, *Vto;
  int n0, N;
  if (b < 128) {
    x = xm; agg = aggm; W1 = W1m; B1 = B1m; W2 = W2m; B2 = B2m; hg = hm;
    Wq = Wqm; bq = bqm; Wk = Wkm; bk = bkm; Wv = Wvm; bv = bvm;
    Qo = Qom; Ko = Kom; Vto = Vtom; n0 = b * 32; N = NMC;
  } else {
    x = xp; agg = aggp; W1 = W1p; B1 = B1p; W2 = W2p; B2 = B2p; hg = hp;
    Wq = Wqp; bq = bqp; Wk = Wkp; bk = bkp; Wv = Wvp; bv = bvp;
    Qo = Qop; Ko = Kop; Vto = Vtop; n0 = (b - 128) * 32; N = NPC;
  }
  const int wave = t >> 6, lane = t & 63;
  const int l16 = lane & 15, quad = lane >> 4;

  auto stageW = [&](const float* W, const float* bias) {
    #pragma unroll
    for (int i = 0; i < 16; i++) {
      int f = t + i * 256;
      sWt[(f & 63) * 68 + (f >> 6)] = (_Float16)W[f];   // transposed
    }
    if (t < 64) sBias[t] = bias[t];
  };

  f32x4 acc[2];
  auto gemm = [&](const _Float16* src) {
    #pragma unroll
    for (int mt = 0; mt < 2; mt++) acc[mt] = (f32x4){0.f, 0.f, 0.f, 0.f};
    #pragma unroll
    for (int ks = 0; ks < 4; ks++) {
      f16x4 bf = *(const f16x4*)(sWt + (wave * 16 + l16) * 68 + ks * 16 + quad * 4);
      #pragma unroll
      for (int mt = 0; mt < 2; mt++) {
        f16x4 af = *(const f16x4*)(src + (mt * 16 + l16) * 68 + ks * 16 + quad * 4);
        acc[mt] = mfma16(af, bf, acc[mt]);
      }
    }
  };

  #pragma unroll
  for (int i = 0; i < 8; i++) {
    int f = t + i * 256;          // 0..2047
    size_t g = (size_t)n0 * 64 + f;
    sA[(f >> 6) * 68 + (f & 63)] = (_Float16)(x[g] + agg[g]);
  }
  stageW(W1, B1);
  __syncthreads();

  int od = wave * 16 + l16;

  // phase 1: hidden = relu(in @ W1 + B1) -> sB
  {
    float bias = sBias[od];
    gemm(sA);
    __syncthreads();
    #pragma unroll
    for (int mt = 0; mt < 2; mt++)
      #pragma unroll
      for (int r = 0; r < 4; r++) {
        int node = mt * 16 + quad * 4 + r;
        sB[node * 68 + od] = (_Float16)fmaxf(acc[mt][r] + bias, 0.f);
      }
    stageW(W2, B2);
    __syncthreads();
  }
  // phase 2: h = relu(hidden @ W2 + B2) -> global f32 + sA
  {
    float bias = sBias[od];
    gemm(sB);
    __syncthreads();
    #pragma unroll
    for (int mt = 0; mt < 2; mt++)
      #pragma unroll
      for (int r = 0; r < 4; r++) {
        int node = mt * 16 + quad * 4 + r;
        float v = fmaxf(acc[mt][r] + bias, 0.f);
        hg[(size_t)(n0 + node) * 64 + od] = v;
        sA[node * 68 + od] = (_Float16)v;
      }
    stageW(Wq, bq);
    __syncthreads();
  }
  // phase 3: Q
  {
    float bias = sBias[od];
    gemm(sA);
    __syncthreads();
    #pragma unroll
    for (int mt = 0; mt < 2; mt++)
      #pragma unroll
      for (int r = 0; r < 4; r++) {
        int node = mt * 16 + quad * 4 + r;
        Qo[((size_t)wave * N + n0 + node) * 16 + l16] =
            (_Float16)((acc[mt][r] + bias) * QSCALE);
      }
    stageW(Wk, bk);
    __syncthreads();
  }
  // phase 4: K
  {
    float bias = sBias[od];
    gemm(sA);
    __syncthreads();
    #pragma unroll
    for (int mt = 0; mt < 2; mt++)
      #pragma unroll
      for (int r = 0; r < 4; r++) {
        int node = mt * 16 + quad * 4 + r;
        Ko[((size_t)wave * N + n0 + node) * 16 + l16] = (_Float16)(acc[mt][r] + bias);
      }
    stageW(Wv, bv);
    __syncthreads();
  }
  // phase 5: Vt
  {
    float bias = sBias[od];
    gemm(sA);
    #pragma unroll
    for (int mt = 0; mt < 2; mt++) {
      f16x4 pk;
      #pragma unroll
      for (int r = 0; r < 4; r++) pk[r] = (_Float16)(acc[mt][r] + bias);
      *(f16x4*)(Vto + ((size_t)wave * 16 + l16) * N + n0 + mt * 16 + quad * 4) = pk;
    }
  }
}

// ---------------------------------------------------------------------------
// Key-split MFMA cross-attention, balanced per-direction splits, ONE
// residency generation: m2p SPLIT_M2P=4 (2048 keys/split), p2m SPLIT_P2M=2
// (2048 keys/split) -> every block runs exactly 8 pipelined 256-key
// iterations; grid (256, H) = 1024 blocks = 4/CU.
// u<128: m2p (qb=u&31, split=u>>5); else p2m (qb=v&63, split=v>>6).
// ---------------------------------------------------------------------------
__global__ __launch_bounds__(256, 4) void attn_split_kernel(
    const _Float16* __restrict__ Qm, const _Float16* __restrict__ Kp,
    const _Float16* __restrict__ Vtp, float* __restrict__ OPm, float* __restrict__ LPm,
    const _Float16* __restrict__ Qp, const _Float16* __restrict__ Km,
    const _Float16* __restrict__ Vtm, float* __restrict__ OPp, float* __restrict__ LPp)
{
  const int u = blockIdx.x;
  const _Float16 *Q, *K, *Vt;
  float *Opart, *Lpart;
  int Nq, Nk, qb, split, nsplit;
  if (u < 128) {
    Q = Qm; K = Kp; Vt = Vtp; Opart = OPm; Lpart = LPm;
    Nq = NMC; Nk = NPC; qb = u & 31; split = u >> 5; nsplit = SPLIT_M2P;
  } else {
    int v = u - 128;
    Q = Qp; K = Km; Vt = Vtm; Opart = OPp; Lpart = LPp;
    Nq = NPC; Nk = NMC; qb = v & 63; split = v >> 6; nsplit = SPLIT_P2M;
  }
  const int h = blockIdx.y;
  const int Ks = Nk / nsplit;
  const int q0 = qb * 128;
  const int t = threadIdx.x;
  const int wave = t >> 6, lane = t & 63;
  const int l16 = lane & 15, quad = lane >> 4;

  f16x4 qf[8];
  #pragma unroll
  for (int g = 0; g < 8; g++)
    qf[g] = *(const f16x4*)(Q + ((size_t)h * Nq + q0 + g * 16 + l16) * 16 + quad * 4);
  const _Float16* Kh = K + (size_t)h * Nk * 16;
  const _Float16* Vh = Vt + ((size_t)h * 16 + l16) * Nk;

  f32x4 oacc[8];
  float lacc[8];
  #pragma unroll
  for (int g = 0; g < 8; g++) { oacc[g] = (f32x4){0.f,0.f,0.f,0.f}; lacc[g] = 0.f; }
  const f32x4 zero = {0.f, 0.f, 0.f, 0.f};
  const h16x2 ones2 = {(__fp16)1.f, (__fp16)1.f};

  union PF { f16x4 v4; h16x2 h2[2]; };

  auto process = [&](const f16x4* kf, const f16x4* vf) {
    #pragma unroll
    for (int g = 0; g < 8; g++) {
      f32x4 s[4];
      #pragma unroll
      for (int c = 0; c < 4; c++) s[c] = mfma16(kf[c], qf[g], zero);
      f16x4 pf[4];
      #pragma unroll
      for (int c = 0; c < 4; c++) {
        float p0 = fast_exp2(s[c][0]);
        float p1 = fast_exp2(s[c][1]);
        float p2 = fast_exp2(s[c][2]);
        float p3 = fast_exp2(s[c][3]);
        PF u2;
        u2.h2[0] = __builtin_amdgcn_cvt_pkrtz(p0, p1);
        u2.h2[1] = __builtin_amdgcn_cvt_pkrtz(p2, p3);
        pf[c] = u2.v4;
        lacc[g] = __builtin_amdgcn_fdot2(u2.h2[0], ones2, lacc[g], false);
        lacc[g] = __builtin_amdgcn_fdot2(u2.h2[1], ones2, lacc[g], false);
      }
      #pragma unroll
      for (int c = 0; c < 4; c++) oacc[g] = mfma16(vf[c], pf[c], oacc[g]);
    }
  };

  const int kend = (split + 1) * Ks;
  int kb = split * Ks + wave * 64;
  for (; kb + 256 < kend; kb += 512) {
    f16x4 kfA[4], vfA[4], kfB[4], vfB[4];
    #pragma unroll
    for (int c = 0; c < 4; c++) {
      kfA[c] = *(const f16x4*)(Kh + (size_t)(kb + c * 16 + l16) * 16 + quad * 4);
      vfA[c] = *(const f16x4*)(Vh + kb + c * 16 + quad * 4);
    }
    #pragma unroll
    for (int c = 0; c < 4; c++) {
      kfB[c] = *(const f16x4*)(Kh + (size_t)(kb + 256 + c * 16 + l16) * 16 + quad * 4);
      vfB[c] = *(const f16x4*)(Vh + kb + 256 + c * 16 + quad * 4);
    }
    process(kfA, vfA);
    process(kfB, vfB);
  }
  for (; kb < kend; kb += 256) {
    f16x4 kf[4], vf[4];
    #pragma unroll
    for (int c = 0; c < 4; c++) {
      kf[c] = *(const f16x4*)(Kh + (size_t)(kb + c * 16 + l16) * 16 + quad * 4);
      vf[c] = *(const f16x4*)(Vh + kb + c * 16 + quad * 4);
    }
    process(kf, vf);
  }

  // quad-reduce L within wave
  #pragma unroll
  for (int g = 0; g < 8; g++) {
    lacc[g] += __shfl_xor(lacc[g], 16);
    lacc[g] += __shfl_xor(lacc[g], 32);
  }

  // two-pass cross-wave combine (padded; ~20 KB)
  __shared__ float sO[4][4][16][17];
  __shared__ float sLw[8][4][16];
  if (quad == 0) {
    #pragma unroll
    for (int g = 0; g < 8; g++) sLw[g][wave][l16] = lacc[g];
  }
  int q = t >> 4, d = t & 15;
  #pragma unroll
  for (int pass = 0; pass < 2; pass++) {
    __syncthreads();
    #pragma unroll
    for (int gg = 0; gg < 4; gg++) {
      int g = pass * 4 + gg;
      #pragma unroll
      for (int r = 0; r < 4; r++) sO[gg][wave][quad * 4 + r][l16] = oacc[g][r];
    }
    __syncthreads();
    #pragma unroll
    for (int gg = 0; gg < 4; gg++) {
      int g = pass * 4 + gg;
      float O = 0.f;
      #pragma unroll
      for (int w = 0; w < 4; w++) O += sO[gg][w][d][q];
      size_t row = (size_t)split * Nq + q0 + g * 16 + q;
      Opart[row * 64 + h * 16 + d] = O;
      if (d == 0) {
        float L = sLw[g][0][q] + sLw[g][1][q] + sLw[g][2][q] + sLw[g][3][q];
        Lpart[row * 4 + h] = L;
      }
    }
  }
}

// ---------------------------------------------------------------------------
// Fused attn-split combine + LayerNorm(h + O/L) * g + b, BOTH graphs.
// ---------------------------------------------------------------------------
__global__ __launch_bounds__(256) void ln_combine_dual(
    const float* __restrict__ hm, const float* __restrict__ Om,
    const float* __restrict__ Lm, const float* __restrict__ gm,
    const float* __restrict__ bm, float* __restrict__ outm,
    const float* __restrict__ hp, const float* __restrict__ Op,
    const float* __restrict__ Lp, const float* __restrict__ gp,
    const float* __restrict__ bp, float* __restrict__ outp)
{
  int idx = blockIdx.x * 256 + threadIdx.x;
  float O = 0.f, L = 0.f;
  const float *hb, *g, *bb;
  float* out;
  int totalM = NMC * 64;
  int n, d, h;
  if (idx < totalM) {
    n = idx >> 6; d = idx & 63; h = d >> 4;
    #pragma unroll
    for (int s = 0; s < SPLIT_M2P; s++) {
      size_t row = (size_t)s * NMC + n;
      O += Om[row * 64 + d];
      L += Lm[row * 4 + h];
    }
    hb = hm; g = gm; bb = bm; out = outm;
  } else {
    idx -= totalM;
    if (idx >= NPC * 64) return;
    n = idx >> 6; d = idx & 63; h = d >> 4;
    #pragma unroll
    for (int s = 0; s < SPLIT_P2M; s++) {
      size_t row = (size_t)s * NPC + n;
      O += Op[row * 64 + d];
      L += Lp[row * 4 + h];
    }
    hb = hp; g = gp; bb = bp; out = outp;
  }
  float v = hb[idx] + O / L;
  float sm = v;
  #pragma unroll
  for (int o = 1; o < 64; o <<= 1) sm += __shfl_xor(sm, o);
  float mu = sm * 0.015625f;
  float c = v - mu;
  float q = c * c;
  #pragma unroll
  for (int o = 1; o < 64; o <<= 1) q += __shfl_xor(q, o);
  float var = q * 0.015625f;
  out[idx] = c * rsqrtf(var + 1e-5f) * g[d] + bb[d];
}

// ---------------------------------------------------------------------------
// Pooling via sorted-run register accumulation.
// ---------------------------------------------------------------------------
__global__ __launch_bounds__(256) void pool_run_kernel(
    const float* __restrict__ xm, const int* __restrict__ bm,
    const float* __restrict__ xp, const int* __restrict__ bp,
    float* __restrict__ sums, float* __restrict__ cnt)
{
  int wid = (blockIdx.x * 256 + threadIdx.x) >> 6;
  int lane = threadIdx.x & 63;
  const float* x;
  const int* batch;
  int n0, colOff, cntOff;
  if (wid < 64) {
    x = xm; batch = bm; n0 = wid * 64; colOff = 0; cntOff = 0;
  } else {
    wid -= 64;
    if (wid >= 128) return;
    x = xp; batch = bp; n0 = wid * 64; colOff = 64; cntOff = 32;
  }
  float acc = 0.f;
  int cur = batch[n0];
  int run = 0;
  for (int i = 0; i < 64; i++) {
    int n = n0 + i;
    int s = batch[n];
    if (s != cur) {
      atomicAdd(&sums[cur * 128 + colOff + lane], acc);
      if (lane == 0) atomicAdd(&cnt[cntOff + cur], (float)run);
      acc = 0.f; run = 0; cur = s;
    }
    acc += x[(size_t)n * 64 + lane];
    run++;
  }
  atomicAdd(&sums[cur * 128 + colOff + lane], acc);
  if (lane == 0) atomicAdd(&cnt[cntOff + cur], (float)run);
}

// ---------------------------------------------------------------------------
// final head
// ---------------------------------------------------------------------------
__global__ __launch_bounds__(256) void final_kernel(
    const float* __restrict__ sums, const float* __restrict__ cnt,
    const float* __restrict__ fc1w, const float* __restrict__ fc1b,
    const float* __restrict__ fc2w, const float* __restrict__ fc2b,
    float* __restrict__ out)
{
  __shared__ float z[32 * 128];
  __shared__ float h1[32 * 64];
  int t = threadIdx.x;
  for (int f = t; f < 32 * 128; f += 256) {
    int s = f >> 7, j = f & 127;
    float c = cnt[(j >> 6) * 32 + s];
    z[f] = sums[f] / fmaxf(c, 1.f);
  }
  __syncthreads();
  for (int f = t; f < 32 * 64; f += 256) {
    int s = f >> 6, o = f & 63;
    float acc = fc1b[o];
    for (int j = 0; j < 128; j++) acc += z[s * 128 + j] * fc1w[j * 64 + o];
    h1[f] = fmaxf(acc, 0.f);
  }
  __syncthreads();
  if (t < 32) {
    float acc = fc2b[0];
    for (int o = 0; o < 64; o++) acc += h1[t * 64 + o] * fc2w[o];
    out[t] = 1.f / (1.f + __expf(-acc));
  }
}

// ---------------------------------------------------------------------------
extern "C" void kernel_launch(void* const* d_in, const int* in_sizes, int n_in,
                              void* d_out, int out_size, void* d_ws, size_t ws_size,
                              hipStream_t stream)
{
  (void)in_sizes; (void)n_in; (void)out_size; (void)ws_size;
  const float* mol_x          = (const float*)d_in[0];
  const float* prot_x         = (const float*)d_in[1];
  const float* mol_edge_attr  = (const float*)d_in[2];
  const float* prot_edge_attr = (const float*)d_in[3];
  const float* inm_w = (const float*)d_in[4];
  const float* inm_b = (const float*)d_in[5];
  const float* inp_w = (const float*)d_in[6];
  const float* inp_b = (const float*)d_in[7];
  const float* iem_w = (const float*)d_in[8];
  const float* iem_b = (const float*)d_in[9];
  const float* iep_w = (const float*)d_in[10];
  const float* iep_b = (const float*)d_in[11];
  const float* gm_w1 = (const float*)d_in[12];
  const float* gm_b1 = (const float*)d_in[13];
  const float* gm_w2 = (const float*)d_in[14];
  const float* gm_b2 = (const float*)d_in[15];
  const float* gp_w1 = (const float*)d_in[16];
  const float* gp_b1 = (const float*)d_in[17];
  const float* gp_w2 = (const float*)d_in[18];
  const float* gp_b2 = (const float*)d_in[19];
  const float* m2p_w = (const float*)d_in[20];
  const float* m2p_b = (const float*)d_in[21];
  const float* p2m_w = (const float*)d_in[22];
  const float* p2m_b = (const float*)d_in[23];
  const float* lnm_g = (const float*)d_in[24];
  const float* lnm_b = (const float*)d_in[25];
  const float* lnp_g = (const float*)d_in[26];
  const float* lnp_b = (const float*)d_in[27];
  const float* fc1_w = (const float*)d_in[28];
  const float* fc1_b = (const float*)d_in[29];
  const float* fc2_w = (const float*)d_in[30];
  const float* fc2_b = (const float*)d_in[31];
  const int* mol_ei     = (const int*)d_in[32];
  const int* prot_ei    = (const int*)d_in[33];
  const int* mol_batch  = (const int*)d_in[34];
  const int* prot_batch = (const int*)d_in[35];

  const int NM = NMC, NP = NPC;

  float* ws = (float*)d_ws;
  size_t off = 0;
  auto nxt  = [&](size_t n) { float* p = ws + off; off += n; return p; };
  auto nxtH = [&](size_t n) { _Float16* p = (_Float16*)(ws + off); off += (n + 1) / 2; return p; };
  auto nxtI = [&](size_t n) { int* p = (int*)(ws + off); off += n; return p; };
  float* x_mol    = nxt((size_t)NM * 64);
  float* x_prot   = nxt((size_t)NP * 64);
  float* agg_mol  = nxt((size_t)NM * 64);
  float* agg_prot = nxt((size_t)NP * 64);
  float* h_mol    = nxt((size_t)NM * 64);
  float* h_prot   = nxt((size_t)NP * 64);
  _Float16* Qm  = nxtH((size_t)NM * 64);
  _Float16* Km  = nxtH((size_t)NM * 64);
  _Float16* Vtm = nxtH((size_t)NM * 64);
  _Float16* Qp  = nxtH((size_t)NP * 64);
  _Float16* Kp  = nxtH((size_t)NP * 64);
  _Float16* Vtp = nxtH((size_t)NP * 64);
  float* OPm = nxt((size_t)SPLIT_M2P * NM * 64);
  float* LPm = nxt((size_t)SPLIT_M2P * NM * 4);
  float* OPp = nxt((size_t)SPLIT_P2M * NP * 64);
  float* LPp = nxt((size_t)SPLIT_P2M * NP * 4);
  float* pool = nxt(32 * 128);
  float* cnt  = nxt(64);
  int* deg      = nxtI(NTOT);
  int* rowStart = nxtI(NTOT + 1);
  int* cursor   = nxtI(NTOT);
  int* slotOf   = nxtI(ETOT);
  int* srcPerm  = nxtI(ETOT);
  float* attrPerm = nxt((size_t)ETOT * 12);
  _Float16* eaPerm = nxtH((size_t)ETOT * 64);

  // ---- CSR + edge-embedding setup (once per call) ----
  (void)hipMemsetAsync(deg, 0, NTOT * 4, stream);
  deg_hist_kernel<<<(ETOT + 255) / 256, 256, 0, stream>>>(mol_ei, prot_ei, deg);
  scan_kernel<<<1, 1024, 0, stream>>>(deg, rowStart, cursor);
  fill_kernel<<<(ETOT + 255) / 256, 256, 0, stream>>>(mol_ei, prot_ei, cursor, srcPerm, slotOf);
  attr_perm_kernel<<<ETOT * 16 / 256, 256, 0, stream>>>(slotOf, mol_edge_attr,
                                                        prot_edge_attr, attrPerm);
  ea_lin_kernel<<<ETOT / 128, 256, 0, stream>>>(attrPerm, iem_w, iem_b, iep_w, iep_b, eaPerm);

  init_embed_dual<<<(NM + NP) * 64 / 256, 256, 0, stream>>>(
      mol_x, inm_w, inm_b, x_mol, prot_x, inp_w, inp_b, x_prot);

  for (int l = 0; l < 3; l++) {
    gine_gather_kernel<<<NTOT / 4, 256, 0, stream>>>(x_mol, x_prot, rowStart, srcPerm,
                                                     eaPerm, agg_mol, agg_prot);
    // m2p: Q=mol (m2p W0), K/V=prot (m2p W1,W2); p2m: Q=prot (p2m W0), K/V=mol (p2m W1,W2)
    mlp_proj_dual<<<384, 256, 0, stream>>>(
        x_mol, agg_mol, gm_w1 + l * 4096, gm_b1 + l * 64, gm_w2 + l * 4096, gm_b2 + l * 64, h_mol,
        m2p_w + (l * 3 + 0) * 4096, m2p_b + (l * 3 + 0) * 64,
        p2m_w + (l * 3 + 1) * 4096, p2m_b + (l * 3 + 1) * 64,
        p2m_w + (l * 3 + 2) * 4096, p2m_b + (l * 3 + 2) * 64,
        Qm, Km, Vtm,
        x_prot, agg_prot, gp_w1 + l * 4096, gp_b1 + l * 64, gp_w2 + l * 4096, gp_b2 + l * 64, h_prot,
        p2m_w + (l * 3 + 0) * 4096, p2m_b + (l * 3 + 0) * 64,
        m2p_w + (l * 3 + 1) * 4096, m2p_b + (l * 3 + 1) * 64,
        m2p_w + (l * 3 + 2) * 4096, m2p_b + (l * 3 + 2) * 64,
        Qp, Kp, Vtp);
    attn_split_kernel<<<dim3(256, 4), 256, 0, stream>>>(
        Qm, Kp, Vtp, OPm, LPm, Qp, Km, Vtm, OPp, LPp);
    ln_combine_dual<<<(NM + NP) * 64 / 256, 256, 0, stream>>>(
        h_mol, OPm, LPm, lnm_g + l * 64, lnm_b + l * 64, x_mol,
        h_prot, OPp, LPp, lnp_g + l * 64, lnp_b + l * 64, x_prot);
  }

  (void)hipMemsetAsync(pool, 0, (32 * 128 + 64) * 4, stream);
  pool_run_kernel<<<48, 256, 0, stream>>>(x_mol, mol_batch, x_prot, prot_batch, pool, cnt);
  final_kernel<<<1, 256, 0, stream>>>(pool, cnt, fc1_w, fc1_b, fc2_w, fc2_b, (float*)d_out);
}